// Round 5
// baseline (443.189 us; speedup 1.0000x reference)
//
#include <hip/hip_runtime.h>
#include <hip/hip_bf16.h>
#include <cstdint>
#include <cstddef>

typedef unsigned short u16;
typedef __bf16 bf16x8 __attribute__((ext_vector_type(8)));
typedef float f32x4 __attribute__((ext_vector_type(4)));

#define D_MODEL 1024
#define D_FF    4096
#define BATCH   2
#define SEQ     2048
#define NH      16
#define HD      64
#define ROWS    (BATCH*SEQ)   // 4096
#define QKVS    3072          // packed QKV row stride

// ---------- helpers ----------
__device__ __forceinline__ u16 f2bf(float f) {
    union { float f; uint32_t u; } v; v.f = f;
    uint32_t u = v.u;
    u += 0x7FFF + ((u >> 16) & 1);   // RNE
    return (u16)(u >> 16);
}

__device__ __forceinline__ uint32_t cvtpk_bf16(float lo, float hi) {
    uint32_t r;
    asm("v_cvt_pk_bf16_f32 %0, %1, %2" : "=v"(r) : "v"(lo), "v"(hi));
    return r;
}

__device__ __forceinline__ bf16x8 ldg8(const u16* p) {
    return *reinterpret_cast<const bf16x8*>(p);
}

__device__ __forceinline__ f32x4 mfma16(bf16x8 a, bf16x8 b, f32x4 c) {
    return __builtin_amdgcn_mfma_f32_16x16x32_bf16(a, b, c, 0, 0, 0);
}

__device__ __forceinline__ void gld_lds16(const void* g, void* l) {
    __builtin_amdgcn_global_load_lds(
        (const __attribute__((address_space(1))) void*)g,
        (__attribute__((address_space(3))) void*)l, 16, 0, 0);
}

struct alignas(8) U16x4 { u16 x, y, z, w; };

// ---------- fused f32 -> bf16 convert for all weights ----------
// dst is the contiguous 12M-elem region at the head of d_ws:
// [Wq 1M][Wk 1M][Wv 1M][Wo 1M][W1 4M][W2 4M]
__global__ void cvt_all(const float* __restrict__ s0, const float* __restrict__ s1,
                        const float* __restrict__ s2, const float* __restrict__ s3,
                        const float* __restrict__ s4, const float* __restrict__ s5,
                        u16* __restrict__ out)
{
    const size_t MM1 = 1 << 20;
    size_t i = ((size_t)blockIdx.x * 256 + threadIdx.x) * 4;
    const float* src; size_t off;
    if      (i <     MM1) { src = s0; off = i; }
    else if (i < 2 * MM1) { src = s1; off = i - MM1; }
    else if (i < 3 * MM1) { src = s2; off = i - 2 * MM1; }
    else if (i < 4 * MM1) { src = s3; off = i - 3 * MM1; }
    else if (i < 8 * MM1) { src = s4; off = i - 4 * MM1; }
    else                  { src = s5; off = i - 8 * MM1; }
    float4 f = *reinterpret_cast<const float4*>(src + off);
    U16x4 o{ f2bf(f.x), f2bf(f.y), f2bf(f.z), f2bf(f.w) };
    *reinterpret_cast<U16x4*>(out + i) = o;
}

// ---------- LayerNorm (f32 in, bf16 out) ----------
__global__ __launch_bounds__(256) void ln_bf16(
    const float* __restrict__ x, const float* __restrict__ g,
    const float* __restrict__ b, u16* __restrict__ out)
{
    int row = blockIdx.x;
    const float* xr = x + (size_t)row * D_MODEL;
    int t = threadIdx.x;
    float4 v = *reinterpret_cast<const float4*>(xr + t * 4);
    float s = v.x + v.y + v.z + v.w;
    float q = v.x*v.x + v.y*v.y + v.z*v.z + v.w*v.w;
    #pragma unroll
    for (int off = 1; off < 64; off <<= 1) {
        s += __shfl_xor(s, off);
        q += __shfl_xor(q, off);
    }
    __shared__ float red[8];
    if ((t & 63) == 0) { red[(t >> 6) * 2] = s; red[(t >> 6) * 2 + 1] = q; }
    __syncthreads();
    float sum = red[0] + red[2] + red[4] + red[6];
    float sq  = red[1] + red[3] + red[5] + red[7];
    float mu  = sum * (1.0f / D_MODEL);
    float var = sq * (1.0f / D_MODEL) - mu * mu;
    float rstd = rsqrtf(var + 1e-6f);
    float4 gg = *reinterpret_cast<const float4*>(g + t * 4);
    float4 bb = *reinterpret_cast<const float4*>(b + t * 4);
    U16x4 o{ f2bf((v.x - mu) * rstd * gg.x + bb.x),
             f2bf((v.y - mu) * rstd * gg.y + bb.y),
             f2bf((v.z - mu) * rstd * gg.z + bb.z),
             f2bf((v.w - mu) * rstd * gg.w + bb.w) };
    *reinterpret_cast<U16x4*>(out + (size_t)row * D_MODEL + t * 4) = o;
}

// ---------- GEMM: C[M,N] = A[M,K](bf16) @ W[N,K]^T(bf16) + bias ----------
// 2-deep counted-vmcnt pipeline (T4): prologue stages tiles 0,1; steady
// state keeps 8 loads (one full K-tile) in flight across the barrier --
// never drains vmcnt to 0 in the main loop. Raw s_barrier (NOT
// __syncthreads, which would drain vmcnt(0)).
#define EPI_BF16   0
#define EPI_RESF32 1
#define EPI_GELU   2

template<int EPI>
__global__ __launch_bounds__(256, 2) void gemm_bt(
    const u16* __restrict__ A, const u16* __restrict__ B,
    const float* __restrict__ bias, const float* __restrict__ res,
    u16* __restrict__ outb, float* __restrict__ outf,
    int M, int N, int K)
{
    __shared__ u16 As[2][128 * 64];
    __shared__ u16 Bs[2][128 * 64];
    const int t = threadIdx.x;
    const int lane = t & 63;
    const int w = t >> 6;
    const int lr = lane & 15, lg = lane >> 4;
    const int wrr = (w >> 1) * 64, wcc = (w & 1) * 64;
    const int brow = blockIdx.y * 128, bcol = blockIdx.x * 128;
    const u16* Ag = A + (size_t)brow * K;
    const u16* Bg = B + (size_t)bcol * K;

    f32x4 acc[4][4] = {};

    const int NT = K >> 6;   // always >= 16 here (K = 1024 or 4096)

    auto stage = [&](int buf, int kt) {
        const u16* ga = Ag + kt * 64;
        const u16* gb = Bg + kt * 64;
        u16* la = As[buf];
        u16* lb = Bs[buf];
        #pragma unroll
        for (int c = 0; c < 4; ++c) {
            int f = c * 256 + t;
            int row = f >> 3, slot = f & 7;
            int sg = slot ^ (row & 7);          // inverse-swizzled global source
            gld_lds16(ga + (size_t)row * K + sg * 8, la + f * 8);
            gld_lds16(gb + (size_t)row * K + sg * 8, lb + f * 8);
        }
    };

    auto compute = [&](int buf) {
        const u16* la = As[buf];
        const u16* lb = Bs[buf];
        bf16x8 af[4][2];
        #pragma unroll
        for (int mi = 0; mi < 4; ++mi) {
            int row = wrr + mi * 16 + lr;
            int base = row * 64;
            af[mi][0] = *reinterpret_cast<const bf16x8*>(la + base + ((0 + lg) ^ (row & 7)) * 8);
            af[mi][1] = *reinterpret_cast<const bf16x8*>(la + base + ((4 + lg) ^ (row & 7)) * 8);
        }
        __builtin_amdgcn_s_setprio(1);
        #pragma unroll
        for (int ni = 0; ni < 4; ++ni) {
            int row = wcc + ni * 16 + lr;
            int base = row * 64;
            bf16x8 b0 = *reinterpret_cast<const bf16x8*>(lb + base + ((0 + lg) ^ (row & 7)) * 8);
            bf16x8 b1 = *reinterpret_cast<const bf16x8*>(lb + base + ((4 + lg) ^ (row & 7)) * 8);
            #pragma unroll
            for (int mi = 0; mi < 4; ++mi) {
                acc[mi][ni] = mfma16(af[mi][0], b0, acc[mi][ni]);
                acc[mi][ni] = mfma16(af[mi][1], b1, acc[mi][ni]);
            }
        }
        __builtin_amdgcn_s_setprio(0);
    };

    // prologue: 2 tiles in flight, wait only for tile 0 (vmcnt(8) = tile 1 stays out)
    stage(0, 0);
    if (NT > 1) {
        stage(1, 1);
        asm volatile("s_waitcnt vmcnt(8)" ::: "memory");
    } else {
        asm volatile("s_waitcnt vmcnt(0)" ::: "memory");
    }
    __builtin_amdgcn_s_barrier();

    for (int kt = 0; kt < NT; ++kt) {
        compute(kt & 1);
        if (kt + 1 == NT) break;
        __builtin_amdgcn_s_barrier();          // all waves done reading buf[kt&1]
        if (kt + 2 < NT) {
            stage(kt & 1, kt + 2);             // refill just-freed buffer
            asm volatile("s_waitcnt vmcnt(8)" ::: "memory");   // tile kt+1 landed; kt+2 in flight
        } else {
            asm volatile("s_waitcnt vmcnt(0)" ::: "memory");   // tail: drain last tile
        }
        __builtin_amdgcn_s_barrier();          // everyone's tile kt+1 visible
    }

    // epilogue
    #pragma unroll
    for (int mi = 0; mi < 4; ++mi) {
        int r0 = brow + wrr + mi * 16 + lg * 4;
        #pragma unroll
        for (int ni = 0; ni < 4; ++ni) {
            int c = bcol + wcc + ni * 16 + lr;
            float bv = bias[c];
            #pragma unroll
            for (int j = 0; j < 4; ++j) {
                float v = acc[mi][ni][j] + bv;
                size_t idx = (size_t)(r0 + j) * N + c;
                if constexpr (EPI == EPI_GELU) {
                    v = 0.5f * v * (1.0f + erff(v * 0.70710678118f));
                    outb[idx] = f2bf(v);
                } else if constexpr (EPI == EPI_RESF32) {
                    outf[idx] = v + res[idx];
                } else {
                    outb[idx] = f2bf(v);
                }
            }
        }
    }
}

// ---------- V transpose: QKV[token][2048+h*64+d] -> VT[(b,h)][d][s] ----------
__global__ __launch_bounds__(256) void vtrans(
    const u16* __restrict__ QKV, u16* __restrict__ VT)
{
    const int st = blockIdx.x * 64;
    const int bh = blockIdx.y;
    const int b = bh >> 4, h = bh & 15;
    const int lane = threadIdx.x & 63, w = threadIdx.x >> 6;
    const u16* src = QKV + ((size_t)(b * SEQ + st + lane)) * QKVS + 2048 + h * HD;
    u16* dst = VT + (size_t)bh * HD * SEQ + st;
    #pragma unroll
    for (int c = 0; c < 2; ++c) {
        int doct = w + c * 4;                 // 0..7
        bf16x8 v = ldg8(src + doct * 8);
        #pragma unroll
        for (int i = 0; i < 8; ++i)
            dst[(size_t)(doct * 8 + i) * SEQ + lane] = ((const u16*)&v)[i];
    }
}

// ---------- causal flash attention v5 ----------
// K/V per (b,h) is 512 KB -> L2-resident. No LDS staging, no block
// barriers: each wave is fully independent (P bounce is per-wave LDS).
// Static-max softmax (scores ~N(0,1): exp can't overflow f32).
#define QBLK  64
#define KVBLK 64

__global__ __launch_bounds__(256, 3) void attn5(
    const u16* __restrict__ QKV, const u16* __restrict__ VT,
    u16* __restrict__ O)
{
    __shared__ u16 Pl[4][16 * 72];    // per-wave P[q][kv], stride 72

    const int bx = (gridDim.x - 1) - blockIdx.x;   // heavy-first
    const int bh = blockIdx.y;
    const int b = bh >> 4, h = bh & 15;
    const int q0 = bx * QBLK;
    const int t = threadIdx.x;
    const int lane = t & 63, w = t >> 6;
    const int lr = lane & 15, lg = lane >> 4;

    const size_t rowbase = (size_t)b * SEQ;
    const u16* Qg = QKV + rowbase * QKVS + h * HD;
    const u16* Kg = Qg + 1024;
    const u16* Vg = VT + (size_t)bh * HD * SEQ;

    // Q fragments: wave w owns rows q0 + w*16 + {0..15}
    const u16* qp = Qg + (size_t)(q0 + w * 16 + lr) * QKVS;
    bf16x8 qf0 = ldg8(qp + lg * 8);
    bf16x8 qf1 = ldg8(qp + 32 + lg * 8);

    f32x4 o[4] = {};
    float lsum[4] = { 0.f, 0.f, 0.f, 0.f };

    const int ntiles = bx + 1;
    u16* Pw = Pl[w];
    const float SC = 0.125f * 1.44269504089f;   // 1/sqrt(64) * log2(e)

    for (int tt = 0; tt < ntiles; ++tt) {
        const int kv0 = tt * KVBLK;

        // K fragments straight from L2: kv = kv0 + lr*4 + ni
        const u16* kp = Kg + (size_t)(kv0 + lr * 4) * QKVS + lg * 8;
        bf16x8 k0[4], k1[4];
        #pragma unroll
        for (int ni = 0; ni < 4; ++ni) {
            k0[ni] = ldg8(kp + (size_t)ni * QKVS);
            k1[ni] = ldg8(kp + (size_t)ni * QKVS + 32);
        }
        f32x4 s[4] = {};
        __builtin_amdgcn_s_setprio(1);
        #pragma unroll
        for (int ni = 0; ni < 4; ++ni) {
            s[ni] = mfma16(qf0, k0[ni], s[ni]);
            s[ni] = mfma16(qf1, k1[ni], s[ni]);
        }
        __builtin_amdgcn_s_setprio(0);

        // V fragments (independent of softmax -> overlap its latency)
        bf16x8 v0[4], v1[4];
        #pragma unroll
        for (int ni = 0; ni < 4; ++ni) {
            const u16* vp = Vg + (size_t)(ni * 16 + lr) * SEQ + kv0 + lg * 8;
            v0[ni] = ldg8(vp);
            v1[ni] = ldg8(vp + 32);
        }

        // static-max softmax: p = exp2(s*SC); mask only the diagonal tile
        const bool full = (tt + 1 < ntiles);
        #pragma unroll
        for (int j = 0; j < 4; ++j) {
            int qi = q0 + w * 16 + lg * 4 + j;
            float p0 = __builtin_amdgcn_exp2f(s[0][j] * SC);
            float p1 = __builtin_amdgcn_exp2f(s[1][j] * SC);
            float p2 = __builtin_amdgcn_exp2f(s[2][j] * SC);
            float p3 = __builtin_amdgcn_exp2f(s[3][j] * SC);
            if (!full) {
                int kvb = kv0 + lr * 4;
                p0 = (kvb     <= qi) ? p0 : 0.f;
                p1 = (kvb + 1 <= qi) ? p1 : 0.f;
                p2 = (kvb + 2 <= qi) ? p2 : 0.f;
                p3 = (kvb + 3 <= qi) ? p3 : 0.f;
            }
            lsum[j] += (p0 + p1) + (p2 + p3);
            uint2 pk = make_uint2(cvtpk_bf16(p0, p1), cvtpk_bf16(p2, p3));
            *reinterpret_cast<uint2*>(&Pw[(lg * 4 + j) * 72 + lr * 4]) = pk;
        }

        // PV: o[ni] += P[16x64] @ V[64x64]  (P via per-wave LDS bounce)
        bf16x8 pa0 = *reinterpret_cast<const bf16x8*>(Pw + lr * 72 + lg * 8);
        bf16x8 pa1 = *reinterpret_cast<const bf16x8*>(Pw + lr * 72 + 32 + lg * 8);
        __builtin_amdgcn_s_setprio(1);
        #pragma unroll
        for (int ni = 0; ni < 4; ++ni) {
            o[ni] = mfma16(pa0, v0[ni], o[ni]);
            o[ni] = mfma16(pa1, v1[ni], o[ni]);
        }
        __builtin_amdgcn_s_setprio(0);
    }

    // reduce denominator across the 16 kv-lanes (same lg group)
    #pragma unroll
    for (int j = 0; j < 4; ++j) {
        float v = lsum[j];
        v += __shfl_xor(v, 1);
        v += __shfl_xor(v, 2);
        v += __shfl_xor(v, 4);
        v += __shfl_xor(v, 8);
        lsum[j] = v;
    }

    // normalize + store: O[row][h*64 + d]
    u16* Ob = O + (rowbase + q0 + w * 16) * D_MODEL + h * HD;
    #pragma unroll
    for (int j = 0; j < 4; ++j) {
        float inv = 1.0f / lsum[j];
        int r = (lg * 4 + j) * D_MODEL;
        #pragma unroll
        for (int ni = 0; ni < 4; ++ni)
            Ob[r + ni * 16 + lr] = f2bf(o[ni][j] * inv);
    }
}

// ---------- launch ----------
extern "C" void kernel_launch(void* const* d_in, const int* in_sizes, int n_in,
                              void* d_out, int out_size, void* d_ws, size_t ws_size,
                              hipStream_t stream)
{
    (void)in_sizes; (void)n_in; (void)out_size; (void)ws_size;
    const float* x   = (const float*)d_in[0];
    const float* Wq  = (const float*)d_in[2];
    const float* bq  = (const float*)d_in[3];
    const float* Wk  = (const float*)d_in[4];
    const float* bk  = (const float*)d_in[5];
    const float* Wv  = (const float*)d_in[6];
    const float* bv  = (const float*)d_in[7];
    const float* Wo  = (const float*)d_in[8];
    const float* bo  = (const float*)d_in[9];
    const float* g1  = (const float*)d_in[10];
    const float* be1 = (const float*)d_in[11];
    const float* g2  = (const float*)d_in[12];
    const float* be2 = (const float*)d_in[13];
    const float* W1  = (const float*)d_in[14];
    const float* b1  = (const float*)d_in[15];
    const float* W2  = (const float*)d_in[16];
    const float* b2  = (const float*)d_in[17];
    float* out = (float*)d_out;

    const size_t MM = 1 << 20;   // 1M elems
    u16* Wqkv_b = (u16*)d_ws;            // 3M u16 (Wq,Wk,Wv packed [3072][1024])
    u16* Wo_b = Wqkv_b + 3 * MM;
    u16* W1_b = Wo_b + MM;               // 4M
    u16* W2_b = W1_b + 4 * MM;           // 4M
    u16* hbuf = W2_b + 4 * MM;           // 4M (LN out; dead after its GEMM)
    u16* QKVb = hbuf + 4 * MM;           // 12M  [4096][3072]
    u16* ctx  = QKVb + 12 * MM;          // 4M
    u16* ffn1 = ctx + 4 * MM;            // 16M
    float* x2 = (float*)(ffn1 + 16 * MM);        // 4M f32
    float* bqkv = (float*)(x2 + 4 * MM);         // 3072 f32
    // VT aliases hbuf: LN1 output is dead once the QKV GEMM completes,
    // and attention finishes before LN2 rewrites hbuf (stream-serial).
    u16* VTb = hbuf;                     // 4M u16 [32 bh][64 d][2048 s]

    // fused weight converts: 12M elems -> contiguous bf16 region at d_ws
    cvt_all<<<12 * MM / 1024, 256, 0, stream>>>(Wq, Wk, Wv, Wo, W1, W2, Wqkv_b);

    // pack QKV bias
    hipMemcpyAsync(bqkv,        bq, D_MODEL * sizeof(float), hipMemcpyDeviceToDevice, stream);
    hipMemcpyAsync(bqkv + 1024, bk, D_MODEL * sizeof(float), hipMemcpyDeviceToDevice, stream);
    hipMemcpyAsync(bqkv + 2048, bv, D_MODEL * sizeof(float), hipMemcpyDeviceToDevice, stream);

    // LN1
    ln_bf16<<<ROWS, 256, 0, stream>>>(x, g1, be1, hbuf);

    dim3 blk(256);
    // fused QKV projection: [4096,1024] @ [3072,1024]^T
    dim3 gqkv(QKVS / 128, ROWS / 128);        // (24, 32)
    gemm_bt<EPI_BF16><<<gqkv, blk, 0, stream>>>(hbuf, Wqkv_b, bqkv, nullptr, QKVb, nullptr, ROWS, QKVS, D_MODEL);

    // V transpose (hbuf is dead now; VTb aliases it)
    vtrans<<<dim3(SEQ / 64, BATCH * NH), blk, 0, stream>>>(QKVb, VTb);

    // attention
    dim3 ga(SEQ / QBLK, BATCH * NH);          // (32, 32)
    attn5<<<ga, blk, 0, stream>>>(QKVb, VTb, ctx);

    dim3 gq(D_MODEL / 128, ROWS / 128);       // (8, 32)
    gemm_bt<EPI_RESF32><<<gq, blk, 0, stream>>>(ctx, Wo_b, bo, x, nullptr, x2, ROWS, D_MODEL, D_MODEL);

    // LN2
    ln_bf16<<<ROWS, 256, 0, stream>>>(x2, g2, be2, hbuf);

    dim3 gf1(D_FF / 128, ROWS / 128);         // (32, 32)
    gemm_bt<EPI_GELU><<<gf1, blk, 0, stream>>>(hbuf, W1_b, b1, nullptr, ffn1, nullptr, ROWS, D_FF, D_MODEL);

    gemm_bt<EPI_RESF32><<<gq, blk, 0, stream>>>(ffn1, W2_b, b2, x2, nullptr, out, ROWS, D_MODEL, D_FF);
}

// Round 6
// 292.797 us; speedup vs baseline: 1.5136x; 1.5136x over previous
//
#include <hip/hip_runtime.h>
#include <hip/hip_bf16.h>
#include <cstdint>
#include <cstddef>

typedef unsigned short u16;
typedef __bf16 bf16x8 __attribute__((ext_vector_type(8)));
typedef float f32x4 __attribute__((ext_vector_type(4)));

#define D_MODEL 1024
#define D_FF    4096
#define BATCH   2
#define SEQ     2048
#define NH      16
#define HD      64
#define ROWS    (BATCH*SEQ)   // 4096
#define QKVS    3072          // packed QKV row stride

// ---------- helpers ----------
__device__ __forceinline__ u16 f2bf(float f) {
    union { float f; uint32_t u; } v; v.f = f;
    uint32_t u = v.u;
    u += 0x7FFF + ((u >> 16) & 1);   // RNE
    return (u16)(u >> 16);
}

__device__ __forceinline__ uint32_t cvtpk_bf16(float lo, float hi) {
    uint32_t r;
    asm("v_cvt_pk_bf16_f32 %0, %1, %2" : "=v"(r) : "v"(lo), "v"(hi));
    return r;
}

__device__ __forceinline__ bf16x8 ldg8(const u16* p) {
    return *reinterpret_cast<const bf16x8*>(p);
}

__device__ __forceinline__ f32x4 mfma16(bf16x8 a, bf16x8 b, f32x4 c) {
    return __builtin_amdgcn_mfma_f32_16x16x32_bf16(a, b, c, 0, 0, 0);
}

__device__ __forceinline__ void gld_lds16(const void* g, void* l) {
    __builtin_amdgcn_global_load_lds(
        (const __attribute__((address_space(1))) void*)g,
        (__attribute__((address_space(3))) void*)l, 16, 0, 0);
}

struct alignas(8) U16x4 { u16 x, y, z, w; };

// ---------- fused f32 -> bf16 convert for all weights ----------
// dst is the contiguous 12M-elem region at the head of d_ws:
// [Wq 1M][Wk 1M][Wv 1M][Wo 1M][W1 4M][W2 4M]
__global__ void cvt_all(const float* __restrict__ s0, const float* __restrict__ s1,
                        const float* __restrict__ s2, const float* __restrict__ s3,
                        const float* __restrict__ s4, const float* __restrict__ s5,
                        u16* __restrict__ out)
{
    const size_t MM1 = 1 << 20;
    size_t i = ((size_t)blockIdx.x * 256 + threadIdx.x) * 4;
    const float* src; size_t off;
    if      (i <     MM1) { src = s0; off = i; }
    else if (i < 2 * MM1) { src = s1; off = i - MM1; }
    else if (i < 3 * MM1) { src = s2; off = i - 2 * MM1; }
    else if (i < 4 * MM1) { src = s3; off = i - 3 * MM1; }
    else if (i < 8 * MM1) { src = s4; off = i - 4 * MM1; }
    else                  { src = s5; off = i - 8 * MM1; }
    float4 f = *reinterpret_cast<const float4*>(src + off);
    U16x4 o{ f2bf(f.x), f2bf(f.y), f2bf(f.z), f2bf(f.w) };
    *reinterpret_cast<U16x4*>(out + i) = o;
}

// ---------- LayerNorm (f32 in, bf16 out) ----------
__global__ __launch_bounds__(256) void ln_bf16(
    const float* __restrict__ x, const float* __restrict__ g,
    const float* __restrict__ b, u16* __restrict__ out)
{
    int row = blockIdx.x;
    const float* xr = x + (size_t)row * D_MODEL;
    int t = threadIdx.x;
    float4 v = *reinterpret_cast<const float4*>(xr + t * 4);
    float s = v.x + v.y + v.z + v.w;
    float q = v.x*v.x + v.y*v.y + v.z*v.z + v.w*v.w;
    #pragma unroll
    for (int off = 1; off < 64; off <<= 1) {
        s += __shfl_xor(s, off);
        q += __shfl_xor(q, off);
    }
    __shared__ float red[8];
    if ((t & 63) == 0) { red[(t >> 6) * 2] = s; red[(t >> 6) * 2 + 1] = q; }
    __syncthreads();
    float sum = red[0] + red[2] + red[4] + red[6];
    float sq  = red[1] + red[3] + red[5] + red[7];
    float mu  = sum * (1.0f / D_MODEL);
    float var = sq * (1.0f / D_MODEL) - mu * mu;
    float rstd = rsqrtf(var + 1e-6f);
    float4 gg = *reinterpret_cast<const float4*>(g + t * 4);
    float4 bb = *reinterpret_cast<const float4*>(b + t * 4);
    U16x4 o{ f2bf((v.x - mu) * rstd * gg.x + bb.x),
             f2bf((v.y - mu) * rstd * gg.y + bb.y),
             f2bf((v.z - mu) * rstd * gg.z + bb.z),
             f2bf((v.w - mu) * rstd * gg.w + bb.w) };
    *reinterpret_cast<U16x4*>(out + (size_t)row * D_MODEL + t * 4) = o;
}

// ---------- GEMM: C[M,N] = A[M,K](bf16) @ W[N,K]^T(bf16) + bias ----------
// 2-deep counted-vmcnt pipeline (T4): never drains vmcnt to 0 in the loop.
#define EPI_BF16   0
#define EPI_RESF32 1
#define EPI_GELU   2

template<int EPI>
__global__ __launch_bounds__(256, 2) void gemm_bt(
    const u16* __restrict__ A, const u16* __restrict__ B,
    const float* __restrict__ bias, const float* __restrict__ res,
    u16* __restrict__ outb, float* __restrict__ outf,
    int M, int N, int K)
{
    __shared__ u16 As[2][128 * 64];
    __shared__ u16 Bs[2][128 * 64];
    const int t = threadIdx.x;
    const int lane = t & 63;
    const int w = t >> 6;
    const int lr = lane & 15, lg = lane >> 4;
    const int wrr = (w >> 1) * 64, wcc = (w & 1) * 64;
    const int brow = blockIdx.y * 128, bcol = blockIdx.x * 128;
    const u16* Ag = A + (size_t)brow * K;
    const u16* Bg = B + (size_t)bcol * K;

    f32x4 acc[4][4] = {};

    const int NT = K >> 6;   // always >= 16 here (K = 1024 or 4096)

    auto stage = [&](int buf, int kt) {
        const u16* ga = Ag + kt * 64;
        const u16* gb = Bg + kt * 64;
        u16* la = As[buf];
        u16* lb = Bs[buf];
        #pragma unroll
        for (int c = 0; c < 4; ++c) {
            int f = c * 256 + t;
            int row = f >> 3, slot = f & 7;
            int sg = slot ^ (row & 7);          // inverse-swizzled global source
            gld_lds16(ga + (size_t)row * K + sg * 8, la + f * 8);
            gld_lds16(gb + (size_t)row * K + sg * 8, lb + f * 8);
        }
    };

    auto compute = [&](int buf) {
        const u16* la = As[buf];
        const u16* lb = Bs[buf];
        bf16x8 af[4][2];
        #pragma unroll
        for (int mi = 0; mi < 4; ++mi) {
            int row = wrr + mi * 16 + lr;
            int base = row * 64;
            af[mi][0] = *reinterpret_cast<const bf16x8*>(la + base + ((0 + lg) ^ (row & 7)) * 8);
            af[mi][1] = *reinterpret_cast<const bf16x8*>(la + base + ((4 + lg) ^ (row & 7)) * 8);
        }
        __builtin_amdgcn_s_setprio(1);
        #pragma unroll
        for (int ni = 0; ni < 4; ++ni) {
            int row = wcc + ni * 16 + lr;
            int base = row * 64;
            bf16x8 b0 = *reinterpret_cast<const bf16x8*>(lb + base + ((0 + lg) ^ (row & 7)) * 8);
            bf16x8 b1 = *reinterpret_cast<const bf16x8*>(lb + base + ((4 + lg) ^ (row & 7)) * 8);
            #pragma unroll
            for (int mi = 0; mi < 4; ++mi) {
                acc[mi][ni] = mfma16(af[mi][0], b0, acc[mi][ni]);
                acc[mi][ni] = mfma16(af[mi][1], b1, acc[mi][ni]);
            }
        }
        __builtin_amdgcn_s_setprio(0);
    };

    // prologue: 2 tiles in flight, wait only for tile 0
    stage(0, 0);
    if (NT > 1) {
        stage(1, 1);
        asm volatile("s_waitcnt vmcnt(8)" ::: "memory");
    } else {
        asm volatile("s_waitcnt vmcnt(0)" ::: "memory");
    }
    __builtin_amdgcn_s_barrier();

    for (int kt = 0; kt < NT; ++kt) {
        compute(kt & 1);
        if (kt + 1 == NT) break;
        __builtin_amdgcn_s_barrier();          // all waves done reading buf[kt&1]
        if (kt + 2 < NT) {
            stage(kt & 1, kt + 2);             // refill just-freed buffer
            asm volatile("s_waitcnt vmcnt(8)" ::: "memory");   // tile kt+1 landed
        } else {
            asm volatile("s_waitcnt vmcnt(0)" ::: "memory");   // tail drain
        }
        __builtin_amdgcn_s_barrier();          // tile kt+1 visible to all
    }

    // epilogue
    #pragma unroll
    for (int mi = 0; mi < 4; ++mi) {
        int r0 = brow + wrr + mi * 16 + lg * 4;
        #pragma unroll
        for (int ni = 0; ni < 4; ++ni) {
            int c = bcol + wcc + ni * 16 + lr;
            float bv = bias[c];
            #pragma unroll
            for (int j = 0; j < 4; ++j) {
                float v = acc[mi][ni][j] + bv;
                size_t idx = (size_t)(r0 + j) * N + c;
                if constexpr (EPI == EPI_GELU) {
                    v = 0.5f * v * (1.0f + erff(v * 0.70710678118f));
                    outb[idx] = f2bf(v);
                } else if constexpr (EPI == EPI_RESF32) {
                    outf[idx] = v + res[idx];
                } else {
                    outb[idx] = f2bf(v);
                }
            }
        }
    }
}

// ---------- V transpose: QKV[token][2048+h*64+d] -> VT[(b,h)][d][s] ----------
__global__ __launch_bounds__(256) void vtrans(
    const u16* __restrict__ QKV, u16* __restrict__ VT)
{
    const int st = blockIdx.x * 64;
    const int bh = blockIdx.y;
    const int b = bh >> 4, h = bh & 15;
    const int lane = threadIdx.x & 63, w = threadIdx.x >> 6;
    const u16* src = QKV + ((size_t)(b * SEQ + st + lane)) * QKVS + 2048 + h * HD;
    u16* dst = VT + (size_t)bh * HD * SEQ + st;
    #pragma unroll
    for (int c = 0; c < 2; ++c) {
        int doct = w + c * 4;                 // 0..7
        bf16x8 v = ldg8(src + doct * 8);
        #pragma unroll
        for (int i = 0; i < 8; ++i)
            dst[(size_t)(doct * 8 + i) * SEQ + lane] = ((const u16*)&v)[i];
    }
}

// ---------- causal flash attention v4 (proven 77.9 us) ----------
// QBLK=64 (4 waves x 16 q-rows), KVBLK=64, double-buffered K/V via
// global_load_lds (swizzled). Static-max softmax (scores ~N(0,1):
// exp can't overflow f32): no running max, no rescale, no in-loop
// cross-lane reduces. Denominator reduced once after the KV loop.
// QK B-frag kv-mapping: kv = lr*4 + ni -> lane's 4 P values adjacent,
// packed with v_cvt_pk_bf16_f32 into one 8B LDS write.
#define QBLK  64
#define KVBLK 64

__global__ __launch_bounds__(256, 3) void attn4(
    const u16* __restrict__ QKV, const u16* __restrict__ VT,
    u16* __restrict__ O)
{
    __shared__ u16 Ks[2][64 * 64];    // [kv][d], swizzle key (kv>>2)&7
    __shared__ u16 Vs[2][64 * 64];    // [d][kv], swizzle key d&7
    __shared__ u16 Pl[4][16 * 72];    // per-wave P[q][kv], stride 72

    const int bx = (gridDim.x - 1) - blockIdx.x;   // heavy-first
    const int bh = blockIdx.y;
    const int b = bh >> 4, h = bh & 15;
    const int q0 = bx * QBLK;
    const int t = threadIdx.x;
    const int lane = t & 63, w = t >> 6;
    const int lr = lane & 15, lg = lane >> 4;

    const size_t rowbase = (size_t)b * SEQ;
    const u16* Qg = QKV + rowbase * QKVS + h * HD;
    const u16* Kg = Qg + 1024;
    const u16* Vg = VT + (size_t)bh * HD * SEQ;

    // Q fragments: wave w owns rows q0 + w*16 + {0..15}
    const u16* qp = Qg + (size_t)(q0 + w * 16 + lr) * QKVS;
    bf16x8 qf0 = ldg8(qp + lg * 8);
    bf16x8 qf1 = ldg8(qp + 32 + lg * 8);

    f32x4 o[4] = {};
    float lsum[4] = { 0.f, 0.f, 0.f, 0.f };

    const int ntiles = bx + 1;
    u16* Pw = Pl[w];
    const float SC = 0.125f * 1.44269504089f;   // 1/sqrt(64) * log2(e)

    auto stage = [&](int buf, int tt) {
        const int kv0 = tt * KVBLK;
        #pragma unroll
        for (int c = 0; c < 2; ++c) {
            int f = c * 256 + t;
            int row = f >> 3, slot = f & 7;
            int sgk = slot ^ ((row >> 2) & 7);   // K swizzle: read rows stride-4
            int sgv = slot ^ (row & 7);          // V swizzle: read rows stride-1
            gld_lds16(Kg + (size_t)(kv0 + row) * QKVS + sgk * 8, Ks[buf] + f * 8);
            gld_lds16(Vg + (size_t)row * SEQ + kv0 + sgv * 8, Vs[buf] + f * 8);
        }
    };

    stage(0, 0);
    __syncthreads();

    for (int tt = 0; tt < ntiles; ++tt) {
        const int buf = tt & 1;
        if (tt + 1 < ntiles) stage(buf ^ 1, tt + 1);
        const int kv0 = tt * KVBLK;

        // QK^T: s[ni], q-row = lg*4+j, kv-col = kv0 + lr*4 + ni
        f32x4 s[4] = {};
        {
            const u16* kb = Ks[buf];
            __builtin_amdgcn_s_setprio(1);
            #pragma unroll
            for (int ni = 0; ni < 4; ++ni) {
                int row = lr * 4 + ni;
                const u16* base = kb + row * 64;
                int key = (row >> 2) & 7;
                bf16x8 k0 = *reinterpret_cast<const bf16x8*>(base + ((0 + lg) ^ key) * 8);
                bf16x8 k1 = *reinterpret_cast<const bf16x8*>(base + ((4 + lg) ^ key) * 8);
                s[ni] = mfma16(qf0, k0, s[ni]);
                s[ni] = mfma16(qf1, k1, s[ni]);
            }
            __builtin_amdgcn_s_setprio(0);
        }

        // static-max softmax: p = exp2(s*SC); mask only on the diag tile
        const bool full = (tt + 1 < ntiles);
        #pragma unroll
        for (int j = 0; j < 4; ++j) {
            int qi = q0 + w * 16 + lg * 4 + j;
            float p0 = __builtin_amdgcn_exp2f(s[0][j] * SC);
            float p1 = __builtin_amdgcn_exp2f(s[1][j] * SC);
            float p2 = __builtin_amdgcn_exp2f(s[2][j] * SC);
            float p3 = __builtin_amdgcn_exp2f(s[3][j] * SC);
            if (!full) {
                int kvb = kv0 + lr * 4;
                p0 = (kvb     <= qi) ? p0 : 0.f;
                p1 = (kvb + 1 <= qi) ? p1 : 0.f;
                p2 = (kvb + 2 <= qi) ? p2 : 0.f;
                p3 = (kvb + 3 <= qi) ? p3 : 0.f;
            }
            lsum[j] += (p0 + p1) + (p2 + p3);
            uint2 pk = make_uint2(cvtpk_bf16(p0, p1), cvtpk_bf16(p2, p3));
            *reinterpret_cast<uint2*>(&Pw[(lg * 4 + j) * 72 + lr * 4]) = pk;
        }

        // PV: o[ni] += P[16x64] @ V[64x64]
        {
            bf16x8 pa0 = *reinterpret_cast<const bf16x8*>(Pw + lr * 72 + lg * 8);
            bf16x8 pa1 = *reinterpret_cast<const bf16x8*>(Pw + lr * 72 + 32 + lg * 8);
            const u16* vb = Vs[buf];
            __builtin_amdgcn_s_setprio(1);
            #pragma unroll
            for (int ni = 0; ni < 4; ++ni) {
                int row = ni * 16 + lr;
                const u16* base = vb + row * 64;
                bf16x8 v0 = *reinterpret_cast<const bf16x8*>(base + ((0 + lg) ^ (row & 7)) * 8);
                bf16x8 v1 = *reinterpret_cast<const bf16x8*>(base + ((4 + lg) ^ (row & 7)) * 8);
                o[ni] = mfma16(pa0, v0, o[ni]);
                o[ni] = mfma16(pa1, v1, o[ni]);
            }
            __builtin_amdgcn_s_setprio(0);
        }
        __syncthreads();
    }

    // reduce denominator across the 16 kv-lanes (same lg group)
    #pragma unroll
    for (int j = 0; j < 4; ++j) {
        float v = lsum[j];
        v += __shfl_xor(v, 1);
        v += __shfl_xor(v, 2);
        v += __shfl_xor(v, 4);
        v += __shfl_xor(v, 8);
        lsum[j] = v;
    }

    // normalize + store: O[row][h*64 + d]
    u16* Ob = O + (rowbase + q0 + w * 16) * D_MODEL + h * HD;
    #pragma unroll
    for (int j = 0; j < 4; ++j) {
        float inv = 1.0f / lsum[j];
        int r = (lg * 4 + j) * D_MODEL;
        #pragma unroll
        for (int ni = 0; ni < 4; ++ni)
            Ob[r + ni * 16 + lr] = f2bf(o[ni][j] * inv);
    }
}

// ---------- launch ----------
extern "C" void kernel_launch(void* const* d_in, const int* in_sizes, int n_in,
                              void* d_out, int out_size, void* d_ws, size_t ws_size,
                              hipStream_t stream)
{
    (void)in_sizes; (void)n_in; (void)out_size; (void)ws_size;
    const float* x   = (const float*)d_in[0];
    const float* Wq  = (const float*)d_in[2];
    const float* bq  = (const float*)d_in[3];
    const float* Wk  = (const float*)d_in[4];
    const float* bk  = (const float*)d_in[5];
    const float* Wv  = (const float*)d_in[6];
    const float* bv  = (const float*)d_in[7];
    const float* Wo  = (const float*)d_in[8];
    const float* bo  = (const float*)d_in[9];
    const float* g1  = (const float*)d_in[10];
    const float* be1 = (const float*)d_in[11];
    const float* g2  = (const float*)d_in[12];
    const float* be2 = (const float*)d_in[13];
    const float* W1  = (const float*)d_in[14];
    const float* b1  = (const float*)d_in[15];
    const float* W2  = (const float*)d_in[16];
    const float* b2  = (const float*)d_in[17];
    float* out = (float*)d_out;

    const size_t MM = 1 << 20;   // 1M elems
    u16* Wqkv_b = (u16*)d_ws;            // 3M u16 (Wq,Wk,Wv packed [3072][1024])
    u16* Wo_b = Wqkv_b + 3 * MM;
    u16* W1_b = Wo_b + MM;               // 4M
    u16* W2_b = W1_b + 4 * MM;           // 4M
    u16* hbuf = W2_b + 4 * MM;           // 4M (LN out; dead after its GEMM)
    u16* QKVb = hbuf + 4 * MM;           // 12M  [4096][3072]
    u16* ctx  = QKVb + 12 * MM;          // 4M
    u16* ffn1 = ctx + 4 * MM;            // 16M
    float* x2 = (float*)(ffn1 + 16 * MM);        // 4M f32
    float* bqkv = (float*)(x2 + 4 * MM);         // 3072 f32
    // VT aliases hbuf: LN1 output is dead once the QKV GEMM completes,
    // and attention finishes before LN2 rewrites hbuf (stream-serial).
    u16* VTb = hbuf;                     // 4M u16 [32 bh][64 d][2048 s]

    // fused weight converts: 12M elems -> contiguous bf16 region at d_ws
    cvt_all<<<12 * MM / 1024, 256, 0, stream>>>(Wq, Wk, Wv, Wo, W1, W2, Wqkv_b);

    // pack QKV bias
    hipMemcpyAsync(bqkv,        bq, D_MODEL * sizeof(float), hipMemcpyDeviceToDevice, stream);
    hipMemcpyAsync(bqkv + 1024, bk, D_MODEL * sizeof(float), hipMemcpyDeviceToDevice, stream);
    hipMemcpyAsync(bqkv + 2048, bv, D_MODEL * sizeof(float), hipMemcpyDeviceToDevice, stream);

    // LN1
    ln_bf16<<<ROWS, 256, 0, stream>>>(x, g1, be1, hbuf);

    dim3 blk(256);
    // fused QKV projection: [4096,1024] @ [3072,1024]^T
    dim3 gqkv(QKVS / 128, ROWS / 128);        // (24, 32)
    gemm_bt<EPI_BF16><<<gqkv, blk, 0, stream>>>(hbuf, Wqkv_b, bqkv, nullptr, QKVb, nullptr, ROWS, QKVS, D_MODEL);

    // V transpose (hbuf is dead now; VTb aliases it)
    vtrans<<<dim3(SEQ / 64, BATCH * NH), blk, 0, stream>>>(QKVb, VTb);

    // attention
    dim3 ga(SEQ / QBLK, BATCH * NH);          // (32, 32)
    attn4<<<ga, blk, 0, stream>>>(QKVb, VTb, ctx);

    dim3 gq(D_MODEL / 128, ROWS / 128);       // (8, 32)
    gemm_bt<EPI_RESF32><<<gq, blk, 0, stream>>>(ctx, Wo_b, bo, x, nullptr, x2, ROWS, D_MODEL, D_MODEL);

    // LN2
    ln_bf16<<<ROWS, 256, 0, stream>>>(x2, g2, be2, hbuf);

    dim3 gf1(D_FF / 128, ROWS / 128);         // (32, 32)
    gemm_bt<EPI_GELU><<<gf1, blk, 0, stream>>>(hbuf, W1_b, b1, nullptr, ffn1, nullptr, ROWS, D_FF, D_MODEL);

    gemm_bt<EPI_RESF32><<<gq, blk, 0, stream>>>(ffn1, W2_b, b2, x2, nullptr, out, ROWS, D_MODEL, D_FF);
}

// Round 7
// 290.954 us; speedup vs baseline: 1.5232x; 1.0063x over previous
//
#include <hip/hip_runtime.h>
#include <hip/hip_bf16.h>
#include <cstdint>
#include <cstddef>

typedef unsigned short u16;
typedef __bf16 bf16x8 __attribute__((ext_vector_type(8)));
typedef float f32x4 __attribute__((ext_vector_type(4)));

#define D_MODEL 1024
#define D_FF    4096
#define BATCH   2
#define SEQ     2048
#define NH      16
#define HD      64
#define ROWS    (BATCH*SEQ)   // 4096
#define QKVS    3072          // packed QKV row stride

// ---------- helpers ----------
__device__ __forceinline__ u16 f2bf(float f) {
    union { float f; uint32_t u; } v; v.f = f;
    uint32_t u = v.u;
    u += 0x7FFF + ((u >> 16) & 1);   // RNE
    return (u16)(u >> 16);
}

__device__ __forceinline__ uint32_t cvtpk_bf16(float lo, float hi) {
    uint32_t r;
    asm("v_cvt_pk_bf16_f32 %0, %1, %2" : "=v"(r) : "v"(lo), "v"(hi));
    return r;
}

__device__ __forceinline__ bf16x8 ldg8(const u16* p) {
    return *reinterpret_cast<const bf16x8*>(p);
}

__device__ __forceinline__ f32x4 mfma16(bf16x8 a, bf16x8 b, f32x4 c) {
    return __builtin_amdgcn_mfma_f32_16x16x32_bf16(a, b, c, 0, 0, 0);
}

__device__ __forceinline__ void gld_lds16(const void* g, void* l) {
    __builtin_amdgcn_global_load_lds(
        (const __attribute__((address_space(1))) void*)g,
        (__attribute__((address_space(3))) void*)l, 16, 0, 0);
}

struct alignas(8) U16x4 { u16 x, y, z, w; };

// ---------- fused f32 -> bf16 convert for all weights ----------
__global__ void cvt_all(const float* __restrict__ s0, const float* __restrict__ s1,
                        const float* __restrict__ s2, const float* __restrict__ s3,
                        const float* __restrict__ s4, const float* __restrict__ s5,
                        u16* __restrict__ out)
{
    const size_t MM1 = 1 << 20;
    size_t i = ((size_t)blockIdx.x * 256 + threadIdx.x) * 4;
    const float* src; size_t off;
    if      (i <     MM1) { src = s0; off = i; }
    else if (i < 2 * MM1) { src = s1; off = i - MM1; }
    else if (i < 3 * MM1) { src = s2; off = i - 2 * MM1; }
    else if (i < 4 * MM1) { src = s3; off = i - 3 * MM1; }
    else if (i < 8 * MM1) { src = s4; off = i - 4 * MM1; }
    else                  { src = s5; off = i - 8 * MM1; }
    float4 f = *reinterpret_cast<const float4*>(src + off);
    U16x4 o{ f2bf(f.x), f2bf(f.y), f2bf(f.z), f2bf(f.w) };
    *reinterpret_cast<U16x4*>(out + i) = o;
}

// ---------- LayerNorm (f32 in, bf16 out) ----------
__global__ __launch_bounds__(256) void ln_bf16(
    const float* __restrict__ x, const float* __restrict__ g,
    const float* __restrict__ b, u16* __restrict__ out)
{
    int row = blockIdx.x;
    const float* xr = x + (size_t)row * D_MODEL;
    int t = threadIdx.x;
    float4 v = *reinterpret_cast<const float4*>(xr + t * 4);
    float s = v.x + v.y + v.z + v.w;
    float q = v.x*v.x + v.y*v.y + v.z*v.z + v.w*v.w;
    #pragma unroll
    for (int off = 1; off < 64; off <<= 1) {
        s += __shfl_xor(s, off);
        q += __shfl_xor(q, off);
    }
    __shared__ float red[8];
    if ((t & 63) == 0) { red[(t >> 6) * 2] = s; red[(t >> 6) * 2 + 1] = q; }
    __syncthreads();
    float sum = red[0] + red[2] + red[4] + red[6];
    float sq  = red[1] + red[3] + red[5] + red[7];
    float mu  = sum * (1.0f / D_MODEL);
    float var = sq * (1.0f / D_MODEL) - mu * mu;
    float rstd = rsqrtf(var + 1e-6f);
    float4 gg = *reinterpret_cast<const float4*>(g + t * 4);
    float4 bb = *reinterpret_cast<const float4*>(b + t * 4);
    U16x4 o{ f2bf((v.x - mu) * rstd * gg.x + bb.x),
             f2bf((v.y - mu) * rstd * gg.y + bb.y),
             f2bf((v.z - mu) * rstd * gg.z + bb.z),
             f2bf((v.w - mu) * rstd * gg.w + bb.w) };
    *reinterpret_cast<U16x4*>(out + (size_t)row * D_MODEL + t * 4) = o;
}

#define EPI_BF16   0
#define EPI_RESF32 1
#define EPI_GELU   2

// ---------- GEMM 256x256, 8-phase schedule (T2+T3+T4+T5) ----------
// 8 waves (2Mx4N), BK=64, 128 KiB LDS double-buffer. Per K-tile: 4 phases,
// each {ds_read subtile || stage 2 chunks of next tile -> BAR -> 16 MFMA
// (setprio) -> BAR}. Counted vmcnt(2) once per K-tile at phase 0 -- the 2
// next-tile loads stay in flight across the tile boundary (never drain to 0
// in the main loop). Requires grid % 8 == 0 (XCD-bijective swizzle).
template<int EPI>
__global__ __launch_bounds__(512, 1) void gemm256(
    const u16* __restrict__ A, const u16* __restrict__ B,
    const float* __restrict__ bias, const float* __restrict__ res,
    u16* __restrict__ outb, float* __restrict__ outf,
    int M, int N, int K)
{
    __shared__ u16 As[2][256 * 64];
    __shared__ u16 Bs[2][256 * 64];
    const int t = threadIdx.x;            // 0..511
    const int lane = t & 63, w = t >> 6;  // 8 waves
    const int lr = lane & 15, lg = lane >> 4;
    const int wr = w >> 2, wc = w & 3;    // 2 x 4 wave grid

    // XCD-aware bijective swizzle (nwg % 8 == 0 for all shapes used)
    const int gw  = N >> 8;
    const int nwg = gridDim.x;
    const int cpx = nwg >> 3;
    const int swz = ((int)blockIdx.x & 7) * cpx + ((int)blockIdx.x >> 3);
    const int by = swz / gw, bx = swz % gw;
    const int brow = by * 256, bcol = bx * 256;

    const u16* Ag = A + (size_t)brow * K;
    const u16* Bg = B + (size_t)bcol * K;

    f32x4 acc[8][4] = {};
    const int NT = K >> 6;

    // chunk c: 0-3 = A rows c*64.., 4-7 = B rows (c-4)*64..
    // per chunk each of 512 threads issues one 16B gld_lds:
    // row = cc*64 + (t>>3), slot = t&7, source col-octet = slot ^ (row&7)
    auto stage2 = [&](int buf, int kt, int p) {
        #pragma unroll
        for (int c2 = 0; c2 < 2; ++c2) {
            int c = p * 2 + c2;
            const u16* g = (c < 4) ? Ag : Bg;
            u16* l = (c < 4) ? As[buf] : Bs[buf];
            int cc = c & 3;
            int row = cc * 64 + (t >> 3);
            int sg = (t & 7) ^ (row & 7);
            gld_lds16(g + (size_t)row * K + kt * 64 + sg * 8, l + cc * 4096 + t * 8);
        }
    };

    // prologue: tile 0 fully staged (8 loads outstanding)
    #pragma unroll
    for (int p = 0; p < 4; ++p) stage2(0, 0, p);

    for (int kt = 0; kt < NT; ++kt) {
        const int buf = kt & 1;
        const u16* la = As[buf];
        const u16* lb = Bs[buf];
        bf16x8 areg[4][2], breg[2][2][2];

        auto loadA = [&](int qm) {
            #pragma unroll
            for (int f = 0; f < 4; ++f) {
                int row = wr * 128 + qm * 64 + f * 16 + lr;
                const u16* bp = la + row * 64;
                int key = row & 7;
                areg[f][0] = ldg8(bp + ((0 + lg) ^ key) * 8);
                areg[f][1] = ldg8(bp + ((4 + lg) ^ key) * 8);
            }
        };
        auto loadB = [&](int qn) {
            #pragma unroll
            for (int f = 0; f < 2; ++f) {
                int row = wc * 64 + qn * 32 + f * 16 + lr;
                const u16* bp = lb + row * 64;
                int key = row & 7;
                breg[qn][f][0] = ldg8(bp + ((0 + lg) ^ key) * 8);
                breg[qn][f][1] = ldg8(bp + ((4 + lg) ^ key) * 8);
            }
        };

        #pragma unroll
        for (int p = 0; p < 4; ++p) {
            const int qm = p >> 1, qn = p & 1;
            // phases >=1 read their new fragments before the barrier
            // (current tile resident since phase 0's barrier)
            if (p == 1) loadB(1);
            if (p == 2) loadA(1);
            if (kt + 1 < NT) stage2(buf ^ 1, kt + 1, p);
            if (p == 0) {
                if (kt + 1 < NT)
                    asm volatile("s_waitcnt vmcnt(2)" ::: "memory");  // tile kt landed; 2 of kt+1 in flight
                else
                    asm volatile("s_waitcnt vmcnt(0)" ::: "memory");  // last tile: drain
            }
            __builtin_amdgcn_s_barrier();
            if (p == 0) { loadA(0); loadB(0); }   // after barrier: all waves' staging visible
            __builtin_amdgcn_s_setprio(1);
            #pragma unroll
            for (int mi = 0; mi < 4; ++mi) {
                #pragma unroll
                for (int fn = 0; fn < 2; ++fn) {
                    acc[qm * 4 + mi][qn * 2 + fn] =
                        mfma16(areg[mi][0], breg[qn][fn][0], acc[qm * 4 + mi][qn * 2 + fn]);
                    acc[qm * 4 + mi][qn * 2 + fn] =
                        mfma16(areg[mi][1], breg[qn][fn][1], acc[qm * 4 + mi][qn * 2 + fn]);
                }
            }
            __builtin_amdgcn_s_setprio(0);
            __builtin_amdgcn_s_barrier();
        }
    }

    // epilogue
    #pragma unroll
    for (int mi = 0; mi < 8; ++mi) {
        int r0 = brow + wr * 128 + mi * 16 + lg * 4;
        #pragma unroll
        for (int ni = 0; ni < 4; ++ni) {
            int c = bcol + wc * 64 + ni * 16 + lr;
            float bv = bias[c];
            #pragma unroll
            for (int j = 0; j < 4; ++j) {
                float v = acc[mi][ni][j] + bv;
                size_t idx = (size_t)(r0 + j) * N + c;
                if constexpr (EPI == EPI_GELU) {
                    v = 0.5f * v * (1.0f + erff(v * 0.70710678118f));
                    outb[idx] = f2bf(v);
                } else if constexpr (EPI == EPI_RESF32) {
                    outf[idx] = v + res[idx];
                } else {
                    outb[idx] = f2bf(v);
                }
            }
        }
    }
}

// ---------- GEMM 128x128, 2-deep counted-vmcnt (for small-N shapes) ----------
template<int EPI>
__global__ __launch_bounds__(256, 2) void gemm_bt(
    const u16* __restrict__ A, const u16* __restrict__ B,
    const float* __restrict__ bias, const float* __restrict__ res,
    u16* __restrict__ outb, float* __restrict__ outf,
    int M, int N, int K)
{
    __shared__ u16 As[2][128 * 64];
    __shared__ u16 Bs[2][128 * 64];
    const int t = threadIdx.x;
    const int lane = t & 63;
    const int w = t >> 6;
    const int lr = lane & 15, lg = lane >> 4;
    const int wrr = (w >> 1) * 64, wcc = (w & 1) * 64;
    const int brow = blockIdx.y * 128, bcol = blockIdx.x * 128;
    const u16* Ag = A + (size_t)brow * K;
    const u16* Bg = B + (size_t)bcol * K;

    f32x4 acc[4][4] = {};

    const int NT = K >> 6;

    auto stage = [&](int buf, int kt) {
        const u16* ga = Ag + kt * 64;
        const u16* gb = Bg + kt * 64;
        u16* la = As[buf];
        u16* lb = Bs[buf];
        #pragma unroll
        for (int c = 0; c < 4; ++c) {
            int f = c * 256 + t;
            int row = f >> 3, slot = f & 7;
            int sg = slot ^ (row & 7);
            gld_lds16(ga + (size_t)row * K + sg * 8, la + f * 8);
            gld_lds16(gb + (size_t)row * K + sg * 8, lb + f * 8);
        }
    };

    auto compute = [&](int buf) {
        const u16* la = As[buf];
        const u16* lb = Bs[buf];
        bf16x8 af[4][2];
        #pragma unroll
        for (int mi = 0; mi < 4; ++mi) {
            int row = wrr + mi * 16 + lr;
            int base = row * 64;
            af[mi][0] = *reinterpret_cast<const bf16x8*>(la + base + ((0 + lg) ^ (row & 7)) * 8);
            af[mi][1] = *reinterpret_cast<const bf16x8*>(la + base + ((4 + lg) ^ (row & 7)) * 8);
        }
        __builtin_amdgcn_s_setprio(1);
        #pragma unroll
        for (int ni = 0; ni < 4; ++ni) {
            int row = wcc + ni * 16 + lr;
            int base = row * 64;
            bf16x8 b0 = *reinterpret_cast<const bf16x8*>(lb + base + ((0 + lg) ^ (row & 7)) * 8);
            bf16x8 b1 = *reinterpret_cast<const bf16x8*>(lb + base + ((4 + lg) ^ (row & 7)) * 8);
            #pragma unroll
            for (int mi = 0; mi < 4; ++mi) {
                acc[mi][ni] = mfma16(af[mi][0], b0, acc[mi][ni]);
                acc[mi][ni] = mfma16(af[mi][1], b1, acc[mi][ni]);
            }
        }
        __builtin_amdgcn_s_setprio(0);
    };

    stage(0, 0);
    if (NT > 1) {
        stage(1, 1);
        asm volatile("s_waitcnt vmcnt(8)" ::: "memory");
    } else {
        asm volatile("s_waitcnt vmcnt(0)" ::: "memory");
    }
    __builtin_amdgcn_s_barrier();

    for (int kt = 0; kt < NT; ++kt) {
        compute(kt & 1);
        if (kt + 1 == NT) break;
        __builtin_amdgcn_s_barrier();
        if (kt + 2 < NT) {
            stage(kt & 1, kt + 2);
            asm volatile("s_waitcnt vmcnt(8)" ::: "memory");
        } else {
            asm volatile("s_waitcnt vmcnt(0)" ::: "memory");
        }
        __builtin_amdgcn_s_barrier();
    }

    #pragma unroll
    for (int mi = 0; mi < 4; ++mi) {
        int r0 = brow + wrr + mi * 16 + lg * 4;
        #pragma unroll
        for (int ni = 0; ni < 4; ++ni) {
            int c = bcol + wcc + ni * 16 + lr;
            float bv = bias[c];
            #pragma unroll
            for (int j = 0; j < 4; ++j) {
                float v = acc[mi][ni][j] + bv;
                size_t idx = (size_t)(r0 + j) * N + c;
                if constexpr (EPI == EPI_GELU) {
                    v = 0.5f * v * (1.0f + erff(v * 0.70710678118f));
                    outb[idx] = f2bf(v);
                } else if constexpr (EPI == EPI_RESF32) {
                    outf[idx] = v + res[idx];
                } else {
                    outb[idx] = f2bf(v);
                }
            }
        }
    }
}

// ---------- V transpose: QKV[token][2048+h*64+d] -> VT[(b,h)][d][s] ----------
__global__ __launch_bounds__(256) void vtrans(
    const u16* __restrict__ QKV, u16* __restrict__ VT)
{
    const int st = blockIdx.x * 64;
    const int bh = blockIdx.y;
    const int b = bh >> 4, h = bh & 15;
    const int lane = threadIdx.x & 63, w = threadIdx.x >> 6;
    const u16* src = QKV + ((size_t)(b * SEQ + st + lane)) * QKVS + 2048 + h * HD;
    u16* dst = VT + (size_t)bh * HD * SEQ + st;
    #pragma unroll
    for (int c = 0; c < 2; ++c) {
        int doct = w + c * 4;
        bf16x8 v = ldg8(src + doct * 8);
        #pragma unroll
        for (int i = 0; i < 8; ++i)
            dst[(size_t)(doct * 8 + i) * SEQ + lane] = ((const u16*)&v)[i];
    }
}

// ---------- causal flash attention v4 (proven 77.9 us) ----------
#define QBLK  64
#define KVBLK 64

__global__ __launch_bounds__(256, 3) void attn4(
    const u16* __restrict__ QKV, const u16* __restrict__ VT,
    u16* __restrict__ O)
{
    __shared__ u16 Ks[2][64 * 64];
    __shared__ u16 Vs[2][64 * 64];
    __shared__ u16 Pl[4][16 * 72];

    const int bx = (gridDim.x - 1) - blockIdx.x;
    const int bh = blockIdx.y;
    const int b = bh >> 4, h = bh & 15;
    const int q0 = bx * QBLK;
    const int t = threadIdx.x;
    const int lane = t & 63, w = t >> 6;
    const int lr = lane & 15, lg = lane >> 4;

    const size_t rowbase = (size_t)b * SEQ;
    const u16* Qg = QKV + rowbase * QKVS + h * HD;
    const u16* Kg = Qg + 1024;
    const u16* Vg = VT + (size_t)bh * HD * SEQ;

    const u16* qp = Qg + (size_t)(q0 + w * 16 + lr) * QKVS;
    bf16x8 qf0 = ldg8(qp + lg * 8);
    bf16x8 qf1 = ldg8(qp + 32 + lg * 8);

    f32x4 o[4] = {};
    float lsum[4] = { 0.f, 0.f, 0.f, 0.f };

    const int ntiles = bx + 1;
    u16* Pw = Pl[w];
    const float SC = 0.125f * 1.44269504089f;

    auto stage = [&](int buf, int tt) {
        const int kv0 = tt * KVBLK;
        #pragma unroll
        for (int c = 0; c < 2; ++c) {
            int f = c * 256 + t;
            int row = f >> 3, slot = f & 7;
            int sgk = slot ^ ((row >> 2) & 7);
            int sgv = slot ^ (row & 7);
            gld_lds16(Kg + (size_t)(kv0 + row) * QKVS + sgk * 8, Ks[buf] + f * 8);
            gld_lds16(Vg + (size_t)row * SEQ + kv0 + sgv * 8, Vs[buf] + f * 8);
        }
    };

    stage(0, 0);
    __syncthreads();

    for (int tt = 0; tt < ntiles; ++tt) {
        const int buf = tt & 1;
        if (tt + 1 < ntiles) stage(buf ^ 1, tt + 1);
        const int kv0 = tt * KVBLK;

        f32x4 s[4] = {};
        {
            const u16* kb = Ks[buf];
            __builtin_amdgcn_s_setprio(1);
            #pragma unroll
            for (int ni = 0; ni < 4; ++ni) {
                int row = lr * 4 + ni;
                const u16* base = kb + row * 64;
                int key = (row >> 2) & 7;
                bf16x8 k0 = *reinterpret_cast<const bf16x8*>(base + ((0 + lg) ^ key) * 8);
                bf16x8 k1 = *reinterpret_cast<const bf16x8*>(base + ((4 + lg) ^ key) * 8);
                s[ni] = mfma16(qf0, k0, s[ni]);
                s[ni] = mfma16(qf1, k1, s[ni]);
            }
            __builtin_amdgcn_s_setprio(0);
        }

        const bool full = (tt + 1 < ntiles);
        #pragma unroll
        for (int j = 0; j < 4; ++j) {
            int qi = q0 + w * 16 + lg * 4 + j;
            float p0 = __builtin_amdgcn_exp2f(s[0][j] * SC);
            float p1 = __builtin_amdgcn_exp2f(s[1][j] * SC);
            float p2 = __builtin_amdgcn_exp2f(s[2][j] * SC);
            float p3 = __builtin_amdgcn_exp2f(s[3][j] * SC);
            if (!full) {
                int kvb = kv0 + lr * 4;
                p0 = (kvb     <= qi) ? p0 : 0.f;
                p1 = (kvb + 1 <= qi) ? p1 : 0.f;
                p2 = (kvb + 2 <= qi) ? p2 : 0.f;
                p3 = (kvb + 3 <= qi) ? p3 : 0.f;
            }
            lsum[j] += (p0 + p1) + (p2 + p3);
            uint2 pk = make_uint2(cvtpk_bf16(p0, p1), cvtpk_bf16(p2, p3));
            *reinterpret_cast<uint2*>(&Pw[(lg * 4 + j) * 72 + lr * 4]) = pk;
        }

        {
            bf16x8 pa0 = *reinterpret_cast<const bf16x8*>(Pw + lr * 72 + lg * 8);
            bf16x8 pa1 = *reinterpret_cast<const bf16x8*>(Pw + lr * 72 + 32 + lg * 8);
            const u16* vb = Vs[buf];
            __builtin_amdgcn_s_setprio(1);
            #pragma unroll
            for (int ni = 0; ni < 4; ++ni) {
                int row = ni * 16 + lr;
                const u16* base = vb + row * 64;
                bf16x8 v0 = *reinterpret_cast<const bf16x8*>(base + ((0 + lg) ^ (row & 7)) * 8);
                bf16x8 v1 = *reinterpret_cast<const bf16x8*>(base + ((4 + lg) ^ (row & 7)) * 8);
                o[ni] = mfma16(pa0, v0, o[ni]);
                o[ni] = mfma16(pa1, v1, o[ni]);
            }
            __builtin_amdgcn_s_setprio(0);
        }
        __syncthreads();
    }

    #pragma unroll
    for (int j = 0; j < 4; ++j) {
        float v = lsum[j];
        v += __shfl_xor(v, 1);
        v += __shfl_xor(v, 2);
        v += __shfl_xor(v, 4);
        v += __shfl_xor(v, 8);
        lsum[j] = v;
    }

    u16* Ob = O + (rowbase + q0 + w * 16) * D_MODEL + h * HD;
    #pragma unroll
    for (int j = 0; j < 4; ++j) {
        float inv = 1.0f / lsum[j];
        int r = (lg * 4 + j) * D_MODEL;
        #pragma unroll
        for (int ni = 0; ni < 4; ++ni)
            Ob[r + ni * 16 + lr] = f2bf(o[ni][j] * inv);
    }
}

// ---------- launch ----------
extern "C" void kernel_launch(void* const* d_in, const int* in_sizes, int n_in,
                              void* d_out, int out_size, void* d_ws, size_t ws_size,
                              hipStream_t stream)
{
    (void)in_sizes; (void)n_in; (void)out_size; (void)ws_size;
    const float* x   = (const float*)d_in[0];
    const float* Wq  = (const float*)d_in[2];
    const float* bq  = (const float*)d_in[3];
    const float* Wk  = (const float*)d_in[4];
    const float* bk  = (const float*)d_in[5];
    const float* Wv  = (const float*)d_in[6];
    const float* bv  = (const float*)d_in[7];
    const float* Wo  = (const float*)d_in[8];
    const float* bo  = (const float*)d_in[9];
    const float* g1  = (const float*)d_in[10];
    const float* be1 = (const float*)d_in[11];
    const float* g2  = (const float*)d_in[12];
    const float* be2 = (const float*)d_in[13];
    const float* W1  = (const float*)d_in[14];
    const float* b1  = (const float*)d_in[15];
    const float* W2  = (const float*)d_in[16];
    const float* b2  = (const float*)d_in[17];
    float* out = (float*)d_out;

    const size_t MM = 1 << 20;   // 1M elems
    u16* Wqkv_b = (u16*)d_ws;            // 3M u16 (Wq,Wk,Wv packed [3072][1024])
    u16* Wo_b = Wqkv_b + 3 * MM;
    u16* W1_b = Wo_b + MM;               // 4M
    u16* W2_b = W1_b + 4 * MM;           // 4M
    u16* hbuf = W2_b + 4 * MM;           // 4M (LN out; dead after its GEMM)
    u16* QKVb = hbuf + 4 * MM;           // 12M  [4096][3072]
    u16* ctx  = QKVb + 12 * MM;          // 4M
    u16* ffn1 = ctx + 4 * MM;            // 16M
    float* x2 = (float*)(ffn1 + 16 * MM);        // 4M f32
    float* bqkv = (float*)(x2 + 4 * MM);         // 3072 f32
    u16* VTb = hbuf;                     // aliases hbuf (dead after QKV GEMM)

    // fused weight converts
    cvt_all<<<12 * MM / 1024, 256, 0, stream>>>(Wq, Wk, Wv, Wo, W1, W2, Wqkv_b);

    // pack QKV bias
    hipMemcpyAsync(bqkv,        bq, D_MODEL * sizeof(float), hipMemcpyDeviceToDevice, stream);
    hipMemcpyAsync(bqkv + 1024, bk, D_MODEL * sizeof(float), hipMemcpyDeviceToDevice, stream);
    hipMemcpyAsync(bqkv + 2048, bv, D_MODEL * sizeof(float), hipMemcpyDeviceToDevice, stream);

    // LN1
    ln_bf16<<<ROWS, 256, 0, stream>>>(x, g1, be1, hbuf);

    // fused QKV projection: [4096,1024] @ [3072,1024]^T  -- 256x256 8-phase
    gemm256<EPI_BF16><<<(ROWS / 256) * (QKVS / 256), 512, 0, stream>>>(
        hbuf, Wqkv_b, bqkv, nullptr, QKVb, nullptr, ROWS, QKVS, D_MODEL);

    // V transpose (hbuf dead now)
    vtrans<<<dim3(SEQ / 64, BATCH * NH), 256, 0, stream>>>(QKVb, VTb);

    // attention
    dim3 ga(SEQ / QBLK, BATCH * NH);
    attn4<<<ga, 256, 0, stream>>>(QKVb, VTb, ctx);

    // Wo projection + residual (N=1024 -> 128x128 kernel)
    dim3 gq(D_MODEL / 128, ROWS / 128);
    gemm_bt<EPI_RESF32><<<gq, 256, 0, stream>>>(ctx, Wo_b, bo, x, nullptr, x2, ROWS, D_MODEL, D_MODEL);

    // LN2
    ln_bf16<<<ROWS, 256, 0, stream>>>(x2, g2, be2, hbuf);

    // FFN1 + GELU: [4096,1024] @ [4096,1024]^T -- 256x256 8-phase
    gemm256<EPI_GELU><<<(ROWS / 256) * (D_FF / 256), 512, 0, stream>>>(
        hbuf, W1_b, b1, nullptr, ffn1, nullptr, ROWS, D_FF, D_MODEL);

    // FFN2 + residual (N=1024 -> 128x128 kernel)
    gemm_bt<EPI_RESF32><<<gq, 256, 0, stream>>>(ffn1, W2_b, b2, x2, nullptr, out, ROWS, D_MODEL, D_FF);
}

// Round 8
// 281.706 us; speedup vs baseline: 1.5732x; 1.0328x over previous
//
#include <hip/hip_runtime.h>
#include <hip/hip_bf16.h>
#include <cstdint>
#include <cstddef>

typedef unsigned short u16;
typedef __bf16 bf16x8 __attribute__((ext_vector_type(8)));
typedef float f32x4 __attribute__((ext_vector_type(4)));

#define D_MODEL 1024
#define D_FF    4096
#define BATCH   2
#define SEQ     2048
#define NH      16
#define HD      64
#define ROWS    (BATCH*SEQ)   // 4096
#define QKVS    3072          // packed QKV row stride

// ---------- helpers ----------
__device__ __forceinline__ u16 f2bf(float f) {
    union { float f; uint32_t u; } v; v.f = f;
    uint32_t u = v.u;
    u += 0x7FFF + ((u >> 16) & 1);   // RNE
    return (u16)(u >> 16);
}

__device__ __forceinline__ uint32_t cvtpk_bf16(float lo, float hi) {
    uint32_t r;
    asm("v_cvt_pk_bf16_f32 %0, %1, %2" : "=v"(r) : "v"(lo), "v"(hi));
    return r;
}

__device__ __forceinline__ bf16x8 ldg8(const u16* p) {
    return *reinterpret_cast<const bf16x8*>(p);
}

__device__ __forceinline__ f32x4 mfma16(bf16x8 a, bf16x8 b, f32x4 c) {
    return __builtin_amdgcn_mfma_f32_16x16x32_bf16(a, b, c, 0, 0, 0);
}

__device__ __forceinline__ void gld_lds16(const void* g, void* l) {
    __builtin_amdgcn_global_load_lds(
        (const __attribute__((address_space(1))) void*)g,
        (__attribute__((address_space(3))) void*)l, 16, 0, 0);
}

struct alignas(8) U16x4 { u16 x, y, z, w; };

// ---------- fused f32 -> bf16 convert for all weights ----------
__global__ void cvt_all(const float* __restrict__ s0, const float* __restrict__ s1,
                        const float* __restrict__ s2, const float* __restrict__ s3,
                        const float* __restrict__ s4, const float* __restrict__ s5,
                        u16* __restrict__ out)
{
    const size_t MM1 = 1 << 20;
    size_t i = ((size_t)blockIdx.x * 256 + threadIdx.x) * 4;
    const float* src; size_t off;
    if      (i <     MM1) { src = s0; off = i; }
    else if (i < 2 * MM1) { src = s1; off = i - MM1; }
    else if (i < 3 * MM1) { src = s2; off = i - 2 * MM1; }
    else if (i < 4 * MM1) { src = s3; off = i - 3 * MM1; }
    else if (i < 8 * MM1) { src = s4; off = i - 4 * MM1; }
    else                  { src = s5; off = i - 8 * MM1; }
    float4 f = *reinterpret_cast<const float4*>(src + off);
    U16x4 o{ f2bf(f.x), f2bf(f.y), f2bf(f.z), f2bf(f.w) };
    *reinterpret_cast<U16x4*>(out + i) = o;
}

// ---------- LayerNorm (f32 in, bf16 out) ----------
__global__ __launch_bounds__(256) void ln_bf16(
    const float* __restrict__ x, const float* __restrict__ g,
    const float* __restrict__ b, u16* __restrict__ out)
{
    int row = blockIdx.x;
    const float* xr = x + (size_t)row * D_MODEL;
    int t = threadIdx.x;
    float4 v = *reinterpret_cast<const float4*>(xr + t * 4);
    float s = v.x + v.y + v.z + v.w;
    float q = v.x*v.x + v.y*v.y + v.z*v.z + v.w*v.w;
    #pragma unroll
    for (int off = 1; off < 64; off <<= 1) {
        s += __shfl_xor(s, off);
        q += __shfl_xor(q, off);
    }
    __shared__ float red[8];
    if ((t & 63) == 0) { red[(t >> 6) * 2] = s; red[(t >> 6) * 2 + 1] = q; }
    __syncthreads();
    float sum = red[0] + red[2] + red[4] + red[6];
    float sq  = red[1] + red[3] + red[5] + red[7];
    float mu  = sum * (1.0f / D_MODEL);
    float var = sq * (1.0f / D_MODEL) - mu * mu;
    float rstd = rsqrtf(var + 1e-6f);
    float4 gg = *reinterpret_cast<const float4*>(g + t * 4);
    float4 bb = *reinterpret_cast<const float4*>(b + t * 4);
    U16x4 o{ f2bf((v.x - mu) * rstd * gg.x + bb.x),
             f2bf((v.y - mu) * rstd * gg.y + bb.y),
             f2bf((v.z - mu) * rstd * gg.z + bb.z),
             f2bf((v.w - mu) * rstd * gg.w + bb.w) };
    *reinterpret_cast<U16x4*>(out + (size_t)row * D_MODEL + t * 4) = o;
}

#define EPI_BF16   0
#define EPI_RESF32 1
#define EPI_GELU   2
#define EPI_PART   3

// ---------- GEMM 128x128, 2-deep counted-vmcnt pipeline ----------
// K = local K this block reduces over; KS = row stride of A/B.
// blockIdx.z selects a K-partition (EPI_PART writes f32 partial at z*M*N).
template<int EPI>
__global__ __launch_bounds__(256, 2) void gemm_bt(
    const u16* __restrict__ A, const u16* __restrict__ B,
    const float* __restrict__ bias, const float* __restrict__ res,
    u16* __restrict__ outb, float* __restrict__ outf,
    int M, int N, int K, int KS)
{
    __shared__ u16 As[2][128 * 64];
    __shared__ u16 Bs[2][128 * 64];
    const int t = threadIdx.x;
    const int lane = t & 63;
    const int w = t >> 6;
    const int lr = lane & 15, lg = lane >> 4;
    const int wrr = (w >> 1) * 64, wcc = (w & 1) * 64;
    const int brow = blockIdx.y * 128, bcol = blockIdx.x * 128;
    const int kz = blockIdx.z;
    const u16* Ag = A + (size_t)brow * KS + (size_t)kz * K;
    const u16* Bg = B + (size_t)bcol * KS + (size_t)kz * K;

    f32x4 acc[4][4] = {};

    const int NT = K >> 6;

    auto stage = [&](int buf, int kt) {
        const u16* ga = Ag + kt * 64;
        const u16* gb = Bg + kt * 64;
        u16* la = As[buf];
        u16* lb = Bs[buf];
        #pragma unroll
        for (int c = 0; c < 4; ++c) {
            int f = c * 256 + t;
            int row = f >> 3, slot = f & 7;
            int sg = slot ^ (row & 7);
            gld_lds16(ga + (size_t)row * KS + sg * 8, la + f * 8);
            gld_lds16(gb + (size_t)row * KS + sg * 8, lb + f * 8);
        }
    };

    auto compute = [&](int buf) {
        const u16* la = As[buf];
        const u16* lb = Bs[buf];
        bf16x8 af[4][2];
        #pragma unroll
        for (int mi = 0; mi < 4; ++mi) {
            int row = wrr + mi * 16 + lr;
            int base = row * 64;
            af[mi][0] = *reinterpret_cast<const bf16x8*>(la + base + ((0 + lg) ^ (row & 7)) * 8);
            af[mi][1] = *reinterpret_cast<const bf16x8*>(la + base + ((4 + lg) ^ (row & 7)) * 8);
        }
        __builtin_amdgcn_s_setprio(1);
        #pragma unroll
        for (int ni = 0; ni < 4; ++ni) {
            int row = wcc + ni * 16 + lr;
            int base = row * 64;
            bf16x8 b0 = *reinterpret_cast<const bf16x8*>(lb + base + ((0 + lg) ^ (row & 7)) * 8);
            bf16x8 b1 = *reinterpret_cast<const bf16x8*>(lb + base + ((4 + lg) ^ (row & 7)) * 8);
            #pragma unroll
            for (int mi = 0; mi < 4; ++mi) {
                acc[mi][ni] = mfma16(af[mi][0], b0, acc[mi][ni]);
                acc[mi][ni] = mfma16(af[mi][1], b1, acc[mi][ni]);
            }
        }
        __builtin_amdgcn_s_setprio(0);
    };

    stage(0, 0);
    if (NT > 1) {
        stage(1, 1);
        asm volatile("s_waitcnt vmcnt(8)" ::: "memory");
    } else {
        asm volatile("s_waitcnt vmcnt(0)" ::: "memory");
    }
    __builtin_amdgcn_s_barrier();

    for (int kt = 0; kt < NT; ++kt) {
        compute(kt & 1);
        if (kt + 1 == NT) break;
        __builtin_amdgcn_s_barrier();
        if (kt + 2 < NT) {
            stage(kt & 1, kt + 2);
            asm volatile("s_waitcnt vmcnt(8)" ::: "memory");
        } else {
            asm volatile("s_waitcnt vmcnt(0)" ::: "memory");
        }
        __builtin_amdgcn_s_barrier();
    }

    #pragma unroll
    for (int mi = 0; mi < 4; ++mi) {
        int r0 = brow + wrr + mi * 16 + lg * 4;
        #pragma unroll
        for (int ni = 0; ni < 4; ++ni) {
            int c = bcol + wcc + ni * 16 + lr;
            float bv = 0.f;
            if constexpr (EPI != EPI_PART) bv = bias[c];
            #pragma unroll
            for (int j = 0; j < 4; ++j) {
                float v = acc[mi][ni][j] + bv;
                size_t idx = (size_t)(r0 + j) * N + c;
                if constexpr (EPI == EPI_GELU) {
                    v = 0.5f * v * (1.0f + erff(v * 0.70710678118f));
                    outb[idx] = f2bf(v);
                } else if constexpr (EPI == EPI_RESF32) {
                    outf[idx] = v + res[idx];
                } else if constexpr (EPI == EPI_PART) {
                    outf[idx + (size_t)kz * M * N] = v;
                } else {
                    outb[idx] = f2bf(v);
                }
            }
        }
    }
}

// ---------- FFN2 partial reduce: out = p0 + p1 + bias + residual ----------
__global__ void ffn2_reduce(const float* __restrict__ p,
                            const float* __restrict__ b2,
                            const float* __restrict__ x2,
                            float* __restrict__ out)
{
    size_t i = ((size_t)blockIdx.x * 256 + threadIdx.x) * 4;
    float4 a0 = *reinterpret_cast<const float4*>(p + i);
    float4 a1 = *reinterpret_cast<const float4*>(p + (size_t)ROWS * D_MODEL + i);
    float4 r  = *reinterpret_cast<const float4*>(x2 + i);
    float4 bb = *reinterpret_cast<const float4*>(b2 + (i & (D_MODEL - 1)));
    float4 o;
    o.x = a0.x + a1.x + r.x + bb.x;
    o.y = a0.y + a1.y + r.y + bb.y;
    o.z = a0.z + a1.z + r.z + bb.z;
    o.w = a0.w + a1.w + r.w + bb.w;
    *reinterpret_cast<float4*>(out + i) = o;
}

// ---------- V transpose via LDS (coalesced both sides) ----------
__global__ __launch_bounds__(256) void vtrans(
    const u16* __restrict__ QKV, u16* __restrict__ VT)
{
    __shared__ u16 tile[64][72];   // +8 pad
    const int st = blockIdx.x * 64;
    const int bh = blockIdx.y;
    const int b = bh >> 4, h = bh & 15;
    const int t = threadIdx.x;

    #pragma unroll
    for (int c = 0; c < 2; ++c) {
        int tok = c * 32 + (t >> 3);
        int d0 = (t & 7) * 8;
        bf16x8 v = ldg8(QKV + ((size_t)(b * SEQ + st + tok)) * QKVS + 2048 + h * HD + d0);
        *reinterpret_cast<bf16x8*>(&tile[tok][d0]) = v;
    }
    __syncthreads();
    u16* dst = VT + (size_t)bh * HD * SEQ + st;
    #pragma unroll
    for (int c = 0; c < 2; ++c) {
        int d = c * 32 + (t >> 3);
        int tok0 = (t & 7) * 8;
        u16 vals[8];
        #pragma unroll
        for (int i = 0; i < 8; ++i) vals[i] = tile[tok0 + i][d];
        *reinterpret_cast<bf16x8*>(dst + (size_t)d * SEQ + tok0) =
            *reinterpret_cast<const bf16x8*>(vals);
    }
}

// ---------- causal flash attention v6: counted-vmcnt double buffer ----------
// Same math as attn4 (static-max softmax), but raw s_barrier + vmcnt(4):
// tile tt+1's staging (issued last iteration) is waited on; tile tt+2's
// 4 loads stay in flight across the barrier -- never vmcnt(0) in the loop.
#define QBLK  64
#define KVBLK 64

__global__ __launch_bounds__(256, 3) void attn6(
    const u16* __restrict__ QKV, const u16* __restrict__ VT,
    u16* __restrict__ O)
{
    __shared__ u16 Ks[2][64 * 64];    // [kv][d], swizzle key (kv>>2)&7
    __shared__ u16 Vs[2][64 * 64];    // [d][kv], swizzle key d&7
    __shared__ u16 Pl[4][16 * 72];    // per-wave P[q][kv], stride 72

    const int bx = (gridDim.x - 1) - blockIdx.x;   // heavy-first
    const int bh = blockIdx.y;
    const int b = bh >> 4, h = bh & 15;
    const int q0 = bx * QBLK;
    const int t = threadIdx.x;
    const int lane = t & 63, w = t >> 6;
    const int lr = lane & 15, lg = lane >> 4;

    const size_t rowbase = (size_t)b * SEQ;
    const u16* Qg = QKV + rowbase * QKVS + h * HD;
    const u16* Kg = Qg + 1024;
    const u16* Vg = VT + (size_t)bh * HD * SEQ;

    const u16* qp = Qg + (size_t)(q0 + w * 16 + lr) * QKVS;
    bf16x8 qf0 = ldg8(qp + lg * 8);
    bf16x8 qf1 = ldg8(qp + 32 + lg * 8);

    f32x4 o[4] = {};
    float lsum[4] = { 0.f, 0.f, 0.f, 0.f };

    const int ntiles = bx + 1;
    u16* Pw = Pl[w];
    const float SC = 0.125f * 1.44269504089f;   // 1/sqrt(64) * log2(e)

    auto stage = [&](int buf, int tt) {
        const int kv0 = tt * KVBLK;
        #pragma unroll
        for (int c = 0; c < 2; ++c) {
            int f = c * 256 + t;
            int row = f >> 3, slot = f & 7;
            int sgk = slot ^ ((row >> 2) & 7);
            int sgv = slot ^ (row & 7);
            gld_lds16(Kg + (size_t)(kv0 + row) * QKVS + sgk * 8, Ks[buf] + f * 8);
            gld_lds16(Vg + (size_t)row * SEQ + kv0 + sgv * 8, Vs[buf] + f * 8);
        }
    };

    // prologue: tiles 0 and 1 in flight (tile 1 always in-range: SEQ=2048)
    stage(0, 0);
    stage(1, 1);
    asm volatile("s_waitcnt vmcnt(4)" ::: "memory");   // tile 0 landed
    __builtin_amdgcn_s_barrier();

    for (int tt = 0; tt < ntiles; ++tt) {
        const int buf = tt & 1;
        const int kv0 = tt * KVBLK;

        // QK^T: s[ni], q-row = lg*4+j, kv-col = kv0 + lr*4 + ni
        f32x4 s[4] = {};
        {
            const u16* kb = Ks[buf];
            __builtin_amdgcn_s_setprio(1);
            #pragma unroll
            for (int ni = 0; ni < 4; ++ni) {
                int row = lr * 4 + ni;
                const u16* base = kb + row * 64;
                int key = (row >> 2) & 7;
                bf16x8 k0 = *reinterpret_cast<const bf16x8*>(base + ((0 + lg) ^ key) * 8);
                bf16x8 k1 = *reinterpret_cast<const bf16x8*>(base + ((4 + lg) ^ key) * 8);
                s[ni] = mfma16(qf0, k0, s[ni]);
                s[ni] = mfma16(qf1, k1, s[ni]);
            }
            __builtin_amdgcn_s_setprio(0);
        }

        // static-max softmax: p = exp2(s*SC); mask only on the diag tile
        const bool full = (tt + 1 < ntiles);
        #pragma unroll
        for (int j = 0; j < 4; ++j) {
            int qi = q0 + w * 16 + lg * 4 + j;
            float p0 = __builtin_amdgcn_exp2f(s[0][j] * SC);
            float p1 = __builtin_amdgcn_exp2f(s[1][j] * SC);
            float p2 = __builtin_amdgcn_exp2f(s[2][j] * SC);
            float p3 = __builtin_amdgcn_exp2f(s[3][j] * SC);
            if (!full) {
                int kvb = kv0 + lr * 4;
                p0 = (kvb     <= qi) ? p0 : 0.f;
                p1 = (kvb + 1 <= qi) ? p1 : 0.f;
                p2 = (kvb + 2 <= qi) ? p2 : 0.f;
                p3 = (kvb + 3 <= qi) ? p3 : 0.f;
            }
            lsum[j] += (p0 + p1) + (p2 + p3);
            uint2 pk = make_uint2(cvtpk_bf16(p0, p1), cvtpk_bf16(p2, p3));
            *reinterpret_cast<uint2*>(&Pw[(lg * 4 + j) * 72 + lr * 4]) = pk;
        }

        // PV: o[ni] += P[16x64] @ V[64x64]
        {
            bf16x8 pa0 = *reinterpret_cast<const bf16x8*>(Pw + lr * 72 + lg * 8);
            bf16x8 pa1 = *reinterpret_cast<const bf16x8*>(Pw + lr * 72 + 32 + lg * 8);
            const u16* vb = Vs[buf];
            __builtin_amdgcn_s_setprio(1);
            #pragma unroll
            for (int ni = 0; ni < 4; ++ni) {
                int row = ni * 16 + lr;
                const u16* base = vb + row * 64;
                bf16x8 v0 = *reinterpret_cast<const bf16x8*>(base + ((0 + lg) ^ (row & 7)) * 8);
                bf16x8 v1 = *reinterpret_cast<const bf16x8*>(base + ((4 + lg) ^ (row & 7)) * 8);
                o[ni] = mfma16(pa0, v0, o[ni]);
                o[ni] = mfma16(pa1, v1, o[ni]);
            }
            __builtin_amdgcn_s_setprio(0);
        }

        if (tt + 1 == ntiles) break;
        __builtin_amdgcn_s_barrier();           // all waves done reading buf
        if (tt + 2 < ntiles) {
            stage(buf, tt + 2);                 // refill just-freed buffer
            asm volatile("s_waitcnt vmcnt(4)" ::: "memory");  // tile tt+1 landed
        } else {
            asm volatile("s_waitcnt vmcnt(0)" ::: "memory");  // tail drain
        }
        __builtin_amdgcn_s_barrier();           // tile tt+1 visible to all
    }

    // reduce denominator across the 16 kv-lanes (same lg group)
    #pragma unroll
    for (int j = 0; j < 4; ++j) {
        float v = lsum[j];
        v += __shfl_xor(v, 1);
        v += __shfl_xor(v, 2);
        v += __shfl_xor(v, 4);
        v += __shfl_xor(v, 8);
        lsum[j] = v;
    }

    // normalize + store
    u16* Ob = O + (rowbase + q0 + w * 16) * D_MODEL + h * HD;
    #pragma unroll
    for (int j = 0; j < 4; ++j) {
        float inv = 1.0f / lsum[j];
        int r = (lg * 4 + j) * D_MODEL;
        #pragma unroll
        for (int ni = 0; ni < 4; ++ni)
            Ob[r + ni * 16 + lr] = f2bf(o[ni][j] * inv);
    }
}

// ---------- launch ----------
extern "C" void kernel_launch(void* const* d_in, const int* in_sizes, int n_in,
                              void* d_out, int out_size, void* d_ws, size_t ws_size,
                              hipStream_t stream)
{
    (void)in_sizes; (void)n_in; (void)out_size; (void)ws_size;
    const float* x   = (const float*)d_in[0];
    const float* Wq  = (const float*)d_in[2];
    const float* bq  = (const float*)d_in[3];
    const float* Wk  = (const float*)d_in[4];
    const float* bk  = (const float*)d_in[5];
    const float* Wv  = (const float*)d_in[6];
    const float* bv  = (const float*)d_in[7];
    const float* Wo  = (const float*)d_in[8];
    const float* bo  = (const float*)d_in[9];
    const float* g1  = (const float*)d_in[10];
    const float* be1 = (const float*)d_in[11];
    const float* g2  = (const float*)d_in[12];
    const float* be2 = (const float*)d_in[13];
    const float* W1  = (const float*)d_in[14];
    const float* b1  = (const float*)d_in[15];
    const float* W2  = (const float*)d_in[16];
    const float* b2  = (const float*)d_in[17];
    float* out = (float*)d_out;

    const size_t MM = 1 << 20;   // 1M elems
    u16* Wqkv_b = (u16*)d_ws;            // 3M u16 (Wq,Wk,Wv packed [3072][1024])
    u16* Wo_b = Wqkv_b + 3 * MM;
    u16* W1_b = Wo_b + MM;               // 4M
    u16* W2_b = W1_b + 4 * MM;           // 4M
    u16* hbuf = W2_b + 4 * MM;           // 4M (LN out; dead after its GEMM)
    u16* QKVb = hbuf + 4 * MM;           // 12M  [4096][3072]
    u16* ctx  = QKVb + 12 * MM;          // 4M
    u16* ffn1 = ctx + 4 * MM;            // 16M
    float* x2 = (float*)(ffn1 + 16 * MM);        // 4M f32
    float* bqkv = (float*)(x2 + 4 * MM);         // 3072 f32
    u16* VTb = hbuf;                     // aliases hbuf (dead after QKV GEMM)
    // FFN2 partials alias QKVb+ctx (both dead after Wo GEMM): 2 x 16MB f32
    float* fpart = (float*)QKVb;

    // fused weight converts
    cvt_all<<<12 * MM / 1024, 256, 0, stream>>>(Wq, Wk, Wv, Wo, W1, W2, Wqkv_b);

    // pack QKV bias
    hipMemcpyAsync(bqkv,        bq, D_MODEL * sizeof(float), hipMemcpyDeviceToDevice, stream);
    hipMemcpyAsync(bqkv + 1024, bk, D_MODEL * sizeof(float), hipMemcpyDeviceToDevice, stream);
    hipMemcpyAsync(bqkv + 2048, bv, D_MODEL * sizeof(float), hipMemcpyDeviceToDevice, stream);

    // LN1
    ln_bf16<<<ROWS, 256, 0, stream>>>(x, g1, be1, hbuf);

    // fused QKV projection: [4096,1024] @ [3072,1024]^T  (768 blocks, 2/CU)
    dim3 gqkv(QKVS / 128, ROWS / 128);
    gemm_bt<EPI_BF16><<<gqkv, 256, 0, stream>>>(hbuf, Wqkv_b, bqkv, nullptr,
                                                QKVb, nullptr, ROWS, QKVS, 1024, 1024);

    // V transpose (hbuf dead now)
    vtrans<<<dim3(SEQ / 64, BATCH * NH), 256, 0, stream>>>(QKVb, VTb);

    // attention
    dim3 ga(SEQ / QBLK, BATCH * NH);
    attn6<<<ga, 256, 0, stream>>>(QKVb, VTb, ctx);

    // Wo projection + residual
    dim3 gq(D_MODEL / 128, ROWS / 128);
    gemm_bt<EPI_RESF32><<<gq, 256, 0, stream>>>(ctx, Wo_b, bo, x, nullptr, x2,
                                                ROWS, D_MODEL, 1024, 1024);

    // LN2
    ln_bf16<<<ROWS, 256, 0, stream>>>(x2, g2, be2, hbuf);

    // FFN1 + GELU: [4096,1024] @ [4096,1024]^T  (1024 blocks, 2/CU)
    dim3 gf1(D_FF / 128, ROWS / 128);
    gemm_bt<EPI_GELU><<<gf1, 256, 0, stream>>>(hbuf, W1_b, b1, nullptr, ffn1, nullptr,
                                               ROWS, D_FF, 1024, 1024);

    // FFN2 split-K2: partials (512 blocks, 2/CU), then fused reduce+bias+res
    dim3 gf2(D_MODEL / 128, ROWS / 128, 2);
    gemm_bt<EPI_PART><<<gf2, 256, 0, stream>>>(ffn1, W2_b, nullptr, nullptr,
                                               nullptr, fpart, ROWS, D_MODEL, 2048, 4096);
    ffn2_reduce<<<(ROWS * D_MODEL) / 1024, 256, 0, stream>>>(fpart, b2, x2, out);
}

// Round 9
// 254.803 us; speedup vs baseline: 1.7393x; 1.1056x over previous
//
#include <hip/hip_runtime.h>
#include <hip/hip_bf16.h>
#include <cstdint>
#include <cstddef>

typedef unsigned short u16;
typedef __bf16 bf16x8 __attribute__((ext_vector_type(8)));
typedef float f32x4 __attribute__((ext_vector_type(4)));

#define D_MODEL 1024
#define D_FF    4096
#define BATCH   2
#define SEQ     2048
#define NH      16
#define HD      64
#define ROWS    (BATCH*SEQ)   // 4096
#define QKVS    3072          // packed QKV row stride

// ---------- helpers ----------
__device__ __forceinline__ u16 f2bf(float f) {
    union { float f; uint32_t u; } v; v.f = f;
    uint32_t u = v.u;
    u += 0x7FFF + ((u >> 16) & 1);   // RNE
    return (u16)(u >> 16);
}

__device__ __forceinline__ uint32_t cvtpk_bf16(float lo, float hi) {
    uint32_t r;
    asm("v_cvt_pk_bf16_f32 %0, %1, %2" : "=v"(r) : "v"(lo), "v"(hi));
    return r;
}

__device__ __forceinline__ bf16x8 ldg8(const u16* p) {
    return *reinterpret_cast<const bf16x8*>(p);
}

__device__ __forceinline__ f32x4 mfma16(bf16x8 a, bf16x8 b, f32x4 c) {
    return __builtin_amdgcn_mfma_f32_16x16x32_bf16(a, b, c, 0, 0, 0);
}

__device__ __forceinline__ void gld_lds16(const void* g, void* l) {
    __builtin_amdgcn_global_load_lds(
        (const __attribute__((address_space(1))) void*)g,
        (__attribute__((address_space(3))) void*)l, 16, 0, 0);
}

struct alignas(8) U16x4 { u16 x, y, z, w; };

// ---------- fused f32 -> bf16 convert for all weights ----------
__global__ void cvt_all(const float* __restrict__ s0, const float* __restrict__ s1,
                        const float* __restrict__ s2, const float* __restrict__ s3,
                        const float* __restrict__ s4, const float* __restrict__ s5,
                        u16* __restrict__ out)
{
    const size_t MM1 = 1 << 20;
    size_t i = ((size_t)blockIdx.x * 256 + threadIdx.x) * 4;
    const float* src; size_t off;
    if      (i <     MM1) { src = s0; off = i; }
    else if (i < 2 * MM1) { src = s1; off = i - MM1; }
    else if (i < 3 * MM1) { src = s2; off = i - 2 * MM1; }
    else if (i < 4 * MM1) { src = s3; off = i - 3 * MM1; }
    else if (i < 8 * MM1) { src = s4; off = i - 4 * MM1; }
    else                  { src = s5; off = i - 8 * MM1; }
    float4 f = *reinterpret_cast<const float4*>(src + off);
    U16x4 o{ f2bf(f.x), f2bf(f.y), f2bf(f.z), f2bf(f.w) };
    *reinterpret_cast<U16x4*>(out + i) = o;
}

// ---------- LayerNorm (f32 in, bf16 out) ----------
__global__ __launch_bounds__(256) void ln_bf16(
    const float* __restrict__ x, const float* __restrict__ g,
    const float* __restrict__ b, u16* __restrict__ out)
{
    int row = blockIdx.x;
    const float* xr = x + (size_t)row * D_MODEL;
    int t = threadIdx.x;
    float4 v = *reinterpret_cast<const float4*>(xr + t * 4);
    float s = v.x + v.y + v.z + v.w;
    float q = v.x*v.x + v.y*v.y + v.z*v.z + v.w*v.w;
    #pragma unroll
    for (int off = 1; off < 64; off <<= 1) {
        s += __shfl_xor(s, off);
        q += __shfl_xor(q, off);
    }
    __shared__ float red[8];
    if ((t & 63) == 0) { red[(t >> 6) * 2] = s; red[(t >> 6) * 2 + 1] = q; }
    __syncthreads();
    float sum = red[0] + red[2] + red[4] + red[6];
    float sq  = red[1] + red[3] + red[5] + red[7];
    float mu  = sum * (1.0f / D_MODEL);
    float var = sq * (1.0f / D_MODEL) - mu * mu;
    float rstd = rsqrtf(var + 1e-6f);
    float4 gg = *reinterpret_cast<const float4*>(g + t * 4);
    float4 bb = *reinterpret_cast<const float4*>(b + t * 4);
    U16x4 o{ f2bf((v.x - mu) * rstd * gg.x + bb.x),
             f2bf((v.y - mu) * rstd * gg.y + bb.y),
             f2bf((v.z - mu) * rstd * gg.z + bb.z),
             f2bf((v.w - mu) * rstd * gg.w + bb.w) };
    *reinterpret_cast<U16x4*>(out + (size_t)row * D_MODEL + t * 4) = o;
}

#define EPI_BF16   0
#define EPI_RESF32 1
#define EPI_GELU   2
#define EPI_PART   3

// ---------- GEMM 256x256 v2: 4-phase, reads-before-barrier, deep staging ----------
// 8 waves (2Mx4N), BK=64, 128 KiB LDS double-buffer. Per K-tile 4 phases:
// {issue ds_reads -> BAR -> 16 MFMA (setprio) -> BAR}. Staging for tile kt+2
// is bunched at P3 (after the post-MFMA barrier proves all reads of `cur`
// are complete), giving a full iteration of latency slack; vmcnt(8) keeps
// those 8 loads in flight -- never drains mid-loop.
template<int EPI>
__global__ __launch_bounds__(512, 1) void gemm256(
    const u16* __restrict__ A, const u16* __restrict__ B,
    const float* __restrict__ bias, const float* __restrict__ res,
    u16* __restrict__ outb, float* __restrict__ outf,
    int M, int N, int K)
{
    __shared__ u16 As[2][256 * 64];
    __shared__ u16 Bs[2][256 * 64];
    const int t = threadIdx.x;            // 0..511
    const int lane = t & 63, w = t >> 6;  // 8 waves
    const int lr = lane & 15, lg = lane >> 4;
    const int wr = w >> 2, wc = w & 3;    // 2 x 4 wave grid

    // XCD-aware bijective swizzle (nwg % 8 == 0)
    const int gw  = N >> 8;
    const int nwg = gridDim.x;
    const int cpx = nwg >> 3;
    const int swz = ((int)blockIdx.x & 7) * cpx + ((int)blockIdx.x >> 3);
    const int by = swz / gw, bx = swz % gw;
    const int brow = by * 256, bcol = bx * 256;

    const u16* Ag = A + (size_t)brow * K;
    const u16* Bg = B + (size_t)bcol * K;

    f32x4 acc[8][4] = {};
    const int NT = K >> 6;

    auto stageAll = [&](int buf, int kt) {
        #pragma unroll
        for (int c = 0; c < 8; ++c) {
            const u16* g = (c < 4) ? Ag : Bg;
            u16* l = (c < 4) ? As[buf] : Bs[buf];
            int cc = c & 3;
            int row = cc * 64 + (t >> 3);
            int sg = (t & 7) ^ (row & 7);
            gld_lds16(g + (size_t)row * K + kt * 64 + sg * 8, l + cc * 4096 + t * 8);
        }
    };

    bf16x8 areg[4][2], breg[2][2][2];

    auto loadA = [&](const u16* la, int qm) {
        #pragma unroll
        for (int f = 0; f < 4; ++f) {
            int row = wr * 128 + qm * 64 + f * 16 + lr;
            const u16* bp = la + row * 64;
            int key = row & 7;
            areg[f][0] = ldg8(bp + ((0 + lg) ^ key) * 8);
            areg[f][1] = ldg8(bp + ((4 + lg) ^ key) * 8);
        }
    };
    auto loadB = [&](const u16* lb, int qn) {
        #pragma unroll
        for (int f = 0; f < 2; ++f) {
            int row = wc * 64 + qn * 32 + f * 16 + lr;
            const u16* bp = lb + row * 64;
            int key = row & 7;
            breg[qn][f][0] = ldg8(bp + ((0 + lg) ^ key) * 8);
            breg[qn][f][1] = ldg8(bp + ((4 + lg) ^ key) * 8);
        }
    };
    auto mmaQ = [&](int qm, int qn) {
        __builtin_amdgcn_s_setprio(1);
        #pragma unroll
        for (int mi = 0; mi < 4; ++mi) {
            #pragma unroll
            for (int fn = 0; fn < 2; ++fn) {
                acc[qm * 4 + mi][qn * 2 + fn] =
                    mfma16(areg[mi][0], breg[qn][fn][0], acc[qm * 4 + mi][qn * 2 + fn]);
                acc[qm * 4 + mi][qn * 2 + fn] =
                    mfma16(areg[mi][1], breg[qn][fn][1], acc[qm * 4 + mi][qn * 2 + fn]);
            }
        }
        __builtin_amdgcn_s_setprio(0);
    };

    // prologue: tiles 0 and 1 fully staged (NT >= 2 always: K >= 1024)
    stageAll(0, 0);
    stageAll(1, 1);
    asm volatile("s_waitcnt vmcnt(8)" ::: "memory");   // tile 0 landed, tile 1 in flight
    __builtin_amdgcn_s_barrier();

    for (int kt = 0; kt < NT; ++kt) {
        const int cur = kt & 1;
        const u16* la = As[cur];
        const u16* lb = Bs[cur];
        // P0
        loadA(la, 0); loadB(lb, 0);
        __builtin_amdgcn_s_barrier();
        mmaQ(0, 0);
        __builtin_amdgcn_s_barrier();
        // P1
        loadB(lb, 1);
        __builtin_amdgcn_s_barrier();
        mmaQ(0, 1);
        __builtin_amdgcn_s_barrier();
        // P2
        loadA(la, 1);
        __builtin_amdgcn_s_barrier();
        mmaQ(1, 0);
        __builtin_amdgcn_s_barrier();
        // P3 (fragments already resident)
        mmaQ(1, 1);
        if (kt + 1 == NT) break;
        __builtin_amdgcn_s_barrier();       // all waves' reads of cur complete
        if (kt + 2 < NT) {
            stageAll(cur, kt + 2);          // refill just-freed buffer
            asm volatile("s_waitcnt vmcnt(8)" ::: "memory");   // tile kt+1 landed
        } else {
            asm volatile("s_waitcnt vmcnt(0)" ::: "memory");   // tail drain
        }
        __builtin_amdgcn_s_barrier();       // tile kt+1 visible to all
    }

    // epilogue
    #pragma unroll
    for (int mi = 0; mi < 8; ++mi) {
        int r0 = brow + wr * 128 + mi * 16 + lg * 4;
        #pragma unroll
        for (int ni = 0; ni < 4; ++ni) {
            int c = bcol + wc * 64 + ni * 16 + lr;
            float bv = bias[c];
            #pragma unroll
            for (int j = 0; j < 4; ++j) {
                float v = acc[mi][ni][j] + bv;
                size_t idx = (size_t)(r0 + j) * N + c;
                if constexpr (EPI == EPI_GELU) {
                    v = 0.5f * v * (1.0f + erff(v * 0.70710678118f));
                    outb[idx] = f2bf(v);
                } else if constexpr (EPI == EPI_RESF32) {
                    outf[idx] = v + res[idx];
                } else {
                    outb[idx] = f2bf(v);
                }
            }
        }
    }
}

// ---------- GEMM 128x128, 2-deep counted-vmcnt pipeline ----------
template<int EPI>
__global__ __launch_bounds__(256, 2) void gemm_bt(
    const u16* __restrict__ A, const u16* __restrict__ B,
    const float* __restrict__ bias, const float* __restrict__ res,
    u16* __restrict__ outb, float* __restrict__ outf,
    int M, int N, int K, int KS)
{
    __shared__ u16 As[2][128 * 64];
    __shared__ u16 Bs[2][128 * 64];
    const int t = threadIdx.x;
    const int lane = t & 63;
    const int w = t >> 6;
    const int lr = lane & 15, lg = lane >> 4;
    const int wrr = (w >> 1) * 64, wcc = (w & 1) * 64;
    const int brow = blockIdx.y * 128, bcol = blockIdx.x * 128;
    const int kz = blockIdx.z;
    const u16* Ag = A + (size_t)brow * KS + (size_t)kz * K;
    const u16* Bg = B + (size_t)bcol * KS + (size_t)kz * K;

    f32x4 acc[4][4] = {};

    const int NT = K >> 6;

    auto stage = [&](int buf, int kt) {
        const u16* ga = Ag + kt * 64;
        const u16* gb = Bg + kt * 64;
        u16* la = As[buf];
        u16* lb = Bs[buf];
        #pragma unroll
        for (int c = 0; c < 4; ++c) {
            int f = c * 256 + t;
            int row = f >> 3, slot = f & 7;
            int sg = slot ^ (row & 7);
            gld_lds16(ga + (size_t)row * KS + sg * 8, la + f * 8);
            gld_lds16(gb + (size_t)row * KS + sg * 8, lb + f * 8);
        }
    };

    auto compute = [&](int buf) {
        const u16* la = As[buf];
        const u16* lb = Bs[buf];
        bf16x8 af[4][2];
        #pragma unroll
        for (int mi = 0; mi < 4; ++mi) {
            int row = wrr + mi * 16 + lr;
            int base = row * 64;
            af[mi][0] = *reinterpret_cast<const bf16x8*>(la + base + ((0 + lg) ^ (row & 7)) * 8);
            af[mi][1] = *reinterpret_cast<const bf16x8*>(la + base + ((4 + lg) ^ (row & 7)) * 8);
        }
        __builtin_amdgcn_s_setprio(1);
        #pragma unroll
        for (int ni = 0; ni < 4; ++ni) {
            int row = wcc + ni * 16 + lr;
            int base = row * 64;
            bf16x8 b0 = *reinterpret_cast<const bf16x8*>(lb + base + ((0 + lg) ^ (row & 7)) * 8);
            bf16x8 b1 = *reinterpret_cast<const bf16x8*>(lb + base + ((4 + lg) ^ (row & 7)) * 8);
            #pragma unroll
            for (int mi = 0; mi < 4; ++mi) {
                acc[mi][ni] = mfma16(af[mi][0], b0, acc[mi][ni]);
                acc[mi][ni] = mfma16(af[mi][1], b1, acc[mi][ni]);
            }
        }
        __builtin_amdgcn_s_setprio(0);
    };

    stage(0, 0);
    if (NT > 1) {
        stage(1, 1);
        asm volatile("s_waitcnt vmcnt(8)" ::: "memory");
    } else {
        asm volatile("s_waitcnt vmcnt(0)" ::: "memory");
    }
    __builtin_amdgcn_s_barrier();

    for (int kt = 0; kt < NT; ++kt) {
        compute(kt & 1);
        if (kt + 1 == NT) break;
        __builtin_amdgcn_s_barrier();
        if (kt + 2 < NT) {
            stage(kt & 1, kt + 2);
            asm volatile("s_waitcnt vmcnt(8)" ::: "memory");
        } else {
            asm volatile("s_waitcnt vmcnt(0)" ::: "memory");
        }
        __builtin_amdgcn_s_barrier();
    }

    #pragma unroll
    for (int mi = 0; mi < 4; ++mi) {
        int r0 = brow + wrr + mi * 16 + lg * 4;
        #pragma unroll
        for (int ni = 0; ni < 4; ++ni) {
            int c = bcol + wcc + ni * 16 + lr;
            float bv = 0.f;
            if constexpr (EPI != EPI_PART) bv = bias[c];
            #pragma unroll
            for (int j = 0; j < 4; ++j) {
                float v = acc[mi][ni][j] + bv;
                size_t idx = (size_t)(r0 + j) * N + c;
                if constexpr (EPI == EPI_GELU) {
                    v = 0.5f * v * (1.0f + erff(v * 0.70710678118f));
                    outb[idx] = f2bf(v);
                } else if constexpr (EPI == EPI_RESF32) {
                    outf[idx] = v + res[idx];
                } else if constexpr (EPI == EPI_PART) {
                    outf[idx + (size_t)kz * M * N] = v;
                } else {
                    outb[idx] = f2bf(v);
                }
            }
        }
    }
}

// ---------- FFN2 partial reduce: out = p0 + p1 + bias + residual ----------
__global__ void ffn2_reduce(const float* __restrict__ p,
                            const float* __restrict__ b2,
                            const float* __restrict__ x2,
                            float* __restrict__ out)
{
    size_t i = ((size_t)blockIdx.x * 256 + threadIdx.x) * 4;
    float4 a0 = *reinterpret_cast<const float4*>(p + i);
    float4 a1 = *reinterpret_cast<const float4*>(p + (size_t)ROWS * D_MODEL + i);
    float4 r  = *reinterpret_cast<const float4*>(x2 + i);
    float4 bb = *reinterpret_cast<const float4*>(b2 + (i & (D_MODEL - 1)));
    float4 o;
    o.x = a0.x + a1.x + r.x + bb.x;
    o.y = a0.y + a1.y + r.y + bb.y;
    o.z = a0.z + a1.z + r.z + bb.z;
    o.w = a0.w + a1.w + r.w + bb.w;
    *reinterpret_cast<float4*>(out + i) = o;
}

// ---------- V transpose via LDS (coalesced both sides) ----------
__global__ __launch_bounds__(256) void vtrans(
    const u16* __restrict__ QKV, u16* __restrict__ VT)
{
    __shared__ u16 tile[64][72];
    const int st = blockIdx.x * 64;
    const int bh = blockIdx.y;
    const int b = bh >> 4, h = bh & 15;
    const int t = threadIdx.x;

    #pragma unroll
    for (int c = 0; c < 2; ++c) {
        int tok = c * 32 + (t >> 3);
        int d0 = (t & 7) * 8;
        bf16x8 v = ldg8(QKV + ((size_t)(b * SEQ + st + tok)) * QKVS + 2048 + h * HD + d0);
        *reinterpret_cast<bf16x8*>(&tile[tok][d0]) = v;
    }
    __syncthreads();
    u16* dst = VT + (size_t)bh * HD * SEQ + st;
    #pragma unroll
    for (int c = 0; c < 2; ++c) {
        int d = c * 32 + (t >> 3);
        int tok0 = (t & 7) * 8;
        u16 vals[8];
        #pragma unroll
        for (int i = 0; i < 8; ++i) vals[i] = tile[tok0 + i][d];
        *reinterpret_cast<bf16x8*>(dst + (size_t)d * SEQ + tok0) =
            *reinterpret_cast<const bf16x8*>(vals);
    }
}

// ---------- causal flash attention v7: PAIRED q-tiles (perfect balance) ----------
// Block i handles q-tiles {31-i (heavy), i (light)}: exactly 33 tile-computes
// per block, 512 equal blocks -> no causal tail. Shared staged K/V (light
// tile's KV range is a subset of heavy's). Counted-vmcnt double buffer,
// static-max softmax, per-wave P bounce.
#define QBLK  64
#define KVBLK 64

__global__ __launch_bounds__(256, 3) void attn7(
    const u16* __restrict__ QKV, const u16* __restrict__ VT,
    u16* __restrict__ O)
{
    __shared__ u16 Ks[2][64 * 64];    // [kv][d], swizzle key (kv>>2)&7
    __shared__ u16 Vs[2][64 * 64];    // [d][kv], swizzle key d&7
    __shared__ u16 Pl[4][16 * 72];    // per-wave P[q][kv], stride 72

    const int i  = blockIdx.x;            // 0..15
    const int bh = blockIdx.y;
    const int b = bh >> 4, h = bh & 15;
    const int qta = 31 - i;               // heavy q-tile
    const int qtb = i;                    // light q-tile
    const int q0a = qta * QBLK, q0b = qtb * QBLK;
    const int t = threadIdx.x;
    const int lane = t & 63, w = t >> 6;
    const int lr = lane & 15, lg = lane >> 4;

    const size_t rowbase = (size_t)b * SEQ;
    const u16* Qg = QKV + rowbase * QKVS + h * HD;
    const u16* Kg = Qg + 1024;
    const u16* Vg = VT + (size_t)bh * HD * SEQ;

    // Q fragments: wave w owns rows q0 + w*16 + {0..15} of each tile
    const u16* qpa = Qg + (size_t)(q0a + w * 16 + lr) * QKVS;
    const u16* qpb = Qg + (size_t)(q0b + w * 16 + lr) * QKVS;
    bf16x8 qa0 = ldg8(qpa + lg * 8), qa1 = ldg8(qpa + 32 + lg * 8);
    bf16x8 qb0 = ldg8(qpb + lg * 8), qb1 = ldg8(qpb + 32 + lg * 8);

    f32x4 oa[4] = {}, ob[4] = {};
    float lsa[4] = {}, lsb[4] = {};

    const int ntiles = qta + 1;           // 17..32, always >= 2
    u16* Pw = Pl[w];
    const float SC = 0.125f * 1.44269504089f;   // 1/sqrt(64) * log2(e)

    auto stage = [&](int buf, int tt) {
        const int kv0 = tt * KVBLK;
        #pragma unroll
        for (int c = 0; c < 2; ++c) {
            int f = c * 256 + t;
            int row = f >> 3, slot = f & 7;
            int sgk = slot ^ ((row >> 2) & 7);
            int sgv = slot ^ (row & 7);
            gld_lds16(Kg + (size_t)(kv0 + row) * QKVS + sgk * 8, Ks[buf] + f * 8);
            gld_lds16(Vg + (size_t)row * SEQ + kv0 + sgv * 8, Vs[buf] + f * 8);
        }
    };

    // one q-tile's QK + softmax + PV against the staged KV tile
    auto qtile = [&](bf16x8 qf0, bf16x8 qf1, f32x4* o, float* ls,
                     int q0, int kv0, bool diag, const u16* kb, const u16* vb) {
        f32x4 s[4] = {};
        __builtin_amdgcn_s_setprio(1);
        #pragma unroll
        for (int ni = 0; ni < 4; ++ni) {
            int row = lr * 4 + ni;
            const u16* base = kb + row * 64;
            int key = (row >> 2) & 7;
            bf16x8 k0 = *reinterpret_cast<const bf16x8*>(base + ((0 + lg) ^ key) * 8);
            bf16x8 k1 = *reinterpret_cast<const bf16x8*>(base + ((4 + lg) ^ key) * 8);
            s[ni] = mfma16(qf0, k0, s[ni]);
            s[ni] = mfma16(qf1, k1, s[ni]);
        }
        __builtin_amdgcn_s_setprio(0);

        #pragma unroll
        for (int j = 0; j < 4; ++j) {
            int qi = q0 + w * 16 + lg * 4 + j;
            float p0 = __builtin_amdgcn_exp2f(s[0][j] * SC);
            float p1 = __builtin_amdgcn_exp2f(s[1][j] * SC);
            float p2 = __builtin_amdgcn_exp2f(s[2][j] * SC);
            float p3 = __builtin_amdgcn_exp2f(s[3][j] * SC);
            if (diag) {
                int kvb = kv0 + lr * 4;
                p0 = (kvb     <= qi) ? p0 : 0.f;
                p1 = (kvb + 1 <= qi) ? p1 : 0.f;
                p2 = (kvb + 2 <= qi) ? p2 : 0.f;
                p3 = (kvb + 3 <= qi) ? p3 : 0.f;
            }
            ls[j] += (p0 + p1) + (p2 + p3);
            uint2 pk = make_uint2(cvtpk_bf16(p0, p1), cvtpk_bf16(p2, p3));
            *reinterpret_cast<uint2*>(&Pw[(lg * 4 + j) * 72 + lr * 4]) = pk;
        }

        bf16x8 pa0 = *reinterpret_cast<const bf16x8*>(Pw + lr * 72 + lg * 8);
        bf16x8 pa1 = *reinterpret_cast<const bf16x8*>(Pw + lr * 72 + 32 + lg * 8);
        __builtin_amdgcn_s_setprio(1);
        #pragma unroll
        for (int ni = 0; ni < 4; ++ni) {
            int row = ni * 16 + lr;
            const u16* base = vb + row * 64;
            bf16x8 v0 = *reinterpret_cast<const bf16x8*>(base + ((0 + lg) ^ (row & 7)) * 8);
            bf16x8 v1 = *reinterpret_cast<const bf16x8*>(base + ((4 + lg) ^ (row & 7)) * 8);
            o[ni] = mfma16(pa0, v0, o[ni]);
            o[ni] = mfma16(pa1, v1, o[ni]);
        }
        __builtin_amdgcn_s_setprio(0);
    };

    // prologue: tiles 0 and 1 in flight (ntiles >= 17)
    stage(0, 0);
    stage(1, 1);
    asm volatile("s_waitcnt vmcnt(4)" ::: "memory");
    __builtin_amdgcn_s_barrier();

    for (int tt = 0; tt < ntiles; ++tt) {
        const int buf = tt & 1;
        const int kv0 = tt * KVBLK;
        const u16* kb = Ks[buf];
        const u16* vb = Vs[buf];

        qtile(qa0, qa1, oa, lsa, q0a, kv0, tt == qta, kb, vb);
        if (tt <= qtb)
            qtile(qb0, qb1, ob, lsb, q0b, kv0, tt == qtb, kb, vb);

        if (tt + 1 == ntiles) break;
        __builtin_amdgcn_s_barrier();           // all waves done reading buf
        if (tt + 2 < ntiles) {
            stage(buf, tt + 2);
            asm volatile("s_waitcnt vmcnt(4)" ::: "memory");  // tile tt+1 landed
        } else {
            asm volatile("s_waitcnt vmcnt(0)" ::: "memory");
        }
        __builtin_amdgcn_s_barrier();           // tile tt+1 visible to all
    }

    // reduce denominators + store both tiles
    #pragma unroll
    for (int j = 0; j < 4; ++j) {
        float va = lsa[j], vb2 = lsb[j];
        va += __shfl_xor(va, 1); vb2 += __shfl_xor(vb2, 1);
        va += __shfl_xor(va, 2); vb2 += __shfl_xor(vb2, 2);
        va += __shfl_xor(va, 4); vb2 += __shfl_xor(vb2, 4);
        va += __shfl_xor(va, 8); vb2 += __shfl_xor(vb2, 8);
        lsa[j] = va; lsb[j] = vb2;
    }

    u16* Oa = O + (rowbase + q0a + w * 16) * D_MODEL + h * HD;
    u16* Ob = O + (rowbase + q0b + w * 16) * D_MODEL + h * HD;
    #pragma unroll
    for (int j = 0; j < 4; ++j) {
        float inva = 1.0f / lsa[j];
        float invb = 1.0f / lsb[j];
        int r = (lg * 4 + j) * D_MODEL;
        #pragma unroll
        for (int ni = 0; ni < 4; ++ni) {
            Oa[r + ni * 16 + lr] = f2bf(oa[ni][j] * inva);
            Ob[r + ni * 16 + lr] = f2bf(ob[ni][j] * invb);
        }
    }
}

// ---------- launch ----------
extern "C" void kernel_launch(void* const* d_in, const int* in_sizes, int n_in,
                              void* d_out, int out_size, void* d_ws, size_t ws_size,
                              hipStream_t stream)
{
    (void)in_sizes; (void)n_in; (void)out_size; (void)ws_size;
    const float* x   = (const float*)d_in[0];
    const float* Wq  = (const float*)d_in[2];
    const float* bq  = (const float*)d_in[3];
    const float* Wk  = (const float*)d_in[4];
    const float* bk  = (const float*)d_in[5];
    const float* Wv  = (const float*)d_in[6];
    const float* bv  = (const float*)d_in[7];
    const float* Wo  = (const float*)d_in[8];
    const float* bo  = (const float*)d_in[9];
    const float* g1  = (const float*)d_in[10];
    const float* be1 = (const float*)d_in[11];
    const float* g2  = (const float*)d_in[12];
    const float* be2 = (const float*)d_in[13];
    const float* W1  = (const float*)d_in[14];
    const float* b1  = (const float*)d_in[15];
    const float* W2  = (const float*)d_in[16];
    const float* b2  = (const float*)d_in[17];
    float* out = (float*)d_out;

    const size_t MM = 1 << 20;   // 1M elems
    u16* Wqkv_b = (u16*)d_ws;            // 3M u16 (Wq,Wk,Wv packed [3072][1024])
    u16* Wo_b = Wqkv_b + 3 * MM;
    u16* W1_b = Wo_b + MM;               // 4M
    u16* W2_b = W1_b + 4 * MM;           // 4M
    u16* hbuf = W2_b + 4 * MM;           // 4M (LN out; dead after its GEMM)
    u16* QKVb = hbuf + 4 * MM;           // 12M  [4096][3072]
    u16* ctx  = QKVb + 12 * MM;          // 4M
    u16* ffn1 = ctx + 4 * MM;            // 16M
    float* x2 = (float*)(ffn1 + 16 * MM);        // 4M f32
    float* bqkv = (float*)(x2 + 4 * MM);         // 3072 f32
    u16* VTb = hbuf;                     // aliases hbuf (dead after QKV GEMM)
    float* fpart = (float*)QKVb;         // FFN2 partials alias QKV+ctx (dead)

    // fused weight converts
    cvt_all<<<12 * MM / 1024, 256, 0, stream>>>(Wq, Wk, Wv, Wo, W1, W2, Wqkv_b);

    // pack QKV bias
    hipMemcpyAsync(bqkv,        bq, D_MODEL * sizeof(float), hipMemcpyDeviceToDevice, stream);
    hipMemcpyAsync(bqkv + 1024, bk, D_MODEL * sizeof(float), hipMemcpyDeviceToDevice, stream);
    hipMemcpyAsync(bqkv + 2048, bv, D_MODEL * sizeof(float), hipMemcpyDeviceToDevice, stream);

    // LN1
    ln_bf16<<<ROWS, 256, 0, stream>>>(x, g1, be1, hbuf);

    // fused QKV projection (128x128 path, 768 blocks)
    dim3 gqkv(QKVS / 128, ROWS / 128);
    gemm_bt<EPI_BF16><<<gqkv, 256, 0, stream>>>(hbuf, Wqkv_b, bqkv, nullptr,
                                                QKVb, nullptr, ROWS, QKVS, 1024, 1024);

    // V transpose (hbuf dead now)
    vtrans<<<dim3(SEQ / 64, BATCH * NH), 256, 0, stream>>>(QKVb, VTb);

    // attention: paired q-tiles, 512 equal blocks
    dim3 ga(SEQ / QBLK / 2, BATCH * NH);      // (16, 32)
    attn7<<<ga, 256, 0, stream>>>(QKVb, VTb, ctx);

    // Wo projection + residual
    dim3 gq(D_MODEL / 128, ROWS / 128);
    gemm_bt<EPI_RESF32><<<gq, 256, 0, stream>>>(ctx, Wo_b, bo, x, nullptr, x2,
                                                ROWS, D_MODEL, 1024, 1024);

    // LN2
    ln_bf16<<<ROWS, 256, 0, stream>>>(x2, g2, be2, hbuf);

    // FFN1 + GELU: 256x256 8-wave deep pipeline, 256 blocks = exact CU fill
    gemm256<EPI_GELU><<<(ROWS / 256) * (D_FF / 256), 512, 0, stream>>>(
        hbuf, W1_b, b1, nullptr, ffn1, nullptr, ROWS, D_FF, D_MODEL);

    // FFN2 split-K2 + fused reduce
    dim3 gf2(D_MODEL / 128, ROWS / 128, 2);
    gemm_bt<EPI_PART><<<gf2, 256, 0, stream>>>(ffn1, W2_b, nullptr, nullptr,
                                               nullptr, fpart, ROWS, D_MODEL, 2048, 4096);
    ffn2_reduce<<<(ROWS * D_MODEL) / 1024, 256, 0, stream>>>(fpart, b2, x2, out);
}

// Round 10
// 242.157 us; speedup vs baseline: 1.8302x; 1.0522x over previous
//
#include <hip/hip_runtime.h>
#include <hip/hip_bf16.h>
#include <cstdint>
#include <cstddef>

typedef unsigned short u16;
typedef __bf16 bf16x8 __attribute__((ext_vector_type(8)));
typedef float f32x4 __attribute__((ext_vector_type(4)));

#define D_MODEL 1024
#define D_FF    4096
#define BATCH   2
#define SEQ     2048
#define NH      16
#define HD      64
#define ROWS    (BATCH*SEQ)   // 4096
#define QKVS    3072          // packed QKV row stride

// ---------- helpers ----------
__device__ __forceinline__ u16 f2bf(float f) {
    union { float f; uint32_t u; } v; v.f = f;
    uint32_t u = v.u;
    u += 0x7FFF + ((u >> 16) & 1);   // RNE
    return (u16)(u >> 16);
}

__device__ __forceinline__ uint32_t cvtpk_bf16(float lo, float hi) {
    uint32_t r;
    asm("v_cvt_pk_bf16_f32 %0, %1, %2" : "=v"(r) : "v"(lo), "v"(hi));
    return r;
}

__device__ __forceinline__ bf16x8 ldg8(const u16* p) {
    return *reinterpret_cast<const bf16x8*>(p);
}

__device__ __forceinline__ f32x4 mfma16(bf16x8 a, bf16x8 b, f32x4 c) {
    return __builtin_amdgcn_mfma_f32_16x16x32_bf16(a, b, c, 0, 0, 0);
}

__device__ __forceinline__ void gld_lds16(const void* g, void* l) {
    __builtin_amdgcn_global_load_lds(
        (const __attribute__((address_space(1))) void*)g,
        (__attribute__((address_space(3))) void*)l, 16, 0, 0);
}

// GELU, tanh-form == x * sigmoid(2*0.7978845608*(x+0.044715x^3)) via exp2.
// |gelu_tanh - gelu_erf| <= ~3e-3; clamped exp arg avoids inf/inf.
__device__ __forceinline__ float gelu_f(float x) {
    float u = fmaf(0.044715f * x, x * x, x);
    float z = fminf(-2.3022036f * u, 126.0f);
    float e = __builtin_amdgcn_exp2f(z);
    return x / (1.0f + e);
}

struct alignas(8) U16x4 { u16 x, y, z, w; };

// ---------- fused f32 -> bf16 convert for all weights ----------
__global__ void cvt_all(const float* __restrict__ s0, const float* __restrict__ s1,
                        const float* __restrict__ s2, const float* __restrict__ s3,
                        const float* __restrict__ s4, const float* __restrict__ s5,
                        u16* __restrict__ out)
{
    const size_t MM1 = 1 << 20;
    size_t i = ((size_t)blockIdx.x * 256 + threadIdx.x) * 4;
    const float* src; size_t off;
    if      (i <     MM1) { src = s0; off = i; }
    else if (i < 2 * MM1) { src = s1; off = i - MM1; }
    else if (i < 3 * MM1) { src = s2; off = i - 2 * MM1; }
    else if (i < 4 * MM1) { src = s3; off = i - 3 * MM1; }
    else if (i < 8 * MM1) { src = s4; off = i - 4 * MM1; }
    else                  { src = s5; off = i - 8 * MM1; }
    float4 f = *reinterpret_cast<const float4*>(src + off);
    U16x4 o{ f2bf(f.x), f2bf(f.y), f2bf(f.z), f2bf(f.w) };
    *reinterpret_cast<U16x4*>(out + i) = o;
}

// ---------- LayerNorm (f32 in, bf16 out) ----------
__global__ __launch_bounds__(256) void ln_bf16(
    const float* __restrict__ x, const float* __restrict__ g,
    const float* __restrict__ b, u16* __restrict__ out)
{
    int row = blockIdx.x;
    const float* xr = x + (size_t)row * D_MODEL;
    int t = threadIdx.x;
    float4 v = *reinterpret_cast<const float4*>(xr + t * 4);
    float s = v.x + v.y + v.z + v.w;
    float q = v.x*v.x + v.y*v.y + v.z*v.z + v.w*v.w;
    #pragma unroll
    for (int off = 1; off < 64; off <<= 1) {
        s += __shfl_xor(s, off);
        q += __shfl_xor(q, off);
    }
    __shared__ float red[8];
    if ((t & 63) == 0) { red[(t >> 6) * 2] = s; red[(t >> 6) * 2 + 1] = q; }
    __syncthreads();
    float sum = red[0] + red[2] + red[4] + red[6];
    float sq  = red[1] + red[3] + red[5] + red[7];
    float mu  = sum * (1.0f / D_MODEL);
    float var = sq * (1.0f / D_MODEL) - mu * mu;
    float rstd = rsqrtf(var + 1e-6f);
    float4 gg = *reinterpret_cast<const float4*>(g + t * 4);
    float4 bb = *reinterpret_cast<const float4*>(b + t * 4);
    U16x4 o{ f2bf((v.x - mu) * rstd * gg.x + bb.x),
             f2bf((v.y - mu) * rstd * gg.y + bb.y),
             f2bf((v.z - mu) * rstd * gg.z + bb.z),
             f2bf((v.w - mu) * rstd * gg.w + bb.w) };
    *reinterpret_cast<U16x4*>(out + (size_t)row * D_MODEL + t * 4) = o;
}

#define EPI_BF16   0
#define EPI_RESF32 1
#define EPI_GELU   2
#define EPI_PART   3

// ---------- GEMM 256x256 v3: barrier-light, 2-deep counted-vmcnt ----------
// 8 waves (2Mx4N), BK=64, 128 KiB LDS dbuf. NO intra-tile barriers: within a
// K-tile each wave's ds_reads/MFMA are independent (tile fully resident), so
// the 2 waves/SIMD skew naturally and LDS reads overlap MFMA across waves
// (m114 co-scheduling). Barriers only at the staging boundary, vmcnt(8)
// keeps the next tile's 8 loads in flight (never drains mid-loop).
template<int EPI>
__global__ __launch_bounds__(512, 1) void gemm256(
    const u16* __restrict__ A, const u16* __restrict__ B,
    const float* __restrict__ bias, const float* __restrict__ res,
    u16* __restrict__ outb, float* __restrict__ outf,
    int M, int N, int K)
{
    __shared__ u16 As[2][256 * 64];
    __shared__ u16 Bs[2][256 * 64];
    const int t = threadIdx.x;            // 0..511
    const int lane = t & 63, w = t >> 6;  // 8 waves
    const int lr = lane & 15, lg = lane >> 4;
    const int wr = w >> 2, wc = w & 3;    // 2 x 4 wave grid

    // XCD-aware bijective swizzle (nwg % 8 == 0)
    const int gw  = N >> 8;
    const int nwg = gridDim.x;
    const int cpx = nwg >> 3;
    const int swz = ((int)blockIdx.x & 7) * cpx + ((int)blockIdx.x >> 3);
    const int by = swz / gw, bx = swz % gw;
    const int brow = by * 256, bcol = bx * 256;

    const u16* Ag = A + (size_t)brow * K;
    const u16* Bg = B + (size_t)bcol * K;

    f32x4 acc[8][4] = {};
    const int NT = K >> 6;

    auto stageAll = [&](int buf, int kt) {
        #pragma unroll
        for (int c = 0; c < 8; ++c) {
            const u16* g = (c < 4) ? Ag : Bg;
            u16* l = (c < 4) ? As[buf] : Bs[buf];
            int cc = c & 3;
            int row = cc * 64 + (t >> 3);
            int sg = (t & 7) ^ (row & 7);
            gld_lds16(g + (size_t)row * K + kt * 64 + sg * 8, l + cc * 4096 + t * 8);
        }
    };

    auto computeTile = [&](int buf) {
        const u16* la = As[buf];
        const u16* lb = Bs[buf];
        bf16x8 breg[4][2];
        #pragma unroll
        for (int ni = 0; ni < 4; ++ni) {
            int row = wc * 64 + ni * 16 + lr;
            const u16* bp = lb + row * 64;
            int key = row & 7;
            breg[ni][0] = ldg8(bp + ((0 + lg) ^ key) * 8);
            breg[ni][1] = ldg8(bp + ((4 + lg) ^ key) * 8);
        }
        #pragma unroll
        for (int mi = 0; mi < 8; ++mi) {
            int row = wr * 128 + mi * 16 + lr;
            const u16* ap = la + row * 64;
            int key = row & 7;
            bf16x8 a0 = ldg8(ap + ((0 + lg) ^ key) * 8);
            bf16x8 a1 = ldg8(ap + ((4 + lg) ^ key) * 8);
            __builtin_amdgcn_s_setprio(1);
            #pragma unroll
            for (int ni = 0; ni < 4; ++ni) {
                acc[mi][ni] = mfma16(a0, breg[ni][0], acc[mi][ni]);
                acc[mi][ni] = mfma16(a1, breg[ni][1], acc[mi][ni]);
            }
            __builtin_amdgcn_s_setprio(0);
        }
    };

    // prologue: tiles 0 and 1 staged (NT >= 2 always: K >= 1024)
    stageAll(0, 0);
    stageAll(1, 1);
    asm volatile("s_waitcnt vmcnt(8)" ::: "memory");   // tile 0 landed
    __builtin_amdgcn_s_barrier();

    for (int kt = 0; kt < NT; ++kt) {
        computeTile(kt & 1);
        if (kt + 1 == NT) break;
        __builtin_amdgcn_s_barrier();       // all waves' reads of buf complete
        if (kt + 2 < NT) {
            stageAll(kt & 1, kt + 2);       // refill just-freed buffer
            asm volatile("s_waitcnt vmcnt(8)" ::: "memory");   // tile kt+1 landed
        } else {
            asm volatile("s_waitcnt vmcnt(0)" ::: "memory");   // tail drain
        }
        __builtin_amdgcn_s_barrier();       // tile kt+1 visible to all
    }

    // epilogue
    #pragma unroll
    for (int mi = 0; mi < 8; ++mi) {
        int r0 = brow + wr * 128 + mi * 16 + lg * 4;
        #pragma unroll
        for (int ni = 0; ni < 4; ++ni) {
            int c = bcol + wc * 64 + ni * 16 + lr;
            float bv = bias[c];
            #pragma unroll
            for (int j = 0; j < 4; ++j) {
                float v = acc[mi][ni][j] + bv;
                size_t idx = (size_t)(r0 + j) * N + c;
                if constexpr (EPI == EPI_GELU) {
                    outb[idx] = f2bf(gelu_f(v));
                } else if constexpr (EPI == EPI_RESF32) {
                    outf[idx] = v + res[idx];
                } else {
                    outb[idx] = f2bf(v);
                }
            }
        }
    }
}

// ---------- GEMM 128x128, 2-deep counted-vmcnt pipeline ----------
template<int EPI>
__global__ __launch_bounds__(256, 2) void gemm_bt(
    const u16* __restrict__ A, const u16* __restrict__ B,
    const float* __restrict__ bias, const float* __restrict__ res,
    u16* __restrict__ outb, float* __restrict__ outf,
    int M, int N, int K, int KS)
{
    __shared__ u16 As[2][128 * 64];
    __shared__ u16 Bs[2][128 * 64];
    const int t = threadIdx.x;
    const int lane = t & 63;
    const int w = t >> 6;
    const int lr = lane & 15, lg = lane >> 4;
    const int wrr = (w >> 1) * 64, wcc = (w & 1) * 64;
    const int brow = blockIdx.y * 128, bcol = blockIdx.x * 128;
    const int kz = blockIdx.z;
    const u16* Ag = A + (size_t)brow * KS + (size_t)kz * K;
    const u16* Bg = B + (size_t)bcol * KS + (size_t)kz * K;

    f32x4 acc[4][4] = {};

    const int NT = K >> 6;

    auto stage = [&](int buf, int kt) {
        const u16* ga = Ag + kt * 64;
        const u16* gb = Bg + kt * 64;
        u16* la = As[buf];
        u16* lb = Bs[buf];
        #pragma unroll
        for (int c = 0; c < 4; ++c) {
            int f = c * 256 + t;
            int row = f >> 3, slot = f & 7;
            int sg = slot ^ (row & 7);
            gld_lds16(ga + (size_t)row * KS + sg * 8, la + f * 8);
            gld_lds16(gb + (size_t)row * KS + sg * 8, lb + f * 8);
        }
    };

    auto compute = [&](int buf) {
        const u16* la = As[buf];
        const u16* lb = Bs[buf];
        bf16x8 af[4][2];
        #pragma unroll
        for (int mi = 0; mi < 4; ++mi) {
            int row = wrr + mi * 16 + lr;
            int base = row * 64;
            af[mi][0] = *reinterpret_cast<const bf16x8*>(la + base + ((0 + lg) ^ (row & 7)) * 8);
            af[mi][1] = *reinterpret_cast<const bf16x8*>(la + base + ((4 + lg) ^ (row & 7)) * 8);
        }
        __builtin_amdgcn_s_setprio(1);
        #pragma unroll
        for (int ni = 0; ni < 4; ++ni) {
            int row = wcc + ni * 16 + lr;
            int base = row * 64;
            bf16x8 b0 = *reinterpret_cast<const bf16x8*>(lb + base + ((0 + lg) ^ (row & 7)) * 8);
            bf16x8 b1 = *reinterpret_cast<const bf16x8*>(lb + base + ((4 + lg) ^ (row & 7)) * 8);
            #pragma unroll
            for (int mi = 0; mi < 4; ++mi) {
                acc[mi][ni] = mfma16(af[mi][0], b0, acc[mi][ni]);
                acc[mi][ni] = mfma16(af[mi][1], b1, acc[mi][ni]);
            }
        }
        __builtin_amdgcn_s_setprio(0);
    };

    stage(0, 0);
    if (NT > 1) {
        stage(1, 1);
        asm volatile("s_waitcnt vmcnt(8)" ::: "memory");
    } else {
        asm volatile("s_waitcnt vmcnt(0)" ::: "memory");
    }
    __builtin_amdgcn_s_barrier();

    for (int kt = 0; kt < NT; ++kt) {
        compute(kt & 1);
        if (kt + 1 == NT) break;
        __builtin_amdgcn_s_barrier();
        if (kt + 2 < NT) {
            stage(kt & 1, kt + 2);
            asm volatile("s_waitcnt vmcnt(8)" ::: "memory");
        } else {
            asm volatile("s_waitcnt vmcnt(0)" ::: "memory");
        }
        __builtin_amdgcn_s_barrier();
    }

    #pragma unroll
    for (int mi = 0; mi < 4; ++mi) {
        int r0 = brow + wrr + mi * 16 + lg * 4;
        #pragma unroll
        for (int ni = 0; ni < 4; ++ni) {
            int c = bcol + wcc + ni * 16 + lr;
            float bv = 0.f;
            if constexpr (EPI != EPI_PART) bv = bias[c];
            #pragma unroll
            for (int j = 0; j < 4; ++j) {
                float v = acc[mi][ni][j] + bv;
                size_t idx = (size_t)(r0 + j) * N + c;
                if constexpr (EPI == EPI_GELU) {
                    outb[idx] = f2bf(gelu_f(v));
                } else if constexpr (EPI == EPI_RESF32) {
                    outf[idx] = v + res[idx];
                } else if constexpr (EPI == EPI_PART) {
                    outf[idx + (size_t)kz * M * N] = v;
                } else {
                    outb[idx] = f2bf(v);
                }
            }
        }
    }
}

// ---------- FFN2 partial reduce: out = p0 + p1 + bias + residual ----------
__global__ void ffn2_reduce(const float* __restrict__ p,
                            const float* __restrict__ b2,
                            const float* __restrict__ x2,
                            float* __restrict__ out)
{
    size_t i = ((size_t)blockIdx.x * 256 + threadIdx.x) * 4;
    float4 a0 = *reinterpret_cast<const float4*>(p + i);
    float4 a1 = *reinterpret_cast<const float4*>(p + (size_t)ROWS * D_MODEL + i);
    float4 r  = *reinterpret_cast<const float4*>(x2 + i);
    float4 bb = *reinterpret_cast<const float4*>(b2 + (i & (D_MODEL - 1)));
    float4 o;
    o.x = a0.x + a1.x + r.x + bb.x;
    o.y = a0.y + a1.y + r.y + bb.y;
    o.z = a0.z + a1.z + r.z + bb.z;
    o.w = a0.w + a1.w + r.w + bb.w;
    *reinterpret_cast<float4*>(out + i) = o;
}

// ---------- V transpose via LDS (coalesced both sides) ----------
__global__ __launch_bounds__(256) void vtrans(
    const u16* __restrict__ QKV, u16* __restrict__ VT)
{
    __shared__ u16 tile[64][72];
    const int st = blockIdx.x * 64;
    const int bh = blockIdx.y;
    const int b = bh >> 4, h = bh & 15;
    const int t = threadIdx.x;

    #pragma unroll
    for (int c = 0; c < 2; ++c) {
        int tok = c * 32 + (t >> 3);
        int d0 = (t & 7) * 8;
        bf16x8 v = ldg8(QKV + ((size_t)(b * SEQ + st + tok)) * QKVS + 2048 + h * HD + d0);
        *reinterpret_cast<bf16x8*>(&tile[tok][d0]) = v;
    }
    __syncthreads();
    u16* dst = VT + (size_t)bh * HD * SEQ + st;
    #pragma unroll
    for (int c = 0; c < 2; ++c) {
        int d = c * 32 + (t >> 3);
        int tok0 = (t & 7) * 8;
        u16 vals[8];
        #pragma unroll
        for (int i = 0; i < 8; ++i) vals[i] = tile[tok0 + i][d];
        *reinterpret_cast<bf16x8*>(dst + (size_t)d * SEQ + tok0) =
            *reinterpret_cast<const bf16x8*>(vals);
    }
}

// ---------- causal flash attention v7: PAIRED q-tiles (perfect balance) ----------
#define QBLK  64
#define KVBLK 64

__global__ __launch_bounds__(256, 3) void attn7(
    const u16* __restrict__ QKV, const u16* __restrict__ VT,
    u16* __restrict__ O)
{
    __shared__ u16 Ks[2][64 * 64];    // [kv][d], swizzle key (kv>>2)&7
    __shared__ u16 Vs[2][64 * 64];    // [d][kv], swizzle key d&7
    __shared__ u16 Pl[4][16 * 72];    // per-wave P[q][kv], stride 72

    const int i  = blockIdx.x;            // 0..15
    const int bh = blockIdx.y;
    const int b = bh >> 4, h = bh & 15;
    const int qta = 31 - i;               // heavy q-tile
    const int qtb = i;                    // light q-tile
    const int q0a = qta * QBLK, q0b = qtb * QBLK;
    const int t = threadIdx.x;
    const int lane = t & 63, w = t >> 6;
    const int lr = lane & 15, lg = lane >> 4;

    const size_t rowbase = (size_t)b * SEQ;
    const u16* Qg = QKV + rowbase * QKVS + h * HD;
    const u16* Kg = Qg + 1024;
    const u16* Vg = VT + (size_t)bh * HD * SEQ;

    const u16* qpa = Qg + (size_t)(q0a + w * 16 + lr) * QKVS;
    const u16* qpb = Qg + (size_t)(q0b + w * 16 + lr) * QKVS;
    bf16x8 qa0 = ldg8(qpa + lg * 8), qa1 = ldg8(qpa + 32 + lg * 8);
    bf16x8 qb0 = ldg8(qpb + lg * 8), qb1 = ldg8(qpb + 32 + lg * 8);

    f32x4 oa[4] = {}, ob[4] = {};
    float lsa[4] = {}, lsb[4] = {};

    const int ntiles = qta + 1;           // 17..32
    u16* Pw = Pl[w];
    const float SC = 0.125f * 1.44269504089f;

    auto stage = [&](int buf, int tt) {
        const int kv0 = tt * KVBLK;
        #pragma unroll
        for (int c = 0; c < 2; ++c) {
            int f = c * 256 + t;
            int row = f >> 3, slot = f & 7;
            int sgk = slot ^ ((row >> 2) & 7);
            int sgv = slot ^ (row & 7);
            gld_lds16(Kg + (size_t)(kv0 + row) * QKVS + sgk * 8, Ks[buf] + f * 8);
            gld_lds16(Vg + (size_t)row * SEQ + kv0 + sgv * 8, Vs[buf] + f * 8);
        }
    };

    auto qtile = [&](bf16x8 qf0, bf16x8 qf1, f32x4* o, float* ls,
                     int q0, int kv0, bool diag, const u16* kb, const u16* vb) {
        f32x4 s[4] = {};
        __builtin_amdgcn_s_setprio(1);
        #pragma unroll
        for (int ni = 0; ni < 4; ++ni) {
            int row = lr * 4 + ni;
            const u16* base = kb + row * 64;
            int key = (row >> 2) & 7;
            bf16x8 k0 = *reinterpret_cast<const bf16x8*>(base + ((0 + lg) ^ key) * 8);
            bf16x8 k1 = *reinterpret_cast<const bf16x8*>(base + ((4 + lg) ^ key) * 8);
            s[ni] = mfma16(qf0, k0, s[ni]);
            s[ni] = mfma16(qf1, k1, s[ni]);
        }
        __builtin_amdgcn_s_setprio(0);

        #pragma unroll
        for (int j = 0; j < 4; ++j) {
            int qi = q0 + w * 16 + lg * 4 + j;
            float p0 = __builtin_amdgcn_exp2f(s[0][j] * SC);
            float p1 = __builtin_amdgcn_exp2f(s[1][j] * SC);
            float p2 = __builtin_amdgcn_exp2f(s[2][j] * SC);
            float p3 = __builtin_amdgcn_exp2f(s[3][j] * SC);
            if (diag) {
                int kvb = kv0 + lr * 4;
                p0 = (kvb     <= qi) ? p0 : 0.f;
                p1 = (kvb + 1 <= qi) ? p1 : 0.f;
                p2 = (kvb + 2 <= qi) ? p2 : 0.f;
                p3 = (kvb + 3 <= qi) ? p3 : 0.f;
            }
            ls[j] += (p0 + p1) + (p2 + p3);
            uint2 pk = make_uint2(cvtpk_bf16(p0, p1), cvtpk_bf16(p2, p3));
            *reinterpret_cast<uint2*>(&Pw[(lg * 4 + j) * 72 + lr * 4]) = pk;
        }

        bf16x8 pa0 = *reinterpret_cast<const bf16x8*>(Pw + lr * 72 + lg * 8);
        bf16x8 pa1 = *reinterpret_cast<const bf16x8*>(Pw + lr * 72 + 32 + lg * 8);
        __builtin_amdgcn_s_setprio(1);
        #pragma unroll
        for (int ni = 0; ni < 4; ++ni) {
            int row = ni * 16 + lr;
            const u16* base = vb + row * 64;
            bf16x8 v0 = *reinterpret_cast<const bf16x8*>(base + ((0 + lg) ^ (row & 7)) * 8);
            bf16x8 v1 = *reinterpret_cast<const bf16x8*>(base + ((4 + lg) ^ (row & 7)) * 8);
            o[ni] = mfma16(pa0, v0, o[ni]);
            o[ni] = mfma16(pa1, v1, o[ni]);
        }
        __builtin_amdgcn_s_setprio(0);
    };

    stage(0, 0);
    stage(1, 1);
    asm volatile("s_waitcnt vmcnt(4)" ::: "memory");
    __builtin_amdgcn_s_barrier();

    for (int tt = 0; tt < ntiles; ++tt) {
        const int buf = tt & 1;
        const int kv0 = tt * KVBLK;
        const u16* kb = Ks[buf];
        const u16* vb = Vs[buf];

        qtile(qa0, qa1, oa, lsa, q0a, kv0, tt == qta, kb, vb);
        if (tt <= qtb)
            qtile(qb0, qb1, ob, lsb, q0b, kv0, tt == qtb, kb, vb);

        if (tt + 1 == ntiles) break;
        __builtin_amdgcn_s_barrier();
        if (tt + 2 < ntiles) {
            stage(buf, tt + 2);
            asm volatile("s_waitcnt vmcnt(4)" ::: "memory");
        } else {
            asm volatile("s_waitcnt vmcnt(0)" ::: "memory");
        }
        __builtin_amdgcn_s_barrier();
    }

    #pragma unroll
    for (int j = 0; j < 4; ++j) {
        float va = lsa[j], vb2 = lsb[j];
        va += __shfl_xor(va, 1); vb2 += __shfl_xor(vb2, 1);
        va += __shfl_xor(va, 2); vb2 += __shfl_xor(vb2, 2);
        va += __shfl_xor(va, 4); vb2 += __shfl_xor(vb2, 4);
        va += __shfl_xor(va, 8); vb2 += __shfl_xor(vb2, 8);
        lsa[j] = va; lsb[j] = vb2;
    }

    u16* Oa = O + (rowbase + q0a + w * 16) * D_MODEL + h * HD;
    u16* Ob = O + (rowbase + q0b + w * 16) * D_MODEL + h * HD;
    #pragma unroll
    for (int j = 0; j < 4; ++j) {
        float inva = 1.0f / lsa[j];
        float invb = 1.0f / lsb[j];
        int r = (lg * 4 + j) * D_MODEL;
        #pragma unroll
        for (int ni = 0; ni < 4; ++ni) {
            Oa[r + ni * 16 + lr] = f2bf(oa[ni][j] * inva);
            Ob[r + ni * 16 + lr] = f2bf(ob[ni][j] * invb);
        }
    }
}

// ---------- launch ----------
extern "C" void kernel_launch(void* const* d_in, const int* in_sizes, int n_in,
                              void* d_out, int out_size, void* d_ws, size_t ws_size,
                              hipStream_t stream)
{
    (void)in_sizes; (void)n_in; (void)out_size; (void)ws_size;
    const float* x   = (const float*)d_in[0];
    const float* Wq  = (const float*)d_in[2];
    const float* bq  = (const float*)d_in[3];
    const float* Wk  = (const float*)d_in[4];
    const float* bk  = (const float*)d_in[5];
    const float* Wv  = (const float*)d_in[6];
    const float* bv  = (const float*)d_in[7];
    const float* Wo  = (const float*)d_in[8];
    const float* bo  = (const float*)d_in[9];
    const float* g1  = (const float*)d_in[10];
    const float* be1 = (const float*)d_in[11];
    const float* g2  = (const float*)d_in[12];
    const float* be2 = (const float*)d_in[13];
    const float* W1  = (const float*)d_in[14];
    const float* b1  = (const float*)d_in[15];
    const float* W2  = (const float*)d_in[16];
    const float* b2  = (const float*)d_in[17];
    float* out = (float*)d_out;

    const size_t MM = 1 << 20;   // 1M elems
    u16* Wqkv_b = (u16*)d_ws;            // 3M u16 (Wq,Wk,Wv packed [3072][1024])
    u16* Wo_b = Wqkv_b + 3 * MM;
    u16* W1_b = Wo_b + MM;               // 4M
    u16* W2_b = W1_b + 4 * MM;           // 4M
    u16* hbuf = W2_b + 4 * MM;           // 4M (LN out; dead after its GEMM)
    u16* QKVb = hbuf + 4 * MM;           // 12M  [4096][3072]
    u16* ctx  = QKVb + 12 * MM;          // 4M
    u16* ffn1 = ctx + 4 * MM;            // 16M
    float* x2 = (float*)(ffn1 + 16 * MM);        // 4M f32
    float* bqkv = (float*)(x2 + 4 * MM);         // 3072 f32
    u16* VTb = hbuf;                     // aliases hbuf (dead after QKV GEMM)
    float* fpart = (float*)QKVb;         // FFN2 partials alias QKV+ctx (dead)

    // fused weight converts
    cvt_all<<<12 * MM / 1024, 256, 0, stream>>>(Wq, Wk, Wv, Wo, W1, W2, Wqkv_b);

    // pack QKV bias
    hipMemcpyAsync(bqkv,        bq, D_MODEL * sizeof(float), hipMemcpyDeviceToDevice, stream);
    hipMemcpyAsync(bqkv + 1024, bk, D_MODEL * sizeof(float), hipMemcpyDeviceToDevice, stream);
    hipMemcpyAsync(bqkv + 2048, bv, D_MODEL * sizeof(float), hipMemcpyDeviceToDevice, stream);

    // LN1
    ln_bf16<<<ROWS, 256, 0, stream>>>(x, g1, be1, hbuf);

    // fused QKV projection (128x128 path, 768 blocks)
    dim3 gqkv(QKVS / 128, ROWS / 128);
    gemm_bt<EPI_BF16><<<gqkv, 256, 0, stream>>>(hbuf, Wqkv_b, bqkv, nullptr,
                                                QKVb, nullptr, ROWS, QKVS, 1024, 1024);

    // V transpose (hbuf dead now)
    vtrans<<<dim3(SEQ / 64, BATCH * NH), 256, 0, stream>>>(QKVb, VTb);

    // attention: paired q-tiles, 512 equal blocks
    dim3 ga(SEQ / QBLK / 2, BATCH * NH);      // (16, 32)
    attn7<<<ga, 256, 0, stream>>>(QKVb, VTb, ctx);

    // Wo projection + residual
    dim3 gq(D_MODEL / 128, ROWS / 128);
    gemm_bt<EPI_RESF32><<<gq, 256, 0, stream>>>(ctx, Wo_b, bo, x, nullptr, x2,
                                                ROWS, D_MODEL, 1024, 1024);

    // LN2
    ln_bf16<<<ROWS, 256, 0, stream>>>(x2, g2, be2, hbuf);

    // FFN1 + GELU: 256x256 barrier-light, 256 blocks = exact CU fill
    gemm256<EPI_GELU><<<(ROWS / 256) * (D_FF / 256), 512, 0, stream>>>(
        hbuf, W1_b, b1, nullptr, ffn1, nullptr, ROWS, D_FF, D_MODEL);

    // FFN2 split-K2 + fused reduce
    dim3 gf2(D_MODEL / 128, ROWS / 128, 2);
    gemm_bt<EPI_PART><<<gf2, 256, 0, stream>>>(ffn1, W2_b, nullptr, nullptr,
                                               nullptr, fpart, ROWS, D_MODEL, 2048, 4096);
    ffn2_reduce<<<(ROWS * D_MODEL) / 1024, 256, 0, stream>>>(fpart, b2, x2, out);
}

// Round 11
// 238.930 us; speedup vs baseline: 1.8549x; 1.0135x over previous
//
#include <hip/hip_runtime.h>
#include <hip/hip_bf16.h>
#include <cstdint>
#include <cstddef>

typedef unsigned short u16;
typedef __bf16 bf16x8 __attribute__((ext_vector_type(8)));
typedef float f32x4 __attribute__((ext_vector_type(4)));

#define D_MODEL 1024
#define D_FF    4096
#define BATCH   2
#define SEQ     2048
#define NH      16
#define HD      64
#define ROWS    (BATCH*SEQ)   // 4096
#define QKVS    3072          // packed QKV row stride

// ---------- helpers ----------
__device__ __forceinline__ u16 f2bf(float f) {
    union { float f; uint32_t u; } v; v.f = f;
    uint32_t u = v.u;
    u += 0x7FFF + ((u >> 16) & 1);   // RNE
    return (u16)(u >> 16);
}

__device__ __forceinline__ uint32_t cvtpk_bf16(float lo, float hi) {
    uint32_t r;
    asm("v_cvt_pk_bf16_f32 %0, %1, %2" : "=v"(r) : "v"(lo), "v"(hi));
    return r;
}

__device__ __forceinline__ bf16x8 ldg8(const u16* p) {
    return *reinterpret_cast<const bf16x8*>(p);
}

__device__ __forceinline__ f32x4 mfma16(bf16x8 a, bf16x8 b, f32x4 c) {
    return __builtin_amdgcn_mfma_f32_16x16x32_bf16(a, b, c, 0, 0, 0);
}

__device__ __forceinline__ void gld_lds16(const void* g, void* l) {
    __builtin_amdgcn_global_load_lds(
        (const __attribute__((address_space(1))) void*)g,
        (__attribute__((address_space(3))) void*)l, 16, 0, 0);
}

// GELU, tanh-form via exp2; |err| <= ~3e-3.
__device__ __forceinline__ float gelu_f(float x) {
    float u = fmaf(0.044715f * x, x * x, x);
    float z = fminf(-2.3022036f * u, 126.0f);
    float e = __builtin_amdgcn_exp2f(z);
    return x / (1.0f + e);
}

struct alignas(8) U16x4 { u16 x, y, z, w; };

// ---------- fused f32 -> bf16 convert for all weights ----------
__global__ void cvt_all(const float* __restrict__ s0, const float* __restrict__ s1,
                        const float* __restrict__ s2, const float* __restrict__ s3,
                        const float* __restrict__ s4, const float* __restrict__ s5,
                        u16* __restrict__ out)
{
    const size_t MM1 = 1 << 20;
    size_t i = ((size_t)blockIdx.x * 256 + threadIdx.x) * 4;
    const float* src; size_t off;
    if      (i <     MM1) { src = s0; off = i; }
    else if (i < 2 * MM1) { src = s1; off = i - MM1; }
    else if (i < 3 * MM1) { src = s2; off = i - 2 * MM1; }
    else if (i < 4 * MM1) { src = s3; off = i - 3 * MM1; }
    else if (i < 8 * MM1) { src = s4; off = i - 4 * MM1; }
    else                  { src = s5; off = i - 8 * MM1; }
    float4 f = *reinterpret_cast<const float4*>(src + off);
    U16x4 o{ f2bf(f.x), f2bf(f.y), f2bf(f.z), f2bf(f.w) };
    *reinterpret_cast<U16x4*>(out + i) = o;
}

// ---------- LayerNorm (f32 in, bf16 out) ----------
__global__ __launch_bounds__(256) void ln_bf16(
    const float* __restrict__ x, const float* __restrict__ g,
    const float* __restrict__ b, u16* __restrict__ out)
{
    int row = blockIdx.x;
    const float* xr = x + (size_t)row * D_MODEL;
    int t = threadIdx.x;
    float4 v = *reinterpret_cast<const float4*>(xr + t * 4);
    float s = v.x + v.y + v.z + v.w;
    float q = v.x*v.x + v.y*v.y + v.z*v.z + v.w*v.w;
    #pragma unroll
    for (int off = 1; off < 64; off <<= 1) {
        s += __shfl_xor(s, off);
        q += __shfl_xor(q, off);
    }
    __shared__ float red[8];
    if ((t & 63) == 0) { red[(t >> 6) * 2] = s; red[(t >> 6) * 2 + 1] = q; }
    __syncthreads();
    float sum = red[0] + red[2] + red[4] + red[6];
    float sq  = red[1] + red[3] + red[5] + red[7];
    float mu  = sum * (1.0f / D_MODEL);
    float var = sq * (1.0f / D_MODEL) - mu * mu;
    float rstd = rsqrtf(var + 1e-6f);
    float4 gg = *reinterpret_cast<const float4*>(g + t * 4);
    float4 bb = *reinterpret_cast<const float4*>(b + t * 4);
    U16x4 o{ f2bf((v.x - mu) * rstd * gg.x + bb.x),
             f2bf((v.y - mu) * rstd * gg.y + bb.y),
             f2bf((v.z - mu) * rstd * gg.z + bb.z),
             f2bf((v.w - mu) * rstd * gg.w + bb.w) };
    *reinterpret_cast<U16x4*>(out + (size_t)row * D_MODEL + t * 4) = o;
}

#define EPI_BF16   0
#define EPI_RESF32 1
#define EPI_GELU   2
#define EPI_PART   3

// ---------- GEMM 256x256 v4: m201-faithful 4-phase/tile schedule ----------
// 8 waves (2Mx4N), BK=64, 128 KiB LDS dbuf, 2-tile prefetch distance.
// Per K-tile 4 phases, one 64x32 C-quadrant each:
//   P0: ds_read A0(8)+B0(4) -> BAR -> lgkm(0) -> 16 MFMA(prio) -> BAR
//   P1: ds_read B1(4)       -> BAR -> lgkm(0) -> 16 MFMA(prio) -> BAR
//   P2: ds_read A1(8)       -> BAR -> lgkm(0) -> 16 MFMA(prio) -> BAR
//   P3: stage tile kt+2 (safe: all reads of cur done at P2's closing BAR),
//       16 MFMA (reg-only, hides wait), vmcnt(8) (tile kt+1 landed,
//       kt+2's 8 loads stay in flight -- never drains mid-loop), BAR.
template<int EPI>
__global__ __launch_bounds__(512, 1) void gemm256(
    const u16* __restrict__ A, const u16* __restrict__ B,
    const float* __restrict__ bias, const float* __restrict__ res,
    u16* __restrict__ outb, float* __restrict__ outf,
    int M, int N, int K)
{
    __shared__ u16 As[2][256 * 64];
    __shared__ u16 Bs[2][256 * 64];
    const int t = threadIdx.x;            // 0..511
    const int lane = t & 63, w = t >> 6;  // 8 waves
    const int lr = lane & 15, lg = lane >> 4;
    const int wr = w >> 2, wc = w & 3;    // 2 x 4 wave grid

    // XCD-aware bijective swizzle (nwg % 8 == 0)
    const int gw  = N >> 8;
    const int nwg = gridDim.x;
    const int cpx = nwg >> 3;
    const int swz = ((int)blockIdx.x & 7) * cpx + ((int)blockIdx.x >> 3);
    const int by = swz / gw, bx = swz % gw;
    const int brow = by * 256, bcol = bx * 256;

    const u16* Ag = A + (size_t)brow * K;
    const u16* Bg = B + (size_t)bcol * K;

    f32x4 acc[8][4] = {};
    const int NT = K >> 6;

    auto stageAll = [&](int buf, int kt) {
        #pragma unroll
        for (int c = 0; c < 8; ++c) {
            const u16* g = (c < 4) ? Ag : Bg;
            u16* l = (c < 4) ? As[buf] : Bs[buf];
            int cc = c & 3;
            int row = cc * 64 + (t >> 3);
            int sg = (t & 7) ^ (row & 7);
            gld_lds16(g + (size_t)row * K + kt * 64 + sg * 8, l + cc * 4096 + t * 8);
        }
    };

    bf16x8 areg[4][2];          // current A half (qm), reloaded at P2
    bf16x8 breg[2][2][2];       // both B halves, live across the tile

    auto loadA = [&](const u16* la, int qm) {
        #pragma unroll
        for (int f = 0; f < 4; ++f) {
            int row = wr * 128 + qm * 64 + f * 16 + lr;
            const u16* bp = la + row * 64;
            int key = row & 7;
            areg[f][0] = ldg8(bp + ((0 + lg) ^ key) * 8);
            areg[f][1] = ldg8(bp + ((4 + lg) ^ key) * 8);
        }
    };
    auto loadB = [&](const u16* lb, int qn) {
        #pragma unroll
        for (int f = 0; f < 2; ++f) {
            int row = wc * 64 + qn * 32 + f * 16 + lr;
            const u16* bp = lb + row * 64;
            int key = row & 7;
            breg[qn][f][0] = ldg8(bp + ((0 + lg) ^ key) * 8);
            breg[qn][f][1] = ldg8(bp + ((4 + lg) ^ key) * 8);
        }
    };
    auto mmaQ = [&](int qm, int qn) {
        __builtin_amdgcn_s_setprio(1);
        #pragma unroll
        for (int mi = 0; mi < 4; ++mi) {
            #pragma unroll
            for (int fn = 0; fn < 2; ++fn) {
                acc[qm * 4 + mi][qn * 2 + fn] =
                    mfma16(areg[mi][0], breg[qn][fn][0], acc[qm * 4 + mi][qn * 2 + fn]);
                acc[qm * 4 + mi][qn * 2 + fn] =
                    mfma16(areg[mi][1], breg[qn][fn][1], acc[qm * 4 + mi][qn * 2 + fn]);
            }
        }
        __builtin_amdgcn_s_setprio(0);
    };

    // prologue: tiles 0 and 1 staged (NT >= 16 here)
    stageAll(0, 0);
    stageAll(1, 1);
    asm volatile("s_waitcnt vmcnt(8)" ::: "memory");   // tile 0 landed
    __builtin_amdgcn_s_barrier();

    for (int kt = 0; kt < NT; ++kt) {
        const int cur = kt & 1;
        const u16* la = As[cur];
        const u16* lb = Bs[cur];
        // P0: quadrant (0,0)
        loadA(la, 0); loadB(lb, 0);
        __builtin_amdgcn_s_barrier();
        asm volatile("s_waitcnt lgkmcnt(0)" ::: "memory");
        mmaQ(0, 0);
        __builtin_amdgcn_s_barrier();
        // P1: quadrant (0,1)
        loadB(lb, 1);
        __builtin_amdgcn_s_barrier();
        asm volatile("s_waitcnt lgkmcnt(0)" ::: "memory");
        mmaQ(0, 1);
        __builtin_amdgcn_s_barrier();
        // P2: quadrant (1,0)
        loadA(la, 1);
        __builtin_amdgcn_s_barrier();
        asm volatile("s_waitcnt lgkmcnt(0)" ::: "memory");
        mmaQ(1, 0);
        __builtin_amdgcn_s_barrier();
        // P3: quadrant (1,1) + staging + boundary
        if (kt + 2 < NT) stageAll(cur, kt + 2);   // all reads of cur complete
        mmaQ(1, 1);                                // reg-only, hides the wait
        if (kt + 1 == NT) break;
        if (kt + 2 < NT)
            asm volatile("s_waitcnt vmcnt(8)" ::: "memory");   // tile kt+1 landed
        else
            asm volatile("s_waitcnt vmcnt(0)" ::: "memory");   // tail drain
        __builtin_amdgcn_s_barrier();              // kt+1 visible to all
    }

    // epilogue
    #pragma unroll
    for (int mi = 0; mi < 8; ++mi) {
        int r0 = brow + wr * 128 + mi * 16 + lg * 4;
        #pragma unroll
        for (int ni = 0; ni < 4; ++ni) {
            int c = bcol + wc * 64 + ni * 16 + lr;
            float bv = bias[c];
            #pragma unroll
            for (int j = 0; j < 4; ++j) {
                float v = acc[mi][ni][j] + bv;
                size_t idx = (size_t)(r0 + j) * N + c;
                if constexpr (EPI == EPI_GELU) {
                    outb[idx] = f2bf(gelu_f(v));
                } else if constexpr (EPI == EPI_RESF32) {
                    outf[idx] = v + res[idx];
                } else {
                    outb[idx] = f2bf(v);
                }
            }
        }
    }
}

// ---------- GEMM 128x128, 2-deep counted-vmcnt pipeline ----------
template<int EPI>
__global__ __launch_bounds__(256, 2) void gemm_bt(
    const u16* __restrict__ A, const u16* __restrict__ B,
    const float* __restrict__ bias, const float* __restrict__ res,
    u16* __restrict__ outb, float* __restrict__ outf,
    int M, int N, int K, int KS)
{
    __shared__ u16 As[2][128 * 64];
    __shared__ u16 Bs[2][128 * 64];
    const int t = threadIdx.x;
    const int lane = t & 63;
    const int w = t >> 6;
    const int lr = lane & 15, lg = lane >> 4;
    const int wrr = (w >> 1) * 64, wcc = (w & 1) * 64;
    const int brow = blockIdx.y * 128, bcol = blockIdx.x * 128;
    const int kz = blockIdx.z;
    const u16* Ag = A + (size_t)brow * KS + (size_t)kz * K;
    const u16* Bg = B + (size_t)bcol * KS + (size_t)kz * K;

    f32x4 acc[4][4] = {};

    const int NT = K >> 6;

    auto stage = [&](int buf, int kt) {
        const u16* ga = Ag + kt * 64;
        const u16* gb = Bg + kt * 64;
        u16* la = As[buf];
        u16* lb = Bs[buf];
        #pragma unroll
        for (int c = 0; c < 4; ++c) {
            int f = c * 256 + t;
            int row = f >> 3, slot = f & 7;
            int sg = slot ^ (row & 7);
            gld_lds16(ga + (size_t)row * KS + sg * 8, la + f * 8);
            gld_lds16(gb + (size_t)row * KS + sg * 8, lb + f * 8);
        }
    };

    auto compute = [&](int buf) {
        const u16* la = As[buf];
        const u16* lb = Bs[buf];
        bf16x8 af[4][2];
        #pragma unroll
        for (int mi = 0; mi < 4; ++mi) {
            int row = wrr + mi * 16 + lr;
            int base = row * 64;
            af[mi][0] = *reinterpret_cast<const bf16x8*>(la + base + ((0 + lg) ^ (row & 7)) * 8);
            af[mi][1] = *reinterpret_cast<const bf16x8*>(la + base + ((4 + lg) ^ (row & 7)) * 8);
        }
        __builtin_amdgcn_s_setprio(1);
        #pragma unroll
        for (int ni = 0; ni < 4; ++ni) {
            int row = wcc + ni * 16 + lr;
            int base = row * 64;
            bf16x8 b0 = *reinterpret_cast<const bf16x8*>(lb + base + ((0 + lg) ^ (row & 7)) * 8);
            bf16x8 b1 = *reinterpret_cast<const bf16x8*>(lb + base + ((4 + lg) ^ (row & 7)) * 8);
            #pragma unroll
            for (int mi = 0; mi < 4; ++mi) {
                acc[mi][ni] = mfma16(af[mi][0], b0, acc[mi][ni]);
                acc[mi][ni] = mfma16(af[mi][1], b1, acc[mi][ni]);
            }
        }
        __builtin_amdgcn_s_setprio(0);
    };

    stage(0, 0);
    if (NT > 1) {
        stage(1, 1);
        asm volatile("s_waitcnt vmcnt(8)" ::: "memory");
    } else {
        asm volatile("s_waitcnt vmcnt(0)" ::: "memory");
    }
    __builtin_amdgcn_s_barrier();

    for (int kt = 0; kt < NT; ++kt) {
        compute(kt & 1);
        if (kt + 1 == NT) break;
        __builtin_amdgcn_s_barrier();
        if (kt + 2 < NT) {
            stage(kt & 1, kt + 2);
            asm volatile("s_waitcnt vmcnt(8)" ::: "memory");
        } else {
            asm volatile("s_waitcnt vmcnt(0)" ::: "memory");
        }
        __builtin_amdgcn_s_barrier();
    }

    #pragma unroll
    for (int mi = 0; mi < 4; ++mi) {
        int r0 = brow + wrr + mi * 16 + lg * 4;
        #pragma unroll
        for (int ni = 0; ni < 4; ++ni) {
            int c = bcol + wcc + ni * 16 + lr;
            float bv = 0.f;
            if constexpr (EPI != EPI_PART) bv = bias[c];
            #pragma unroll
            for (int j = 0; j < 4; ++j) {
                float v = acc[mi][ni][j] + bv;
                size_t idx = (size_t)(r0 + j) * N + c;
                if constexpr (EPI == EPI_GELU) {
                    outb[idx] = f2bf(gelu_f(v));
                } else if constexpr (EPI == EPI_RESF32) {
                    outf[idx] = v + res[idx];
                } else if constexpr (EPI == EPI_PART) {
                    outf[idx + (size_t)kz * M * N] = v;
                } else {
                    outb[idx] = f2bf(v);
                }
            }
        }
    }
}

// ---------- FFN2 partial reduce: out = p0 + p1 + bias + residual ----------
__global__ void ffn2_reduce(const float* __restrict__ p,
                            const float* __restrict__ b2,
                            const float* __restrict__ x2,
                            float* __restrict__ out)
{
    size_t i = ((size_t)blockIdx.x * 256 + threadIdx.x) * 4;
    float4 a0 = *reinterpret_cast<const float4*>(p + i);
    float4 a1 = *reinterpret_cast<const float4*>(p + (size_t)ROWS * D_MODEL + i);
    float4 r  = *reinterpret_cast<const float4*>(x2 + i);
    float4 bb = *reinterpret_cast<const float4*>(b2 + (i & (D_MODEL - 1)));
    float4 o;
    o.x = a0.x + a1.x + r.x + bb.x;
    o.y = a0.y + a1.y + r.y + bb.y;
    o.z = a0.z + a1.z + r.z + bb.z;
    o.w = a0.w + a1.w + r.w + bb.w;
    *reinterpret_cast<float4*>(out + i) = o;
}

// ---------- V transpose via LDS (coalesced both sides) ----------
__global__ __launch_bounds__(256) void vtrans(
    const u16* __restrict__ QKV, u16* __restrict__ VT)
{
    __shared__ u16 tile[64][72];
    const int st = blockIdx.x * 64;
    const int bh = blockIdx.y;
    const int b = bh >> 4, h = bh & 15;
    const int t = threadIdx.x;

    #pragma unroll
    for (int c = 0; c < 2; ++c) {
        int tok = c * 32 + (t >> 3);
        int d0 = (t & 7) * 8;
        bf16x8 v = ldg8(QKV + ((size_t)(b * SEQ + st + tok)) * QKVS + 2048 + h * HD + d0);
        *reinterpret_cast<bf16x8*>(&tile[tok][d0]) = v;
    }
    __syncthreads();
    u16* dst = VT + (size_t)bh * HD * SEQ + st;
    #pragma unroll
    for (int c = 0; c < 2; ++c) {
        int d = c * 32 + (t >> 3);
        int tok0 = (t & 7) * 8;
        u16 vals[8];
        #pragma unroll
        for (int i = 0; i < 8; ++i) vals[i] = tile[tok0 + i][d];
        *reinterpret_cast<bf16x8*>(dst + (size_t)d * SEQ + tok0) =
            *reinterpret_cast<const bf16x8*>(vals);
    }
}

// ---------- causal flash attention v7: PAIRED q-tiles (perfect balance) ----------
#define QBLK  64
#define KVBLK 64

__global__ __launch_bounds__(256, 3) void attn7(
    const u16* __restrict__ QKV, const u16* __restrict__ VT,
    u16* __restrict__ O)
{
    __shared__ u16 Ks[2][64 * 64];    // [kv][d], swizzle key (kv>>2)&7
    __shared__ u16 Vs[2][64 * 64];    // [d][kv], swizzle key d&7
    __shared__ u16 Pl[4][16 * 72];    // per-wave P[q][kv], stride 72

    const int i  = blockIdx.x;            // 0..15
    const int bh = blockIdx.y;
    const int b = bh >> 4, h = bh & 15;
    const int qta = 31 - i;               // heavy q-tile
    const int qtb = i;                    // light q-tile
    const int q0a = qta * QBLK, q0b = qtb * QBLK;
    const int t = threadIdx.x;
    const int lane = t & 63, w = t >> 6;
    const int lr = lane & 15, lg = lane >> 4;

    const size_t rowbase = (size_t)b * SEQ;
    const u16* Qg = QKV + rowbase * QKVS + h * HD;
    const u16* Kg = Qg + 1024;
    const u16* Vg = VT + (size_t)bh * HD * SEQ;

    const u16* qpa = Qg + (size_t)(q0a + w * 16 + lr) * QKVS;
    const u16* qpb = Qg + (size_t)(q0b + w * 16 + lr) * QKVS;
    bf16x8 qa0 = ldg8(qpa + lg * 8), qa1 = ldg8(qpa + 32 + lg * 8);
    bf16x8 qb0 = ldg8(qpb + lg * 8), qb1 = ldg8(qpb + 32 + lg * 8);

    f32x4 oa[4] = {}, ob[4] = {};
    float lsa[4] = {}, lsb[4] = {};

    const int ntiles = qta + 1;           // 17..32
    u16* Pw = Pl[w];
    const float SC = 0.125f * 1.44269504089f;

    auto stage = [&](int buf, int tt) {
        const int kv0 = tt * KVBLK;
        #pragma unroll
        for (int c = 0; c < 2; ++c) {
            int f = c * 256 + t;
            int row = f >> 3, slot = f & 7;
            int sgk = slot ^ ((row >> 2) & 7);
            int sgv = slot ^ (row & 7);
            gld_lds16(Kg + (size_t)(kv0 + row) * QKVS + sgk * 8, Ks[buf] + f * 8);
            gld_lds16(Vg + (size_t)row * SEQ + kv0 + sgv * 8, Vs[buf] + f * 8);
        }
    };

    auto qtile = [&](bf16x8 qf0, bf16x8 qf1, f32x4* o, float* ls,
                     int q0, int kv0, bool diag, const u16* kb, const u16* vb) {
        f32x4 s[4] = {};
        __builtin_amdgcn_s_setprio(1);
        #pragma unroll
        for (int ni = 0; ni < 4; ++ni) {
            int row = lr * 4 + ni;
            const u16* base = kb + row * 64;
            int key = (row >> 2) & 7;
            bf16x8 k0 = *reinterpret_cast<const bf16x8*>(base + ((0 + lg) ^ key) * 8);
            bf16x8 k1 = *reinterpret_cast<const bf16x8*>(base + ((4 + lg) ^ key) * 8);
            s[ni] = mfma16(qf0, k0, s[ni]);
            s[ni] = mfma16(qf1, k1, s[ni]);
        }
        __builtin_amdgcn_s_setprio(0);

        #pragma unroll
        for (int j = 0; j < 4; ++j) {
            int qi = q0 + w * 16 + lg * 4 + j;
            float p0 = __builtin_amdgcn_exp2f(s[0][j] * SC);
            float p1 = __builtin_amdgcn_exp2f(s[1][j] * SC);
            float p2 = __builtin_amdgcn_exp2f(s[2][j] * SC);
            float p3 = __builtin_amdgcn_exp2f(s[3][j] * SC);
            if (diag) {
                int kvb = kv0 + lr * 4;
                p0 = (kvb     <= qi) ? p0 : 0.f;
                p1 = (kvb + 1 <= qi) ? p1 : 0.f;
                p2 = (kvb + 2 <= qi) ? p2 : 0.f;
                p3 = (kvb + 3 <= qi) ? p3 : 0.f;
            }
            ls[j] += (p0 + p1) + (p2 + p3);
            uint2 pk = make_uint2(cvtpk_bf16(p0, p1), cvtpk_bf16(p2, p3));
            *reinterpret_cast<uint2*>(&Pw[(lg * 4 + j) * 72 + lr * 4]) = pk;
        }

        bf16x8 pa0 = *reinterpret_cast<const bf16x8*>(Pw + lr * 72 + lg * 8);
        bf16x8 pa1 = *reinterpret_cast<const bf16x8*>(Pw + lr * 72 + 32 + lg * 8);
        __builtin_amdgcn_s_setprio(1);
        #pragma unroll
        for (int ni = 0; ni < 4; ++ni) {
            int row = ni * 16 + lr;
            const u16* base = vb + row * 64;
            bf16x8 v0 = *reinterpret_cast<const bf16x8*>(base + ((0 + lg) ^ (row & 7)) * 8);
            bf16x8 v1 = *reinterpret_cast<const bf16x8*>(base + ((4 + lg) ^ (row & 7)) * 8);
            o[ni] = mfma16(pa0, v0, o[ni]);
            o[ni] = mfma16(pa1, v1, o[ni]);
        }
        __builtin_amdgcn_s_setprio(0);
    };

    stage(0, 0);
    stage(1, 1);
    asm volatile("s_waitcnt vmcnt(4)" ::: "memory");
    __builtin_amdgcn_s_barrier();

    for (int tt = 0; tt < ntiles; ++tt) {
        const int buf = tt & 1;
        const int kv0 = tt * KVBLK;
        const u16* kb = Ks[buf];
        const u16* vb = Vs[buf];

        qtile(qa0, qa1, oa, lsa, q0a, kv0, tt == qta, kb, vb);
        if (tt <= qtb)
            qtile(qb0, qb1, ob, lsb, q0b, kv0, tt == qtb, kb, vb);

        if (tt + 1 == ntiles) break;
        __builtin_amdgcn_s_barrier();
        if (tt + 2 < ntiles) {
            stage(buf, tt + 2);
            asm volatile("s_waitcnt vmcnt(4)" ::: "memory");
        } else {
            asm volatile("s_waitcnt vmcnt(0)" ::: "memory");
        }
        __builtin_amdgcn_s_barrier();
    }

    #pragma unroll
    for (int j = 0; j < 4; ++j) {
        float va = lsa[j], vb2 = lsb[j];
        va += __shfl_xor(va, 1); vb2 += __shfl_xor(vb2, 1);
        va += __shfl_xor(va, 2); vb2 += __shfl_xor(vb2, 2);
        va += __shfl_xor(va, 4); vb2 += __shfl_xor(vb2, 4);
        va += __shfl_xor(va, 8); vb2 += __shfl_xor(vb2, 8);
        lsa[j] = va; lsb[j] = vb2;
    }

    u16* Oa = O + (rowbase + q0a + w * 16) * D_MODEL + h * HD;
    u16* Ob = O + (rowbase + q0b + w * 16) * D_MODEL + h * HD;
    #pragma unroll
    for (int j = 0; j < 4; ++j) {
        float inva = 1.0f / lsa[j];
        float invb = 1.0f / lsb[j];
        int r = (lg * 4 + j) * D_MODEL;
        #pragma unroll
        for (int ni = 0; ni < 4; ++ni) {
            Oa[r + ni * 16 + lr] = f2bf(oa[ni][j] * inva);
            Ob[r + ni * 16 + lr] = f2bf(ob[ni][j] * invb);
        }
    }
}

// ---------- launch ----------
extern "C" void kernel_launch(void* const* d_in, const int* in_sizes, int n_in,
                              void* d_out, int out_size, void* d_ws, size_t ws_size,
                              hipStream_t stream)
{
    (void)in_sizes; (void)n_in; (void)out_size; (void)ws_size;
    const float* x   = (const float*)d_in[0];
    const float* Wq  = (const float*)d_in[2];
    const float* bq  = (const float*)d_in[3];
    const float* Wk  = (const float*)d_in[4];
    const float* bk  = (const float*)d_in[5];
    const float* Wv  = (const float*)d_in[6];
    const float* bv  = (const float*)d_in[7];
    const float* Wo  = (const float*)d_in[8];
    const float* bo  = (const float*)d_in[9];
    const float* g1  = (const float*)d_in[10];
    const float* be1 = (const float*)d_in[11];
    const float* g2  = (const float*)d_in[12];
    const float* be2 = (const float*)d_in[13];
    const float* W1  = (const float*)d_in[14];
    const float* b1  = (const float*)d_in[15];
    const float* W2  = (const float*)d_in[16];
    const float* b2  = (const float*)d_in[17];
    float* out = (float*)d_out;

    const size_t MM = 1 << 20;   // 1M elems
    u16* Wqkv_b = (u16*)d_ws;            // 3M u16 (Wq,Wk,Wv packed [3072][1024])
    u16* Wo_b = Wqkv_b + 3 * MM;
    u16* W1_b = Wo_b + MM;               // 4M
    u16* W2_b = W1_b + 4 * MM;           // 4M
    u16* hbuf = W2_b + 4 * MM;           // 4M (LN out; dead after its GEMM)
    u16* QKVb = hbuf + 4 * MM;           // 12M  [4096][3072]
    u16* ctx  = QKVb + 12 * MM;          // 4M
    u16* ffn1 = ctx + 4 * MM;            // 16M
    float* x2 = (float*)(ffn1 + 16 * MM);        // 4M f32
    float* bqkv = (float*)(x2 + 4 * MM);         // 3072 f32
    u16* VTb = hbuf;                     // aliases hbuf (dead after QKV GEMM)
    float* fpart = (float*)QKVb;         // FFN2 partials alias QKV+ctx (dead)

    // fused weight converts
    cvt_all<<<12 * MM / 1024, 256, 0, stream>>>(Wq, Wk, Wv, Wo, W1, W2, Wqkv_b);

    // pack QKV bias
    hipMemcpyAsync(bqkv,        bq, D_MODEL * sizeof(float), hipMemcpyDeviceToDevice, stream);
    hipMemcpyAsync(bqkv + 1024, bk, D_MODEL * sizeof(float), hipMemcpyDeviceToDevice, stream);
    hipMemcpyAsync(bqkv + 2048, bv, D_MODEL * sizeof(float), hipMemcpyDeviceToDevice, stream);

    // LN1
    ln_bf16<<<ROWS, 256, 0, stream>>>(x, g1, be1, hbuf);

    // fused QKV projection: 256x256 v4, 192 blocks (75% fill, 2x work/block)
    gemm256<EPI_BF16><<<(ROWS / 256) * (QKVS / 256), 512, 0, stream>>>(
        hbuf, Wqkv_b, bqkv, nullptr, QKVb, nullptr, ROWS, QKVS, D_MODEL);

    // V transpose (hbuf dead now)
    vtrans<<<dim3(SEQ / 64, BATCH * NH), 256, 0, stream>>>(QKVb, VTb);

    // attention: paired q-tiles, 512 equal blocks
    dim3 ga(SEQ / QBLK / 2, BATCH * NH);      // (16, 32)
    attn7<<<ga, 256, 0, stream>>>(QKVb, VTb, ctx);

    // Wo projection + residual
    dim3 gq(D_MODEL / 128, ROWS / 128);
    gemm_bt<EPI_RESF32><<<gq, 256, 0, stream>>>(ctx, Wo_b, bo, x, nullptr, x2,
                                                ROWS, D_MODEL, 1024, 1024);

    // LN2
    ln_bf16<<<ROWS, 256, 0, stream>>>(x2, g2, be2, hbuf);

    // FFN1 + GELU: 256x256 v4, 256 blocks = exact CU fill
    gemm256<EPI_GELU><<<(ROWS / 256) * (D_FF / 256), 512, 0, stream>>>(
        hbuf, W1_b, b1, nullptr, ffn1, nullptr, ROWS, D_FF, D_MODEL);

    // FFN2 split-K2 + fused reduce
    dim3 gf2(D_MODEL / 128, ROWS / 128, 2);
    gemm_bt<EPI_PART><<<gf2, 256, 0, stream>>>(ffn1, W2_b, nullptr, nullptr,
                                               nullptr, fpart, ROWS, D_MODEL, 2048, 4096);
    ffn2_reduce<<<(ROWS * D_MODEL) / 1024, 256, 0, stream>>>(fpart, b2, x2, out);
}

// Round 12
// 237.976 us; speedup vs baseline: 1.8623x; 1.0040x over previous
//
#include <hip/hip_runtime.h>
#include <hip/hip_bf16.h>
#include <cstdint>
#include <cstddef>

typedef unsigned short u16;
typedef __bf16 bf16x8 __attribute__((ext_vector_type(8)));
typedef float f32x4 __attribute__((ext_vector_type(4)));

#define D_MODEL 1024
#define D_FF    4096
#define BATCH   2
#define SEQ     2048
#define NH      16
#define HD      64
#define ROWS    (BATCH*SEQ)   // 4096
#define QKVS    3072          // packed QKV row stride

// ---------- helpers ----------
__device__ __forceinline__ u16 f2bf(float f) {
    union { float f; uint32_t u; } v; v.f = f;
    uint32_t u = v.u;
    u += 0x7FFF + ((u >> 16) & 1);   // RNE
    return (u16)(u >> 16);
}

__device__ __forceinline__ uint32_t cvtpk_bf16(float lo, float hi) {
    uint32_t r;
    asm("v_cvt_pk_bf16_f32 %0, %1, %2" : "=v"(r) : "v"(lo), "v"(hi));
    return r;
}

__device__ __forceinline__ bf16x8 ldg8(const u16* p) {
    return *reinterpret_cast<const bf16x8*>(p);
}

__device__ __forceinline__ f32x4 mfma16(bf16x8 a, bf16x8 b, f32x4 c) {
    return __builtin_amdgcn_mfma_f32_16x16x32_bf16(a, b, c, 0, 0, 0);
}

__device__ __forceinline__ void gld_lds16(const void* g, void* l) {
    __builtin_amdgcn_global_load_lds(
        (const __attribute__((address_space(1))) void*)g,
        (__attribute__((address_space(3))) void*)l, 16, 0, 0);
}

// GELU, tanh-form via exp2; |err| <= ~3e-3.
__device__ __forceinline__ float gelu_f(float x) {
    float u = fmaf(0.044715f * x, x * x, x);
    float z = fminf(-2.3022036f * u, 126.0f);
    float e = __builtin_amdgcn_exp2f(z);
    return x / (1.0f + e);
}

struct alignas(8) U16x4 { u16 x, y, z, w; };

// ---------- fused f32 -> bf16 convert for all weights ----------
__global__ void cvt_all(const float* __restrict__ s0, const float* __restrict__ s1,
                        const float* __restrict__ s2, const float* __restrict__ s3,
                        const float* __restrict__ s4, const float* __restrict__ s5,
                        u16* __restrict__ out)
{
    const size_t MM1 = 1 << 20;
    size_t i = ((size_t)blockIdx.x * 256 + threadIdx.x) * 4;
    const float* src; size_t off;
    if      (i <     MM1) { src = s0; off = i; }
    else if (i < 2 * MM1) { src = s1; off = i - MM1; }
    else if (i < 3 * MM1) { src = s2; off = i - 2 * MM1; }
    else if (i < 4 * MM1) { src = s3; off = i - 3 * MM1; }
    else if (i < 8 * MM1) { src = s4; off = i - 4 * MM1; }
    else                  { src = s5; off = i - 8 * MM1; }
    float4 f = *reinterpret_cast<const float4*>(src + off);
    U16x4 o{ f2bf(f.x), f2bf(f.y), f2bf(f.z), f2bf(f.w) };
    *reinterpret_cast<U16x4*>(out + i) = o;
}

// ---------- LayerNorm (f32 in, bf16 out) ----------
__global__ __launch_bounds__(256) void ln_bf16(
    const float* __restrict__ x, const float* __restrict__ g,
    const float* __restrict__ b, u16* __restrict__ out)
{
    int row = blockIdx.x;
    const float* xr = x + (size_t)row * D_MODEL;
    int t = threadIdx.x;
    float4 v = *reinterpret_cast<const float4*>(xr + t * 4);
    float s = v.x + v.y + v.z + v.w;
    float q = v.x*v.x + v.y*v.y + v.z*v.z + v.w*v.w;
    #pragma unroll
    for (int off = 1; off < 64; off <<= 1) {
        s += __shfl_xor(s, off);
        q += __shfl_xor(q, off);
    }
    __shared__ float red[8];
    if ((t & 63) == 0) { red[(t >> 6) * 2] = s; red[(t >> 6) * 2 + 1] = q; }
    __syncthreads();
    float sum = red[0] + red[2] + red[4] + red[6];
    float sq  = red[1] + red[3] + red[5] + red[7];
    float mu  = sum * (1.0f / D_MODEL);
    float var = sq * (1.0f / D_MODEL) - mu * mu;
    float rstd = rsqrtf(var + 1e-6f);
    float4 gg = *reinterpret_cast<const float4*>(g + t * 4);
    float4 bb = *reinterpret_cast<const float4*>(b + t * 4);
    U16x4 o{ f2bf((v.x - mu) * rstd * gg.x + bb.x),
             f2bf((v.y - mu) * rstd * gg.y + bb.y),
             f2bf((v.z - mu) * rstd * gg.z + bb.z),
             f2bf((v.w - mu) * rstd * gg.w + bb.w) };
    *reinterpret_cast<U16x4*>(out + (size_t)row * D_MODEL + t * 4) = o;
}

#define EPI_BF16   0
#define EPI_RESF32 1
#define EPI_GELU   2
#define EPI_PART   3

// ---------- GEMM 128x128, m97-style single-buffer (occupancy-driven) ----------
// 32 KB LDS, 2 barriers/K-step, 4 blocks/CU (16 waves/CU): co-resident
// blocks' MFMA covers each block's staging drain (m114 overlap) -- the
// proven 874-912 TF structure. VGPR capped at 128 by launch bounds.
template<int EPI>
__global__ __launch_bounds__(256, 4) void gemm97(
    const u16* __restrict__ A, const u16* __restrict__ B,
    const float* __restrict__ bias, const float* __restrict__ res,
    u16* __restrict__ outb, float* __restrict__ outf,
    int M, int N, int K, int KS)
{
    __shared__ u16 As[128 * 64];
    __shared__ u16 Bs[128 * 64];
    const int t = threadIdx.x;
    const int lane = t & 63, w = t >> 6;
    const int lr = lane & 15, lg = lane >> 4;
    const int wrr = (w >> 1) * 64, wcc = (w & 1) * 64;
    const int brow = blockIdx.y * 128, bcol = blockIdx.x * 128;
    const u16* Ag = A + (size_t)brow * KS;
    const u16* Bg = B + (size_t)bcol * KS;

    f32x4 acc[4][4] = {};
    const int NT = K >> 6;

    for (int kt = 0; kt < NT; ++kt) {
        // stage tile kt (8 x 16B per thread), inverse-swizzled source
        #pragma unroll
        for (int c = 0; c < 4; ++c) {
            int f = c * 256 + t;
            int row = f >> 3, slot = f & 7;
            int sg = slot ^ (row & 7);
            gld_lds16(Ag + (size_t)row * KS + kt * 64 + sg * 8, As + f * 8);
            gld_lds16(Bg + (size_t)row * KS + kt * 64 + sg * 8, Bs + f * 8);
        }
        __syncthreads();   // drains vmcnt(0): tile resident

        bf16x8 af[4][2];
        #pragma unroll
        for (int mi = 0; mi < 4; ++mi) {
            int row = wrr + mi * 16 + lr;
            const u16* bp = As + row * 64;
            int key = row & 7;
            af[mi][0] = ldg8(bp + ((0 + lg) ^ key) * 8);
            af[mi][1] = ldg8(bp + ((4 + lg) ^ key) * 8);
        }
        __builtin_amdgcn_s_setprio(1);
        #pragma unroll
        for (int ni = 0; ni < 4; ++ni) {
            int row = wcc + ni * 16 + lr;
            const u16* bp = Bs + row * 64;
            int key = row & 7;
            bf16x8 b0 = ldg8(bp + ((0 + lg) ^ key) * 8);
            bf16x8 b1 = ldg8(bp + ((4 + lg) ^ key) * 8);
            #pragma unroll
            for (int mi = 0; mi < 4; ++mi) {
                acc[mi][ni] = mfma16(af[mi][0], b0, acc[mi][ni]);
                acc[mi][ni] = mfma16(af[mi][1], b1, acc[mi][ni]);
            }
        }
        __builtin_amdgcn_s_setprio(0);
        __syncthreads();   // all reads done before next stage overwrites
    }

    #pragma unroll
    for (int mi = 0; mi < 4; ++mi) {
        int r0 = brow + wrr + mi * 16 + lg * 4;
        #pragma unroll
        for (int ni = 0; ni < 4; ++ni) {
            int c = bcol + wcc + ni * 16 + lr;
            float bv = bias[c];
            #pragma unroll
            for (int j = 0; j < 4; ++j) {
                float v = acc[mi][ni][j] + bv;
                size_t idx = (size_t)(r0 + j) * N + c;
                if constexpr (EPI == EPI_GELU) {
                    outb[idx] = f2bf(gelu_f(v));
                } else if constexpr (EPI == EPI_RESF32) {
                    outf[idx] = v + res[idx];
                } else {
                    outb[idx] = f2bf(v);
                }
            }
        }
    }
}

// ---------- GEMM 128x128, 2-deep counted-vmcnt pipeline (Wo / FFN2 splitK) ----------
template<int EPI>
__global__ __launch_bounds__(256, 2) void gemm_bt(
    const u16* __restrict__ A, const u16* __restrict__ B,
    const float* __restrict__ bias, const float* __restrict__ res,
    u16* __restrict__ outb, float* __restrict__ outf,
    int M, int N, int K, int KS)
{
    __shared__ u16 As[2][128 * 64];
    __shared__ u16 Bs[2][128 * 64];
    const int t = threadIdx.x;
    const int lane = t & 63;
    const int w = t >> 6;
    const int lr = lane & 15, lg = lane >> 4;
    const int wrr = (w >> 1) * 64, wcc = (w & 1) * 64;
    const int brow = blockIdx.y * 128, bcol = blockIdx.x * 128;
    const int kz = blockIdx.z;
    const u16* Ag = A + (size_t)brow * KS + (size_t)kz * K;
    const u16* Bg = B + (size_t)bcol * KS + (size_t)kz * K;

    f32x4 acc[4][4] = {};

    const int NT = K >> 6;

    auto stage = [&](int buf, int kt) {
        const u16* ga = Ag + kt * 64;
        const u16* gb = Bg + kt * 64;
        u16* la = As[buf];
        u16* lb = Bs[buf];
        #pragma unroll
        for (int c = 0; c < 4; ++c) {
            int f = c * 256 + t;
            int row = f >> 3, slot = f & 7;
            int sg = slot ^ (row & 7);
            gld_lds16(ga + (size_t)row * KS + sg * 8, la + f * 8);
            gld_lds16(gb + (size_t)row * KS + sg * 8, lb + f * 8);
        }
    };

    auto compute = [&](int buf) {
        const u16* la = As[buf];
        const u16* lb = Bs[buf];
        bf16x8 af[4][2];
        #pragma unroll
        for (int mi = 0; mi < 4; ++mi) {
            int row = wrr + mi * 16 + lr;
            int base = row * 64;
            af[mi][0] = *reinterpret_cast<const bf16x8*>(la + base + ((0 + lg) ^ (row & 7)) * 8);
            af[mi][1] = *reinterpret_cast<const bf16x8*>(la + base + ((4 + lg) ^ (row & 7)) * 8);
        }
        __builtin_amdgcn_s_setprio(1);
        #pragma unroll
        for (int ni = 0; ni < 4; ++ni) {
            int row = wcc + ni * 16 + lr;
            int base = row * 64;
            bf16x8 b0 = *reinterpret_cast<const bf16x8*>(lb + base + ((0 + lg) ^ (row & 7)) * 8);
            bf16x8 b1 = *reinterpret_cast<const bf16x8*>(lb + base + ((4 + lg) ^ (row & 7)) * 8);
            #pragma unroll
            for (int mi = 0; mi < 4; ++mi) {
                acc[mi][ni] = mfma16(af[mi][0], b0, acc[mi][ni]);
                acc[mi][ni] = mfma16(af[mi][1], b1, acc[mi][ni]);
            }
        }
        __builtin_amdgcn_s_setprio(0);
    };

    stage(0, 0);
    if (NT > 1) {
        stage(1, 1);
        asm volatile("s_waitcnt vmcnt(8)" ::: "memory");
    } else {
        asm volatile("s_waitcnt vmcnt(0)" ::: "memory");
    }
    __builtin_amdgcn_s_barrier();

    for (int kt = 0; kt < NT; ++kt) {
        compute(kt & 1);
        if (kt + 1 == NT) break;
        __builtin_amdgcn_s_barrier();
        if (kt + 2 < NT) {
            stage(kt & 1, kt + 2);
            asm volatile("s_waitcnt vmcnt(8)" ::: "memory");
        } else {
            asm volatile("s_waitcnt vmcnt(0)" ::: "memory");
        }
        __builtin_amdgcn_s_barrier();
    }

    #pragma unroll
    for (int mi = 0; mi < 4; ++mi) {
        int r0 = brow + wrr + mi * 16 + lg * 4;
        #pragma unroll
        for (int ni = 0; ni < 4; ++ni) {
            int c = bcol + wcc + ni * 16 + lr;
            float bv = 0.f;
            if constexpr (EPI != EPI_PART) bv = bias[c];
            #pragma unroll
            for (int j = 0; j < 4; ++j) {
                float v = acc[mi][ni][j] + bv;
                size_t idx = (size_t)(r0 + j) * N + c;
                if constexpr (EPI == EPI_GELU) {
                    outb[idx] = f2bf(gelu_f(v));
                } else if constexpr (EPI == EPI_RESF32) {
                    outf[idx] = v + res[idx];
                } else if constexpr (EPI == EPI_PART) {
                    outf[idx + (size_t)kz * M * N] = v;
                } else {
                    outb[idx] = f2bf(v);
                }
            }
        }
    }
}

// ---------- FFN2 partial reduce: out = p0 + p1 + bias + residual ----------
__global__ void ffn2_reduce(const float* __restrict__ p,
                            const float* __restrict__ b2,
                            const float* __restrict__ x2,
                            float* __restrict__ out)
{
    size_t i = ((size_t)blockIdx.x * 256 + threadIdx.x) * 4;
    float4 a0 = *reinterpret_cast<const float4*>(p + i);
    float4 a1 = *reinterpret_cast<const float4*>(p + (size_t)ROWS * D_MODEL + i);
    float4 r  = *reinterpret_cast<const float4*>(x2 + i);
    float4 bb = *reinterpret_cast<const float4*>(b2 + (i & (D_MODEL - 1)));
    float4 o;
    o.x = a0.x + a1.x + r.x + bb.x;
    o.y = a0.y + a1.y + r.y + bb.y;
    o.z = a0.z + a1.z + r.z + bb.z;
    o.w = a0.w + a1.w + r.w + bb.w;
    *reinterpret_cast<float4*>(out + i) = o;
}

// ---------- V transpose via LDS (coalesced both sides) ----------
__global__ __launch_bounds__(256) void vtrans(
    const u16* __restrict__ QKV, u16* __restrict__ VT)
{
    __shared__ u16 tile[64][72];
    const int st = blockIdx.x * 64;
    const int bh = blockIdx.y;
    const int b = bh >> 4, h = bh & 15;
    const int t = threadIdx.x;

    #pragma unroll
    for (int c = 0; c < 2; ++c) {
        int tok = c * 32 + (t >> 3);
        int d0 = (t & 7) * 8;
        bf16x8 v = ldg8(QKV + ((size_t)(b * SEQ + st + tok)) * QKVS + 2048 + h * HD + d0);
        *reinterpret_cast<bf16x8*>(&tile[tok][d0]) = v;
    }
    __syncthreads();
    u16* dst = VT + (size_t)bh * HD * SEQ + st;
    #pragma unroll
    for (int c = 0; c < 2; ++c) {
        int d = c * 32 + (t >> 3);
        int tok0 = (t & 7) * 8;
        u16 vals[8];
        #pragma unroll
        for (int i = 0; i < 8; ++i) vals[i] = tile[tok0 + i][d];
        *reinterpret_cast<bf16x8*>(dst + (size_t)d * SEQ + tok0) =
            *reinterpret_cast<const bf16x8*>(vals);
    }
}

// ---------- causal flash attention v7: PAIRED q-tiles (perfect balance) ----------
#define QBLK  64
#define KVBLK 64

__global__ __launch_bounds__(256, 3) void attn7(
    const u16* __restrict__ QKV, const u16* __restrict__ VT,
    u16* __restrict__ O)
{
    __shared__ u16 Ks[2][64 * 64];    // [kv][d], swizzle key (kv>>2)&7
    __shared__ u16 Vs[2][64 * 64];    // [d][kv], swizzle key d&7
    __shared__ u16 Pl[4][16 * 72];    // per-wave P[q][kv], stride 72

    const int i  = blockIdx.x;            // 0..15
    const int bh = blockIdx.y;
    const int b = bh >> 4, h = bh & 15;
    const int qta = 31 - i;               // heavy q-tile
    const int qtb = i;                    // light q-tile
    const int q0a = qta * QBLK, q0b = qtb * QBLK;
    const int t = threadIdx.x;
    const int lane = t & 63, w = t >> 6;
    const int lr = lane & 15, lg = lane >> 4;

    const size_t rowbase = (size_t)b * SEQ;
    const u16* Qg = QKV + rowbase * QKVS + h * HD;
    const u16* Kg = Qg + 1024;
    const u16* Vg = VT + (size_t)bh * HD * SEQ;

    const u16* qpa = Qg + (size_t)(q0a + w * 16 + lr) * QKVS;
    const u16* qpb = Qg + (size_t)(q0b + w * 16 + lr) * QKVS;
    bf16x8 qa0 = ldg8(qpa + lg * 8), qa1 = ldg8(qpa + 32 + lg * 8);
    bf16x8 qb0 = ldg8(qpb + lg * 8), qb1 = ldg8(qpb + 32 + lg * 8);

    f32x4 oa[4] = {}, ob[4] = {};
    float lsa[4] = {}, lsb[4] = {};

    const int ntiles = qta + 1;           // 17..32
    u16* Pw = Pl[w];
    const float SC = 0.125f * 1.44269504089f;

    auto stage = [&](int buf, int tt) {
        const int kv0 = tt * KVBLK;
        #pragma unroll
        for (int c = 0; c < 2; ++c) {
            int f = c * 256 + t;
            int row = f >> 3, slot = f & 7;
            int sgk = slot ^ ((row >> 2) & 7);
            int sgv = slot ^ (row & 7);
            gld_lds16(Kg + (size_t)(kv0 + row) * QKVS + sgk * 8, Ks[buf] + f * 8);
            gld_lds16(Vg + (size_t)row * SEQ + kv0 + sgv * 8, Vs[buf] + f * 8);
        }
    };

    auto qtile = [&](bf16x8 qf0, bf16x8 qf1, f32x4* o, float* ls,
                     int q0, int kv0, bool diag, const u16* kb, const u16* vb) {
        f32x4 s[4] = {};
        __builtin_amdgcn_s_setprio(1);
        #pragma unroll
        for (int ni = 0; ni < 4; ++ni) {
            int row = lr * 4 + ni;
            const u16* base = kb + row * 64;
            int key = (row >> 2) & 7;
            bf16x8 k0 = *reinterpret_cast<const bf16x8*>(base + ((0 + lg) ^ key) * 8);
            bf16x8 k1 = *reinterpret_cast<const bf16x8*>(base + ((4 + lg) ^ key) * 8);
            s[ni] = mfma16(qf0, k0, s[ni]);
            s[ni] = mfma16(qf1, k1, s[ni]);
        }
        __builtin_amdgcn_s_setprio(0);

        #pragma unroll
        for (int j = 0; j < 4; ++j) {
            int qi = q0 + w * 16 + lg * 4 + j;
            float p0 = __builtin_amdgcn_exp2f(s[0][j] * SC);
            float p1 = __builtin_amdgcn_exp2f(s[1][j] * SC);
            float p2 = __builtin_amdgcn_exp2f(s[2][j] * SC);
            float p3 = __builtin_amdgcn_exp2f(s[3][j] * SC);
            if (diag) {
                int kvb = kv0 + lr * 4;
                p0 = (kvb     <= qi) ? p0 : 0.f;
                p1 = (kvb + 1 <= qi) ? p1 : 0.f;
                p2 = (kvb + 2 <= qi) ? p2 : 0.f;
                p3 = (kvb + 3 <= qi) ? p3 : 0.f;
            }
            ls[j] += (p0 + p1) + (p2 + p3);
            uint2 pk = make_uint2(cvtpk_bf16(p0, p1), cvtpk_bf16(p2, p3));
            *reinterpret_cast<uint2*>(&Pw[(lg * 4 + j) * 72 + lr * 4]) = pk;
        }

        bf16x8 pa0 = *reinterpret_cast<const bf16x8*>(Pw + lr * 72 + lg * 8);
        bf16x8 pa1 = *reinterpret_cast<const bf16x8*>(Pw + lr * 72 + 32 + lg * 8);
        __builtin_amdgcn_s_setprio(1);
        #pragma unroll
        for (int ni = 0; ni < 4; ++ni) {
            int row = ni * 16 + lr;
            const u16* base = vb + row * 64;
            bf16x8 v0 = *reinterpret_cast<const bf16x8*>(base + ((0 + lg) ^ (row & 7)) * 8);
            bf16x8 v1 = *reinterpret_cast<const bf16x8*>(base + ((4 + lg) ^ (row & 7)) * 8);
            o[ni] = mfma16(pa0, v0, o[ni]);
            o[ni] = mfma16(pa1, v1, o[ni]);
        }
        __builtin_amdgcn_s_setprio(0);
    };

    stage(0, 0);
    stage(1, 1);
    asm volatile("s_waitcnt vmcnt(4)" ::: "memory");
    __builtin_amdgcn_s_barrier();

    for (int tt = 0; tt < ntiles; ++tt) {
        const int buf = tt & 1;
        const int kv0 = tt * KVBLK;
        const u16* kb = Ks[buf];
        const u16* vb = Vs[buf];

        qtile(qa0, qa1, oa, lsa, q0a, kv0, tt == qta, kb, vb);
        if (tt <= qtb)
            qtile(qb0, qb1, ob, lsb, q0b, kv0, tt == qtb, kb, vb);

        if (tt + 1 == ntiles) break;
        __builtin_amdgcn_s_barrier();
        if (tt + 2 < ntiles) {
            stage(buf, tt + 2);
            asm volatile("s_waitcnt vmcnt(4)" ::: "memory");
        } else {
            asm volatile("s_waitcnt vmcnt(0)" ::: "memory");
        }
        __builtin_amdgcn_s_barrier();
    }

    #pragma unroll
    for (int j = 0; j < 4; ++j) {
        float va = lsa[j], vb2 = lsb[j];
        va += __shfl_xor(va, 1); vb2 += __shfl_xor(vb2, 1);
        va += __shfl_xor(va, 2); vb2 += __shfl_xor(vb2, 2);
        va += __shfl_xor(va, 4); vb2 += __shfl_xor(vb2, 4);
        va += __shfl_xor(va, 8); vb2 += __shfl_xor(vb2, 8);
        lsa[j] = va; lsb[j] = vb2;
    }

    u16* Oa = O + (rowbase + q0a + w * 16) * D_MODEL + h * HD;
    u16* Ob = O + (rowbase + q0b + w * 16) * D_MODEL + h * HD;
    #pragma unroll
    for (int j = 0; j < 4; ++j) {
        float inva = 1.0f / lsa[j];
        float invb = 1.0f / lsb[j];
        int r = (lg * 4 + j) * D_MODEL;
        #pragma unroll
        for (int ni = 0; ni < 4; ++ni) {
            Oa[r + ni * 16 + lr] = f2bf(oa[ni][j] * inva);
            Ob[r + ni * 16 + lr] = f2bf(ob[ni][j] * invb);
        }
    }
}

// ---------- launch ----------
extern "C" void kernel_launch(void* const* d_in, const int* in_sizes, int n_in,
                              void* d_out, int out_size, void* d_ws, size_t ws_size,
                              hipStream_t stream)
{
    (void)in_sizes; (void)n_in; (void)out_size; (void)ws_size;
    const float* x   = (const float*)d_in[0];
    const float* Wq  = (const float*)d_in[2];
    const float* bq  = (const float*)d_in[3];
    const float* Wk  = (const float*)d_in[4];
    const float* bk  = (const float*)d_in[5];
    const float* Wv  = (const float*)d_in[6];
    const float* bv  = (const float*)d_in[7];
    const float* Wo  = (const float*)d_in[8];
    const float* bo  = (const float*)d_in[9];
    const float* g1  = (const float*)d_in[10];
    const float* be1 = (const float*)d_in[11];
    const float* g2  = (const float*)d_in[12];
    const float* be2 = (const float*)d_in[13];
    const float* W1  = (const float*)d_in[14];
    const float* b1  = (const float*)d_in[15];
    const float* W2  = (const float*)d_in[16];
    const float* b2  = (const float*)d_in[17];
    float* out = (float*)d_out;

    const size_t MM = 1 << 20;   // 1M elems
    u16* Wqkv_b = (u16*)d_ws;            // 3M u16 (Wq,Wk,Wv packed [3072][1024])
    u16* Wo_b = Wqkv_b + 3 * MM;
    u16* W1_b = Wo_b + MM;               // 4M
    u16* W2_b = W1_b + 4 * MM;           // 4M
    u16* hbuf = W2_b + 4 * MM;           // 4M (LN out; dead after its GEMM)
    u16* QKVb = hbuf + 4 * MM;           // 12M  [4096][3072]
    u16* ctx  = QKVb + 12 * MM;          // 4M
    u16* ffn1 = ctx + 4 * MM;            // 16M
    float* x2 = (float*)(ffn1 + 16 * MM);        // 4M f32
    float* bqkv = (float*)(x2 + 4 * MM);         // 3072 f32
    u16* VTb = hbuf;                     // aliases hbuf (dead after QKV GEMM)
    float* fpart = (float*)QKVb;         // FFN2 partials alias QKV+ctx (dead)

    // fused weight converts
    cvt_all<<<12 * MM / 1024, 256, 0, stream>>>(Wq, Wk, Wv, Wo, W1, W2, Wqkv_b);

    // pack QKV bias
    hipMemcpyAsync(bqkv,        bq, D_MODEL * sizeof(float), hipMemcpyDeviceToDevice, stream);
    hipMemcpyAsync(bqkv + 1024, bk, D_MODEL * sizeof(float), hipMemcpyDeviceToDevice, stream);
    hipMemcpyAsync(bqkv + 2048, bv, D_MODEL * sizeof(float), hipMemcpyDeviceToDevice, stream);

    // LN1
    ln_bf16<<<ROWS, 256, 0, stream>>>(x, g1, be1, hbuf);

    // fused QKV projection: m97 single-buffer, 768 blocks = 3 blocks/CU
    dim3 gqkv(QKVS / 128, ROWS / 128);
    gemm97<EPI_BF16><<<gqkv, 256, 0, stream>>>(hbuf, Wqkv_b, bqkv, nullptr,
                                               QKVb, nullptr, ROWS, QKVS, 1024, 1024);

    // V transpose (hbuf dead now)
    vtrans<<<dim3(SEQ / 64, BATCH * NH), 256, 0, stream>>>(QKVb, VTb);

    // attention: paired q-tiles, 512 equal blocks
    dim3 ga(SEQ / QBLK / 2, BATCH * NH);      // (16, 32)
    attn7<<<ga, 256, 0, stream>>>(QKVb, VTb, ctx);

    // Wo projection + residual (counted-vmcnt dbuf, 2/CU)
    dim3 gq(D_MODEL / 128, ROWS / 128);
    gemm_bt<EPI_RESF32><<<gq, 256, 0, stream>>>(ctx, Wo_b, bo, x, nullptr, x2,
                                                ROWS, D_MODEL, 1024, 1024);

    // LN2
    ln_bf16<<<ROWS, 256, 0, stream>>>(x2, g2, be2, hbuf);

    // FFN1 + GELU: m97 single-buffer, 1024 blocks = 4 blocks/CU
    dim3 gf1(D_FF / 128, ROWS / 128);
    gemm97<EPI_GELU><<<gf1, 256, 0, stream>>>(hbuf, W1_b, b1, nullptr, ffn1, nullptr,
                                              ROWS, D_FF, 1024, 1024);

    // FFN2 split-K2 + fused reduce
    dim3 gf2(D_MODEL / 128, ROWS / 128, 2);
    gemm_bt<EPI_PART><<<gf2, 256, 0, stream>>>(ffn1, W2_b, nullptr, nullptr,
                                               nullptr, fpart, ROWS, D_MODEL, 2048, 4096);
    ffn2_reduce<<<(ROWS * D_MODEL) / 1024, 256, 0, stream>>>(fpart, b2, x2, out);
}